// Round 5
// baseline (515.332 us; speedup 1.0000x reference)
//
#include <hip/hip_runtime.h>

#define T_LEN 2048
#define C_DIM 1024
#define PAIR_F 768          // floats per (head, step-pair) packet
#define NCH 16              // chunks
#define CPAIR 64            // pairs per chunk (NCH*CPAIR = 1024)

#define AS1 __attribute__((address_space(1)))
#define AS3 __attribute__((address_space(3)))

typedef __attribute__((ext_vector_type(8))) short bf8_t;
typedef __attribute__((ext_vector_type(4))) float f4_t;
typedef __attribute__((ext_vector_type(2))) float f2_t;

static __device__ __forceinline__ float sigf(float x) {
    return 1.f / (1.f + __expf(-x));
}
static __device__ __forceinline__ unsigned short f2bf(float f) {
    unsigned u = __float_as_uint(f);
    u += 0x7fff + ((u >> 16) & 1);
    return (unsigned short)(u >> 16);
}

// ---------------------------------------------------------------------------
// Convert the four 1024x1024 fp32 weights into one bf16 block (1M strides),
// plus the transposed LoRA stage-1 weights (blocks 4096..4383).
// ---------------------------------------------------------------------------
__global__ __launch_bounds__(256) void wcvtall(
    const float* __restrict__ Wr, const float* __restrict__ Wk,
    const float* __restrict__ Wv, const float* __restrict__ Wo,
    const float* __restrict__ w1, const float* __restrict__ a1,
    const float* __restrict__ v1, const float* __restrict__ g1,
    unsigned short* __restrict__ dst, unsigned short* __restrict__ lw16)
{
    const int b = blockIdx.x;
    if (b < 4096) {
        const size_t idx = ((size_t)b * 256 + threadIdx.x) * 4;
        const int sel = (int)(idx >> 20);
        const float* src = sel == 0 ? Wr : sel == 1 ? Wk : sel == 2 ? Wv : Wo;
        float4 v = *(const float4*)(src + (idx & 0xFFFFF));
        ushort4 o = {f2bf(v.x), f2bf(v.y), f2bf(v.z), f2bf(v.w)};
        *(ushort4*)(dst + idx) = o;
        return;
    }
    const int row = b - 4096;         // 0..287
    const float* src; int Kh, i; unsigned short* dl;
    if (row < 64)       { src = w1; Kh = 64;  i = row;       dl = lw16 + (size_t)row * 1024; }
    else if (row < 128) { src = a1; Kh = 64;  i = row - 64;  dl = lw16 + (size_t)row * 1024; }
    else if (row < 160) { src = v1; Kh = 32;  i = row - 128; dl = lw16 + (size_t)(row - 128 + 128) * 1024; }
    else                { src = g1; Kh = 128; i = row - 160; dl = lw16 + (size_t)(row - 160 + 192) * 1024; }
    const int c0 = threadIdx.x * 4;
#pragma unroll
    for (int u = 0; u < 4; ++u)
        dl[c0 + u] = f2bf(src[(size_t)(c0 + u) * Kh + i]);
}

// ---------------------------------------------------------------------------
// Token-shift mix -> bf16 A-matrices for r/k/v projections and w/a/g LoRA.
// ---------------------------------------------------------------------------
__global__ __launch_bounds__(256) void xcvt(
    const float* __restrict__ x, const float* __restrict__ xprev,
    const float* __restrict__ x_r, const float* __restrict__ x_k,
    const float* __restrict__ x_v, const float* __restrict__ x_w,
    const float* __restrict__ x_a, const float* __restrict__ x_g,
    unsigned short* __restrict__ xr16, unsigned short* __restrict__ xk16,
    unsigned short* __restrict__ xv16, unsigned short* __restrict__ xw16,
    unsigned short* __restrict__ xa16, unsigned short* __restrict__ xg16)
{
    const int t = blockIdx.x;
    const int c0 = threadIdx.x * 4;
    const size_t base = (size_t)t * C_DIM + c0;
    float4 xv = *(const float4*)(x + base);
    float4 pv = (t == 0) ? *(const float4*)(xprev + c0)
                         : *(const float4*)(x + base - C_DIM);
    float4 dx = {pv.x - xv.x, pv.y - xv.y, pv.z - xv.z, pv.w - xv.w};
#define MIXOUT(mixp, dstp)                                                    \
    {                                                                          \
        float4 mv = *(const float4*)(mixp + c0);                               \
        ushort4 o = {f2bf(xv.x + dx.x * mv.x), f2bf(xv.y + dx.y * mv.y),       \
                     f2bf(xv.z + dx.z * mv.z), f2bf(xv.w + dx.w * mv.w)};      \
        *(ushort4*)(dstp + base) = o;                                          \
    }
    MIXOUT(x_r, xr16) MIXOUT(x_k, xk16) MIXOUT(x_v, xv16)
    MIXOUT(x_w, xw16) MIXOUT(x_a, xa16) MIXOUT(x_g, xg16)
#undef MIXOUT
}

// ---------------------------------------------------------------------------
// bf16 MFMA NT GEMM core: out[t,i] = sum_c A[t,c]*W[i,c], fp32 accumulate.
// ---------------------------------------------------------------------------
static __device__ __forceinline__ void gemm_core(
    const unsigned short* __restrict__ A, const unsigned short* __restrict__ W,
    float* __restrict__ out)
{
    __shared__ unsigned short Ab[2][128 * 32];
    __shared__ unsigned short Bb[2][64 * 32];
    const int tid = threadIdx.x;
    const int lane = tid & 63;
    const int w = tid >> 6;
    const int n0 = blockIdx.x * 64;
    const int t0 = blockIdx.y * 128;
    const int wm = (w & 1) * 64;
    const int wn = (w >> 1) * 32;
    const int srow = lane >> 2;
    const int scol = (lane & 3) * 8;

    f4_t acc[4][2];
#pragma unroll
    for (int i = 0; i < 4; ++i)
#pragma unroll
        for (int j = 0; j < 2; ++j)
            acc[i][j] = (f4_t){0.f, 0.f, 0.f, 0.f};

#pragma unroll
    for (int s = 0; s < 2; ++s) {
        const int i = 2 * w + s;
        __builtin_amdgcn_global_load_lds(
            (const AS1 unsigned int*)(A + (size_t)(t0 + i * 16 + srow) * 1024 + scol),
            (AS3 unsigned int*)(&Ab[0][i * 512 + lane * 8]), 16, 0, 0);
    }
    __builtin_amdgcn_global_load_lds(
        (const AS1 unsigned int*)(W + (size_t)(n0 + w * 16 + srow) * 1024 + scol),
        (AS3 unsigned int*)(&Bb[0][w * 512 + lane * 8]), 16, 0, 0);

    const int mrow = lane & 15;
    const int kq = (lane >> 4) * 8;
    for (int k0 = 0; k0 < 1024; k0 += 32) {
        const int cur = (k0 >> 5) & 1, nxt = cur ^ 1;
        __syncthreads();
        if (k0 + 32 < 1024) {
            const int k1 = k0 + 32;
#pragma unroll
            for (int s = 0; s < 2; ++s) {
                const int i = 2 * w + s;
                __builtin_amdgcn_global_load_lds(
                    (const AS1 unsigned int*)(A + (size_t)(t0 + i * 16 + srow) * 1024 + k1 + scol),
                    (AS3 unsigned int*)(&Ab[nxt][i * 512 + lane * 8]), 16, 0, 0);
            }
            __builtin_amdgcn_global_load_lds(
                (const AS1 unsigned int*)(W + (size_t)(n0 + w * 16 + srow) * 1024 + k1 + scol),
                (AS3 unsigned int*)(&Bb[nxt][w * 512 + lane * 8]), 16, 0, 0);
        }
        bf8_t af[4], bfr[2];
#pragma unroll
        for (int i = 0; i < 4; ++i)
            af[i] = *(const bf8_t*)(&Ab[cur][(wm + 16 * i + mrow) * 32 + kq]);
#pragma unroll
        for (int j = 0; j < 2; ++j)
            bfr[j] = *(const bf8_t*)(&Bb[cur][(wn + 16 * j + mrow) * 32 + kq]);
#pragma unroll
        for (int i = 0; i < 4; ++i)
#pragma unroll
            for (int j = 0; j < 2; ++j)
                acc[i][j] = __builtin_amdgcn_mfma_f32_16x16x32_bf16(
                    af[i], bfr[j], acc[i][j], 0, 0, 0);
    }
    const int crow = (lane >> 4) * 4;
    const int ccol = lane & 15;
#pragma unroll
    for (int i = 0; i < 4; ++i)
#pragma unroll
        for (int j = 0; j < 2; ++j)
#pragma unroll
            for (int u = 0; u < 4; ++u)
                out[(size_t)(t0 + wm + 16 * i + crow + u) * 1024
                    + n0 + wn + 16 * j + ccol] = acc[i][j][u];
}

__global__ __launch_bounds__(256) void gemm_bf16_3(
    const unsigned short* __restrict__ xr, const unsigned short* __restrict__ xk,
    const unsigned short* __restrict__ xv,
    const unsigned short* __restrict__ Wr, const unsigned short* __restrict__ Wk,
    const unsigned short* __restrict__ Wv,
    float* __restrict__ rB, float* __restrict__ kB, float* __restrict__ vB)
{
    const int z = blockIdx.z;
    const unsigned short* A = z == 0 ? xr : z == 1 ? xk : xv;
    const unsigned short* W = z == 0 ? Wr : z == 1 ? Wk : Wv;
    float* out = z == 0 ? rB : z == 1 ? kB : vB;
    gemm_core(A, W, out);
}

__global__ __launch_bounds__(256) void gemm_bf16(
    const unsigned short* __restrict__ A, const unsigned short* __restrict__ W,
    float* __restrict__ out)
{
    gemm_core(A, W, out);
}

// ---------------------------------------------------------------------------
// Fused LoRA stage-1 via MFMA: z = 0:w(tanh,N=64) 1:a(N=64) 2:v(N=32) 3:g(sig,N=128)
// ---------------------------------------------------------------------------
__global__ __launch_bounds__(256) void lora1m(
    const unsigned short* __restrict__ xw, const unsigned short* __restrict__ xa,
    const unsigned short* __restrict__ xv, const unsigned short* __restrict__ xg,
    const unsigned short* __restrict__ lw16,
    float* __restrict__ hw, float* __restrict__ ha, float* __restrict__ hv,
    float* __restrict__ hg)
{
    const int z = blockIdx.z;
    const unsigned short* A = z == 0 ? xw : z == 1 ? xa : z == 2 ? xv : xg;
    const unsigned short* W = lw16 + (size_t)(z == 0 ? 0 : z == 1 ? 64 : z == 2 ? 128 : 192) * 1024;
    float* out = z == 0 ? hw : z == 1 ? ha : z == 2 ? hv : hg;
    const int N  = z == 3 ? 128 : z == 2 ? 32 : 64;
    const int Ns = z == 3 ? 128 : 64;
    const int n0 = blockIdx.x * 64;
    if (n0 >= Ns) return;

    __shared__ unsigned short Ab[2][128 * 32];
    __shared__ unsigned short Bb[2][64 * 32];
    const int tid = threadIdx.x;
    const int lane = tid & 63;
    const int w = tid >> 6;
    const int t0 = blockIdx.y * 128;
    const int wm = (w & 1) * 64;
    const int wn = (w >> 1) * 32;
    const int srow = lane >> 2;
    const int scol = (lane & 3) * 8;

    f4_t acc[4][2];
#pragma unroll
    for (int i = 0; i < 4; ++i)
#pragma unroll
        for (int j = 0; j < 2; ++j)
            acc[i][j] = (f4_t){0.f, 0.f, 0.f, 0.f};

#pragma unroll
    for (int s = 0; s < 2; ++s) {
        const int i = 2 * w + s;
        __builtin_amdgcn_global_load_lds(
            (const AS1 unsigned int*)(A + (size_t)(t0 + i * 16 + srow) * 1024 + scol),
            (AS3 unsigned int*)(&Ab[0][i * 512 + lane * 8]), 16, 0, 0);
    }
    __builtin_amdgcn_global_load_lds(
        (const AS1 unsigned int*)(W + (size_t)(n0 + w * 16 + srow) * 1024 + scol),
        (AS3 unsigned int*)(&Bb[0][w * 512 + lane * 8]), 16, 0, 0);

    const int mrow = lane & 15;
    const int kq = (lane >> 4) * 8;
    for (int k0 = 0; k0 < 1024; k0 += 32) {
        const int cur = (k0 >> 5) & 1, nxt = cur ^ 1;
        __syncthreads();
        if (k0 + 32 < 1024) {
            const int k1 = k0 + 32;
#pragma unroll
            for (int s = 0; s < 2; ++s) {
                const int i = 2 * w + s;
                __builtin_amdgcn_global_load_lds(
                    (const AS1 unsigned int*)(A + (size_t)(t0 + i * 16 + srow) * 1024 + k1 + scol),
                    (AS3 unsigned int*)(&Ab[nxt][i * 512 + lane * 8]), 16, 0, 0);
            }
            __builtin_amdgcn_global_load_lds(
                (const AS1 unsigned int*)(W + (size_t)(n0 + w * 16 + srow) * 1024 + k1 + scol),
                (AS3 unsigned int*)(&Bb[nxt][w * 512 + lane * 8]), 16, 0, 0);
        }
        bf8_t af[4], bfr[2];
#pragma unroll
        for (int i = 0; i < 4; ++i)
            af[i] = *(const bf8_t*)(&Ab[cur][(wm + 16 * i + mrow) * 32 + kq]);
#pragma unroll
        for (int j = 0; j < 2; ++j)
            bfr[j] = *(const bf8_t*)(&Bb[cur][(wn + 16 * j + mrow) * 32 + kq]);
#pragma unroll
        for (int i = 0; i < 4; ++i)
#pragma unroll
            for (int j = 0; j < 2; ++j)
                acc[i][j] = __builtin_amdgcn_mfma_f32_16x16x32_bf16(
                    af[i], bfr[j], acc[i][j], 0, 0, 0);
    }
    const int crow = (lane >> 4) * 4;
    const int ccol = lane & 15;
#pragma unroll
    for (int i = 0; i < 4; ++i)
#pragma unroll
        for (int j = 0; j < 2; ++j) {
            const int col = n0 + wn + 16 * j + ccol;
            if (col < N) {
#pragma unroll
                for (int u = 0; u < 4; ++u) {
                    float vv = acc[i][j][u];
                    if (z == 0) vv = tanhf(vv);
                    else if (z == 3) vv = sigf(vv);
                    out[(size_t)(t0 + wm + 16 * i + crow + u) * N + col] = vv;
                }
            }
        }
}

// ---------------------------------------------------------------------------
// Fused LoRA-2 (w/a/v/g) + k post-process + PAIR-COMPOSED packet packing.
// Packet layout (768 floats) unchanged from r4.
// ---------------------------------------------------------------------------
__global__ __launch_bounds__(256) void lora2f(
    const float* __restrict__ hwB, const float* __restrict__ haB,
    const float* __restrict__ hvB, const float* __restrict__ hgB,
    const float* __restrict__ w2, const float* __restrict__ a2,
    const float* __restrict__ v2, const float* __restrict__ g2,
    const float* __restrict__ w0, const float* __restrict__ a0,
    const float* __restrict__ v0,
    const float* __restrict__ k_k, const float* __restrict__ k_a,
    const float* __restrict__ v_first, const float* __restrict__ rB,
    float* __restrict__ kB, float* __restrict__ vB, float* __restrict__ gB,
    float* __restrict__ pk)
{
    __shared__ __align__(16) float hsW[16 * 64], hsA[16 * 64];
    __shared__ __align__(16) float hsV[16 * 32], hsG[16 * 128];
    const int tid = threadIdx.x;
    const int t0 = blockIdx.y * 16;
    const int i  = blockIdx.x * 256 + tid;
    const int h  = i >> 6;
    const int j  = i & 63;
    for (int idx = tid; idx < 16 * 64; idx += 256) {
        hsW[idx] = hwB[(size_t)t0 * 64 + idx];
        hsA[idx] = haB[(size_t)t0 * 64 + idx];
    }
    for (int idx = tid; idx < 16 * 32; idx += 256)
        hsV[idx] = hvB[(size_t)t0 * 32 + idx];
    for (int idx = tid; idx < 16 * 128; idx += 256)
        hsG[idx] = hgB[(size_t)t0 * 128 + idx];
    __syncthreads();

    float av[16], ew[16], vf[16];
    { // a = sigmoid(a0 + ha@a2)
        float acc[16];
        const float b0 = a0[i];
#pragma unroll
        for (int tt = 0; tt < 16; ++tt) acc[tt] = b0;
        for (int jj = 0; jj < 64; jj += 4) {
            const float q0 = a2[(size_t)(jj + 0) * C_DIM + i];
            const float q1 = a2[(size_t)(jj + 1) * C_DIM + i];
            const float q2 = a2[(size_t)(jj + 2) * C_DIM + i];
            const float q3 = a2[(size_t)(jj + 3) * C_DIM + i];
#pragma unroll
            for (int tt = 0; tt < 16; ++tt) {
                float4 h4 = *(const float4*)(hsA + tt * 64 + jj);
                acc[tt] = fmaf(h4.x, q0, acc[tt]);
                acc[tt] = fmaf(h4.y, q1, acc[tt]);
                acc[tt] = fmaf(h4.z, q2, acc[tt]);
                acc[tt] = fmaf(h4.w, q3, acc[tt]);
            }
        }
#pragma unroll
        for (int tt = 0; tt < 16; ++tt) av[tt] = sigf(acc[tt]);
    }
    { // exp(w)
        float acc[16];
        const float b0 = w0[i];
#pragma unroll
        for (int tt = 0; tt < 16; ++tt) acc[tt] = b0;
        for (int jj = 0; jj < 64; jj += 4) {
            const float q0 = w2[(size_t)(jj + 0) * C_DIM + i];
            const float q1 = w2[(size_t)(jj + 1) * C_DIM + i];
            const float q2 = w2[(size_t)(jj + 2) * C_DIM + i];
            const float q3 = w2[(size_t)(jj + 3) * C_DIM + i];
#pragma unroll
            for (int tt = 0; tt < 16; ++tt) {
                float4 h4 = *(const float4*)(hsW + tt * 64 + jj);
                acc[tt] = fmaf(h4.x, q0, acc[tt]);
                acc[tt] = fmaf(h4.y, q1, acc[tt]);
                acc[tt] = fmaf(h4.z, q2, acc[tt]);
                acc[tt] = fmaf(h4.w, q3, acc[tt]);
            }
        }
#pragma unroll
        for (int tt = 0; tt < 16; ++tt)
            ew[tt] = __expf(-0.6065306597126334f * sigf(acc[tt]));
    }
    { // v mix
        float acc[16];
        const float b0 = v0[i];
#pragma unroll
        for (int tt = 0; tt < 16; ++tt) acc[tt] = b0;
        for (int jj = 0; jj < 32; jj += 4) {
            const float q0 = v2[(size_t)(jj + 0) * C_DIM + i];
            const float q1 = v2[(size_t)(jj + 1) * C_DIM + i];
            const float q2 = v2[(size_t)(jj + 2) * C_DIM + i];
            const float q3 = v2[(size_t)(jj + 3) * C_DIM + i];
#pragma unroll
            for (int tt = 0; tt < 16; ++tt) {
                float4 h4 = *(const float4*)(hsV + tt * 32 + jj);
                acc[tt] = fmaf(h4.x, q0, acc[tt]);
                acc[tt] = fmaf(h4.y, q1, acc[tt]);
                acc[tt] = fmaf(h4.z, q2, acc[tt]);
                acc[tt] = fmaf(h4.w, q3, acc[tt]);
            }
        }
#pragma unroll
        for (int tt = 0; tt < 16; ++tt) {
            const size_t gi = (size_t)(t0 + tt) * C_DIM + i;
            const float s = sigf(acc[tt]);
            const float vr = vB[gi];
            vf[tt] = vr + (v_first[gi] - vr) * s;
            vB[gi] = vf[tt];
        }
    }
    { // g
        float acc[16];
#pragma unroll
        for (int tt = 0; tt < 16; ++tt) acc[tt] = 0.f;
        for (int jj = 0; jj < 128; jj += 4) {
            const float q0 = g2[(size_t)(jj + 0) * C_DIM + i];
            const float q1 = g2[(size_t)(jj + 1) * C_DIM + i];
            const float q2 = g2[(size_t)(jj + 2) * C_DIM + i];
            const float q3 = g2[(size_t)(jj + 3) * C_DIM + i];
#pragma unroll
            for (int tt = 0; tt < 16; ++tt) {
                float4 h4 = *(const float4*)(hsG + tt * 128 + jj);
                acc[tt] = fmaf(h4.x, q0, acc[tt]);
                acc[tt] = fmaf(h4.y, q1, acc[tt]);
                acc[tt] = fmaf(h4.z, q2, acc[tt]);
                acc[tt] = fmaf(h4.w, q3, acc[tt]);
            }
        }
#pragma unroll
        for (int tt = 0; tt < 16; ++tt)
            gB[(size_t)(t0 + tt) * C_DIM + i] = acc[tt];
    }
    // k post-process + pair-composed packing
    const float kkw = k_k[i], kaw = k_a[i];
    const size_t pbase = (size_t)h * 1024 * PAIR_F;
    for (int pt = 0; pt < 8; ++pt) {
        float r_[2], e_[2], kf_[2], v_[2], aa_[2], bb_[2];
#pragma unroll
        for (int u = 0; u < 2; ++u) {
            const int tt = 2 * pt + u;
            const size_t gi = (size_t)(t0 + tt) * C_DIM + i;
            const float kraw = kB[gi];
            const float kn = kraw * kkw;
            float ss = kn * kn;
#pragma unroll
            for (int m = 1; m <= 32; m <<= 1) ss += __shfl_xor(ss, m);
            const float sc = 1.f / fmaxf(sqrtf(ss), 1e-12f);
            const float kk = kn * sc;
            const float a_ = av[tt];
            const float kf = kraw * (1.f + (a_ - 1.f) * kaw);
            kB[gi] = kf;
            r_[u] = rB[gi];
            e_[u] = ew[tt];
            kf_[u] = kf;
            v_[u] = vf[tt];
            aa_[u] = -kk;
            bb_[u] = kk * a_;
        }
        const float E   = e_[0] * e_[1];
        const float A2e = e_[0] * aa_[1];
        const float B1e = bb_[0] * e_[1];
        const float K1e = kf_[0] * e_[1];
        const float R1e = e_[0] * r_[0];
        float cba = bb_[0] * aa_[1];
        float cka = kf_[0] * aa_[1];
        float cbr = bb_[0] * r_[0];
        float ckr = kf_[0] * r_[0];
        float cbr2  = B1e * r_[1];
        float ckr2  = K1e * r_[1];
        float cb2r2 = bb_[1] * r_[1];
        float ck2r2 = kf_[1] * r_[1];
#pragma unroll
        for (int m = 1; m <= 32; m <<= 1) {
            cba += __shfl_xor(cba, m);
            cka += __shfl_xor(cka, m);
            cbr += __shfl_xor(cbr, m);
            ckr += __shfl_xor(ckr, m);
            cbr2  += __shfl_xor(cbr2, m);
            ckr2  += __shfl_xor(ckr2, m);
            cb2r2 += __shfl_xor(cb2r2, m);
            ck2r2 += __shfl_xor(ck2r2, m);
        }
        float* p = pk + pbase + (size_t)(blockIdx.y * 8 + pt) * PAIR_F;
        p[j]        = E;
        p[64 + j]   = aa_[0];
        p[128 + j]  = A2e;
        p[192 + j]  = B1e;
        p[256 + j]  = K1e;
        p[320 + j]  = bb_[1];
        p[384 + j]  = kf_[1];
        p[448 + j]  = R1e;
        p[512 + j]  = E * r_[1];          // R2e = E ⊙ R2
        p[576 + 2 * j]     = v_[0];       // vv interleaved
        p[576 + 2 * j + 1] = v_[1];
        if (j == 0) {
            p[704] = cba;  p[705] = cka;  p[706] = cbr;  p[707] = ckr;
            p[708] = cbr2; p[709] = ckr2; p[710] = cb2r2; p[711] = ck2r2;
        }
    }
}

// ---------------------------------------------------------------------------
// CHUNKED SCAN. The recurrence is affine in S: over a chunk of CPAIR pairs,
// S_end = S_start · P + C with P (64x64 homogeneous map, shared over v) and
// C (offset = scan from 0). Phases:
//   pc_scan<P>:  P_c per (chunk,head) — identity rows, v-terms off, no outputs
//   pc_scan<C>:  C_c per (chunk,head) — zero init, v-terms on, no outputs
//   combine:     serial over 16 chunks: S <- S·P_c + C_c; stores chunk starts
//   out_scan:    original scan w/ outputs, 64 pairs/block, init from S_c
// Serial length 1024 -> 64 pairs; occupancy 1 -> 16 blocks/CU.
// ---------------------------------------------------------------------------
struct PairV {
    float4 E, A1, A2e, B1e, K1e, B2, K2, R1e, R2e;
    f2_t vv;       // {v1, v2}
    float4 sc;     // cba, cka, cbr, ckr
    float4 sc2;    // cbr2, ckr2, cb2r2, ck2r2
};

static __device__ __forceinline__ float red16(float x) {
    int xi;
    xi = __builtin_amdgcn_mov_dpp(__float_as_int(x), 0x128, 0xf, 0xf, true);
    x += __int_as_float(xi);
    xi = __builtin_amdgcn_mov_dpp(__float_as_int(x), 0x124, 0xf, 0xf, true);
    x += __int_as_float(xi);
    xi = __builtin_amdgcn_mov_dpp(__float_as_int(x), 0x122, 0xf, 0xf, true);
    x += __int_as_float(xi);
    xi = __builtin_amdgcn_mov_dpp(__float_as_int(x), 0x121, 0xf, 0xf, true);
    x += __int_as_float(xi);
    return x;
}

static __device__ __forceinline__ f2_t f2bc(float s) { return (f2_t){s, s}; }
static __device__ __forceinline__ f2_t fma2(f2_t a, f2_t b, f2_t c) {
    return __builtin_elementwise_fma(a, b, c);
}
static __device__ __forceinline__ f2_t lo2(const float4& v) { return (f2_t){v.x, v.y}; }
static __device__ __forceinline__ f2_t hi2(const float4& v) { return (f2_t){v.z, v.w}; }

static __device__ __forceinline__ float dot4pk(f2_t Sl, f2_t Sh, const float4& A) {
    f2_t m = Sl * lo2(A);
    m = fma2(Sh, hi2(A), m);
    return m.x + m.y;
}

template <bool LOADV>
static __device__ __forceinline__ void slot_load(
    PairV& P, const float* __restrict__ p, int j0, int vidx)
{
    P.E   = *(const float4*)(p + j0);
    P.A1  = *(const float4*)(p + 64 + j0);
    P.A2e = *(const float4*)(p + 128 + j0);
    P.B1e = *(const float4*)(p + 192 + j0);
    P.K1e = *(const float4*)(p + 256 + j0);
    P.B2  = *(const float4*)(p + 320 + j0);
    P.K2  = *(const float4*)(p + 384 + j0);
    P.R1e = *(const float4*)(p + 448 + j0);
    P.R2e = *(const float4*)(p + 512 + j0);
    if (LOADV) P.vv = *(const f2_t*)(p + 576 + 2 * vidx);
    else       P.vv = (f2_t){0.f, 0.f};
    P.sc  = *(const float4*)(p + 704);
    P.sc2 = *(const float4*)(p + 708);
}

template <bool OUT>
static __device__ __forceinline__ void pair_compute(
    f2_t& Sl, f2_t& Sh, const PairV& P, float& o1o, float& o2o)
{
    const float u1 = red16(dot4pk(Sl, Sh, P.A1));
    const float u2 = red16(dot4pk(Sl, Sh, P.A2e));
    float o1 = 0.f, oz = 0.f;
    if (OUT) {
        o1 = red16(dot4pk(Sl, Sh, P.R1e));
        oz = red16(dot4pk(Sl, Sh, P.R2e));
    }
    const float sa1 = u1;
    const float sa2 = fmaf(P.vv.x, P.sc.y, fmaf(sa1, P.sc.x, u2));
    if (OUT) {
        o1o = fmaf(P.vv.x, P.sc.w, fmaf(sa1, P.sc.z, o1));
        o2o = fmaf(P.vv.y, P.sc2.w, fmaf(sa2, P.sc2.z,
              fmaf(P.vv.x, P.sc2.y, fmaf(sa1, P.sc2.x, oz))));
    }
    const f2_t sa1v = f2bc(sa1), sa2v = f2bc(sa2);
    const f2_t v1v = f2bc(P.vv.x), v2v = f2bc(P.vv.y);
    f2_t nl = Sl * lo2(P.E);
    f2_t nh = Sh * hi2(P.E);
    nl = fma2(sa1v, lo2(P.B1e), nl);
    nh = fma2(sa1v, hi2(P.B1e), nh);
    nl = fma2(v1v, lo2(P.K1e), nl);
    nh = fma2(v1v, hi2(P.K1e), nh);
    nl = fma2(sa2v, lo2(P.B2), nl);
    nh = fma2(sa2v, hi2(P.B2), nh);
    nl = fma2(v2v, lo2(P.K2), nl);
    nh = fma2(v2v, hi2(P.K2), nh);
    Sl = nl; Sh = nh;
}

// Phase 1: per-chunk P (PMODE) or C (!PMODE). 4096 blocks x 64 thr.
// Block -> (h = b&15, rowgroup g = (b>>4)&15, chunk c = b>>8).
template <bool PMODE>
__global__ __launch_bounds__(64, 1) void pc_scan(
    const float* __restrict__ pk, float* __restrict__ dst)
{
    const int b = blockIdx.x;
    const int h = b & 15;
    const int g = (b >> 4) & 15;
    const int c = b >> 8;
    const int l = threadIdx.x;
    const int ridx = g * 4 + (l >> 4);
    const int j0 = (l & 15) * 4;
    const float* hbase = pk + ((size_t)h * 1024 + (size_t)c * CPAIR) * PAIR_F;

    f2_t Sl, Sh;
    if (PMODE) {   // identity rows: elem (ridx, col) = (col == ridx)
        Sl = (f2_t){j0 == ridx ? 1.f : 0.f, j0 + 1 == ridx ? 1.f : 0.f};
        Sh = (f2_t){j0 + 2 == ridx ? 1.f : 0.f, j0 + 3 == ridx ? 1.f : 0.f};
    } else {
        Sl = (f2_t){0.f, 0.f};
        Sh = (f2_t){0.f, 0.f};
    }

    PairV s0, s1, s2, s3;
    slot_load<!PMODE>(s0, hbase + 0 * PAIR_F, j0, ridx);
    slot_load<!PMODE>(s1, hbase + 1 * PAIR_F, j0, ridx);
    slot_load<!PMODE>(s2, hbase + 2 * PAIR_F, j0, ridx);
    slot_load<!PMODE>(s3, hbase + 3 * PAIR_F, j0, ridx);

    float d0, d1;
    for (int i = 0; i < CPAIR - 4; i += 4) {
        const float* pl = hbase + (size_t)(i + 4) * PAIR_F;
        pair_compute<false>(Sl, Sh, s0, d0, d1);
        slot_load<!PMODE>(s0, pl + 0 * PAIR_F, j0, ridx);
        pair_compute<false>(Sl, Sh, s1, d0, d1);
        slot_load<!PMODE>(s1, pl + 1 * PAIR_F, j0, ridx);
        pair_compute<false>(Sl, Sh, s2, d0, d1);
        slot_load<!PMODE>(s2, pl + 2 * PAIR_F, j0, ridx);
        pair_compute<false>(Sl, Sh, s3, d0, d1);
        slot_load<!PMODE>(s3, pl + 3 * PAIR_F, j0, ridx);
    }
    pair_compute<false>(Sl, Sh, s0, d0, d1);
    pair_compute<false>(Sl, Sh, s1, d0, d1);
    pair_compute<false>(Sl, Sh, s2, d0, d1);
    pair_compute<false>(Sl, Sh, s3, d0, d1);

    float4 o = {Sl.x, Sl.y, Sh.x, Sh.y};
    *(float4*)(dst + (((size_t)h * NCH + c) * 64 + ridx) * 64 + j0) = o;
}

// Phase 2: serial chunk combine S <- S*P_c + C_c; stores each chunk's
// START state to Scbuf. 256 blocks (16 heads x 16 v-groups) x 64 thr.
__global__ __launch_bounds__(64) void combine(
    const float* __restrict__ Pbuf, const float* __restrict__ Cbuf,
    const float* __restrict__ init_state, float* __restrict__ Scbuf)
{
    const int b = blockIdx.x;
    const int h = b & 15;
    const int g = b >> 4;
    const int l = threadIdx.x;
    const int vl = l >> 4;
    const int vidx = g * 4 + vl;
    const int j0 = (l & 15) * 4;
    __shared__ __align__(16) float Pl[64 * 64];
    __shared__ __align__(16) float sl[4 * 64];

    float4 s = *(const float4*)(init_state + h * 4096 + vidx * 64 + j0);
    for (int c = 0; c < NCH; ++c) {
        const size_t cbase = ((size_t)h * NCH + c) * 4096;
        *(float4*)(Scbuf + cbase + (size_t)vidx * 64 + j0) = s;
        const float* Psrc = Pbuf + cbase;
#pragma unroll
        for (int t = 0; t < 16; ++t)
            *(float4*)(&Pl[t * 256 + l * 4]) = *(const float4*)(Psrc + t * 256 + l * 4);
        *(float4*)(&sl[vl * 64 + j0]) = s;
        __syncthreads();
        float4 Cv = *(const float4*)(Cbuf + cbase + (size_t)vidx * 64 + j0);
        f2_t al = {Cv.x, Cv.y}, ah = {Cv.z, Cv.w};
        for (int k = 0; k < 64; ++k) {
            const float sk = sl[vl * 64 + k];
            float4 Pr = *(const float4*)(&Pl[k * 64 + j0]);
            al = fma2(f2bc(sk), lo2(Pr), al);
            ah = fma2(f2bc(sk), hi2(Pr), ah);
        }
        s = (float4){al.x, al.y, ah.x, ah.y};
        __syncthreads();
    }
}

// Phase 3: chunk-parallel output scan, init from Scbuf. 4096 blocks x 64 thr.
__global__ __launch_bounds__(64, 1) void out_scan(
    const float* __restrict__ pk, const float* __restrict__ Scbuf,
    float* __restrict__ y)
{
    const int b = blockIdx.x;
    const int h = b & 15;
    const int g = (b >> 4) & 15;
    const int c = b >> 8;
    const int l = threadIdx.x;
    const int vidx = g * 4 + (l >> 4);
    const int j0 = (l & 15) * 4;
    const int cb = h * 64;
    const float* hbase = pk + ((size_t)h * 1024 + (size_t)c * CPAIR) * PAIR_F;

    float4 S4 = *(const float4*)(Scbuf + (((size_t)h * NCH + c) * 64 + vidx) * 64 + j0);
    f2_t Sl = {S4.x, S4.y};
    f2_t Sh = {S4.z, S4.w};

    PairV s0, s1, s2, s3;
    slot_load<true>(s0, hbase + 0 * PAIR_F, j0, vidx);
    slot_load<true>(s1, hbase + 1 * PAIR_F, j0, vidx);
    slot_load<true>(s2, hbase + 2 * PAIR_F, j0, vidx);
    slot_load<true>(s3, hbase + 3 * PAIR_F, j0, vidx);

    const bool wr = (l & 15) == 0;
    const int pi0 = c * CPAIR;
    float o0, o1, o2, o3, o4, o5, o6, o7;
    for (int i = 0; i < CPAIR - 4; i += 4) {
        const float* pl = hbase + (size_t)(i + 4) * PAIR_F;
        pair_compute<true>(Sl, Sh, s0, o0, o1);
        slot_load<true>(s0, pl + 0 * PAIR_F, j0, vidx);
        pair_compute<true>(Sl, Sh, s1, o2, o3);
        slot_load<true>(s1, pl + 1 * PAIR_F, j0, vidx);
        pair_compute<true>(Sl, Sh, s2, o4, o5);
        slot_load<true>(s2, pl + 2 * PAIR_F, j0, vidx);
        pair_compute<true>(Sl, Sh, s3, o6, o7);
        slot_load<true>(s3, pl + 3 * PAIR_F, j0, vidx);
        if (wr) {
            float* yp = y + (size_t)(2 * (pi0 + i)) * C_DIM + cb + vidx;
            yp[0]    = o0; yp[1024] = o1; yp[2048] = o2; yp[3072] = o3;
            yp[4096] = o4; yp[5120] = o5; yp[6144] = o6; yp[7168] = o7;
        }
    }
    pair_compute<true>(Sl, Sh, s0, o0, o1);
    pair_compute<true>(Sl, Sh, s1, o2, o3);
    pair_compute<true>(Sl, Sh, s2, o4, o5);
    pair_compute<true>(Sl, Sh, s3, o6, o7);
    if (wr) {
        float* yp = y + (size_t)(2 * (pi0 + CPAIR - 4)) * C_DIM + cb + vidx;
        yp[0]    = o0; yp[1024] = o1; yp[2048] = o2; yp[3072] = o3;
        yp[4096] = o4; yp[5120] = o5; yp[6144] = o6; yp[7168] = o7;
    }
}

// ---------------------------------------------------------------------------
// GroupNorm + bonus + *g ; writes bf16 (xo*g) for the final MFMA GEMM.
// ---------------------------------------------------------------------------
__global__ __launch_bounds__(256) void gn_bonus(
    const float* __restrict__ y, const float* __restrict__ rb,
    const float* __restrict__ kb, const float* __restrict__ vb,
    const float* __restrict__ gb, const float* __restrict__ r_k,
    const float* __restrict__ lnw, const float* __restrict__ lnb,
    unsigned short* __restrict__ yg)
{
    const int t = blockIdx.x, tid = threadIdx.x;
    const int c0 = tid << 2;
    const size_t base = (size_t)t * C_DIM + c0;
    float4 yv = *(const float4*)(y + base);
    float sum = yv.x + yv.y + yv.z + yv.w;
    float ss  = yv.x * yv.x + yv.y * yv.y + yv.z * yv.z + yv.w * yv.w;
    float4 rv = *(const float4*)(rb + base);
    float4 kv = *(const float4*)(kb + base);
    float4 rkv = *(const float4*)(r_k + c0);
    float dot = rv.x * kv.x * rkv.x + rv.y * kv.y * rkv.y +
                rv.z * kv.z * rkv.z + rv.w * kv.w * rkv.w;
#pragma unroll
    for (int m = 1; m <= 8; m <<= 1) {
        sum += __shfl_xor(sum, m);
        ss  += __shfl_xor(ss, m);
        dot += __shfl_xor(dot, m);
    }
    const float mu = sum * 0.015625f;
    const float var = ss * 0.015625f - mu * mu;
    const float rstd = rsqrtf(var + 0.00064f);
    float4 wv = *(const float4*)(lnw + c0);
    float4 bv = *(const float4*)(lnb + c0);
    float4 vv = *(const float4*)(vb + base);
    float4 gv = *(const float4*)(gb + base);
    ushort4 o;
    o.x = f2bf(((yv.x - mu) * rstd * wv.x + bv.x + dot * vv.x) * gv.x);
    o.y = f2bf(((yv.y - mu) * rstd * wv.y + bv.y + dot * vv.y) * gv.y);
    o.z = f2bf(((yv.z - mu) * rstd * wv.z + bv.z + dot * vv.z) * gv.z);
    o.w = f2bf(((yv.w - mu) * rstd * wv.w + bv.w + dot * vv.w) * gv.w);
    *(ushort4*)(yg + base) = o;
}

// ---------------------------------------------------------------------------
extern "C" void kernel_launch(void* const* d_in, const int* in_sizes, int n_in,
                              void* d_out, int out_size, void* d_ws, size_t ws_size,
                              hipStream_t stream)
{
    (void)in_sizes; (void)n_in; (void)out_size; (void)ws_size;
    const float* x       = (const float*)d_in[0];
    const float* v_first = (const float*)d_in[1];
    const float* x_prev  = (const float*)d_in[2];
    const float* init_st = (const float*)d_in[3];
    const float* x_r = (const float*)d_in[4];
    const float* x_w = (const float*)d_in[5];
    const float* x_k = (const float*)d_in[6];
    const float* x_v = (const float*)d_in[7];
    const float* x_a = (const float*)d_in[8];
    const float* x_g = (const float*)d_in[9];
    const float* w0  = (const float*)d_in[10];
    const float* a0  = (const float*)d_in[11];
    const float* v0  = (const float*)d_in[12];
    const float* k_k = (const float*)d_in[13];
    const float* k_a = (const float*)d_in[14];
    const float* w1  = (const float*)d_in[15];
    const float* w2  = (const float*)d_in[16];
    const float* a1  = (const float*)d_in[17];
    const float* a2  = (const float*)d_in[18];
    const float* v1  = (const float*)d_in[19];
    const float* v2  = (const float*)d_in[20];
    const float* g1  = (const float*)d_in[21];
    const float* g2  = (const float*)d_in[22];
    const float* r_k = (const float*)d_in[23];
    const float* Wr  = (const float*)d_in[24];
    const float* Wk  = (const float*)d_in[25];
    const float* Wv  = (const float*)d_in[26];
    const float* Wo  = (const float*)d_in[27];
    const float* ln_w = (const float*)d_in[28];
    const float* ln_b = (const float*)d_in[29];

    float* out = (float*)d_out;
    float* ws  = (float*)d_ws;
    const size_t NE = (size_t)T_LEN * C_DIM;   // 2M
    const size_t WE = (size_t)C_DIM * C_DIM;   // 1M
    float* rB  = ws;
    float* kB  = ws + NE;
    float* vB  = ws + 2 * NE;
    float* gB  = ws + 3 * NE;
    float* hwB = ws + 4 * NE;                  // T*64
    float* haB = hwB + (size_t)T_LEN * 64;
    float* hvB = haB + (size_t)T_LEN * 64;
    float* hgB = hvB + (size_t)T_LEN * 32;     // h region < NE/2
    float* pk  = ws + 4 * NE + NE / 2;         // 6*NE floats (16*1024*768)
    unsigned short* b16 = (unsigned short*)(ws + 10 * NE + NE / 2);
    unsigned short* xr16 = b16;                // NE shorts
    unsigned short* xk16 = b16 + NE;
    unsigned short* xv16 = b16 + 2 * NE;
    unsigned short* Wr16 = b16 + 3 * NE;       // 4*WE shorts
    unsigned short* Wk16 = Wr16 + WE;
    unsigned short* Wv16 = Wr16 + 2 * WE;
    unsigned short* Wo16 = Wr16 + 3 * WE;
    unsigned short* yg16 = b16 + 3 * NE + 4 * WE;  // NE shorts
    unsigned short* lw16 = yg16 + NE;              // 320K shorts (LoRA weights)
    // xw/xa/xg bf16 live in the pk region (pk written later by lora2f)
    unsigned short* xw16 = (unsigned short*)pk;
    unsigned short* xa16 = xw16 + NE;
    unsigned short* xg16 = xw16 + 2 * NE;
    // yB aliases xr16/xk16 (consumed by gemms before the scan writes it)
    float* yB = (float*)xr16;
    // Chunk-scan buffers, all aliased into regions dead by scan time:
    //   Pbuf  <- xv16   (NE shorts = 1M floats; dead after gemm3/lora1m)
    //   Cbuf  <- Wr16+Wk16 (2*WE shorts = 1M floats; dead after gemm3)
    //   Scbuf <- yg16   (NE shorts = 1M floats; gn_bonus writes it LATER)
    float* Pbuf  = (float*)xv16;   // 16h x 16c x 64 x 64
    float* Cbuf  = (float*)Wr16;
    float* Scbuf = (float*)yg16;

    wcvtall<<<4384, 256, 0, stream>>>(Wr, Wk, Wv, Wo, w1, a1, v1, g1,
                                      Wr16, lw16);
    xcvt<<<T_LEN, 256, 0, stream>>>(x, x_prev, x_r, x_k, x_v, x_w, x_a, x_g,
                                    xr16, xk16, xv16, xw16, xa16, xg16);

    gemm_bf16_3<<<dim3(16, 16, 3), 256, 0, stream>>>(
        xr16, xk16, xv16, Wr16, Wk16, Wv16, rB, kB, vB);

    lora1m<<<dim3(2, 16, 4), 256, 0, stream>>>(
        xw16, xa16, xv16, xg16, lw16, hwB, haB, hvB, hgB);

    lora2f<<<dim3(4, 128), 256, 0, stream>>>(
        hwB, haB, hvB, hgB, w2, a2, v2, g2, w0, a0, v0,
        k_k, k_a, v_first, rB, kB, vB, gB, pk);

    pc_scan<true><<<4096, 64, 0, stream>>>(pk, Pbuf);
    pc_scan<false><<<4096, 64, 0, stream>>>(pk, Cbuf);
    combine<<<256, 64, 0, stream>>>(Pbuf, Cbuf, init_st, Scbuf);
    out_scan<<<4096, 64, 0, stream>>>(pk, Scbuf, yB);

    gn_bonus<<<T_LEN, 256, 0, stream>>>(yB, rB, kB, vB, gB, r_k, ln_w, ln_b, yg16);
    gemm_bf16<<<dim3(16, 16), 256, 0, stream>>>(yg16, Wo16, out);
}

// Round 6
// 427.298 us; speedup vs baseline: 1.2060x; 1.2060x over previous
//
#include <hip/hip_runtime.h>

#define T_LEN 2048
#define C_DIM 1024
#define PAIR_F 768          // floats per (head, step-pair) packet
#define NCH 16              // chunks
#define CPAIR 64            // pairs per chunk (NCH*CPAIR = 1024)

#define AS1 __attribute__((address_space(1)))
#define AS3 __attribute__((address_space(3)))

typedef __attribute__((ext_vector_type(8))) short bf8_t;
typedef __attribute__((ext_vector_type(4))) float f4_t;
typedef __attribute__((ext_vector_type(2))) float f2_t;

static __device__ __forceinline__ float sigf(float x) {
    return 1.f / (1.f + __expf(-x));
}
static __device__ __forceinline__ unsigned short f2bf(float f) {
    unsigned u = __float_as_uint(f);
    u += 0x7fff + ((u >> 16) & 1);
    return (unsigned short)(u >> 16);
}

// ---------------------------------------------------------------------------
// Convert the four 1024x1024 fp32 weights into one bf16 block (1M strides),
// plus the transposed LoRA stage-1 weights (blocks 4096..4383).
// ---------------------------------------------------------------------------
__global__ __launch_bounds__(256) void wcvtall(
    const float* __restrict__ Wr, const float* __restrict__ Wk,
    const float* __restrict__ Wv, const float* __restrict__ Wo,
    const float* __restrict__ w1, const float* __restrict__ a1,
    const float* __restrict__ v1, const float* __restrict__ g1,
    unsigned short* __restrict__ dst, unsigned short* __restrict__ lw16)
{
    const int b = blockIdx.x;
    if (b < 4096) {
        const size_t idx = ((size_t)b * 256 + threadIdx.x) * 4;
        const int sel = (int)(idx >> 20);
        const float* src = sel == 0 ? Wr : sel == 1 ? Wk : sel == 2 ? Wv : Wo;
        float4 v = *(const float4*)(src + (idx & 0xFFFFF));
        ushort4 o = {f2bf(v.x), f2bf(v.y), f2bf(v.z), f2bf(v.w)};
        *(ushort4*)(dst + idx) = o;
        return;
    }
    const int row = b - 4096;         // 0..287
    const float* src; int Kh, i; unsigned short* dl;
    if (row < 64)       { src = w1; Kh = 64;  i = row;       dl = lw16 + (size_t)row * 1024; }
    else if (row < 128) { src = a1; Kh = 64;  i = row - 64;  dl = lw16 + (size_t)row * 1024; }
    else if (row < 160) { src = v1; Kh = 32;  i = row - 128; dl = lw16 + (size_t)(row - 128 + 128) * 1024; }
    else                { src = g1; Kh = 128; i = row - 160; dl = lw16 + (size_t)(row - 160 + 192) * 1024; }
    const int c0 = threadIdx.x * 4;
#pragma unroll
    for (int u = 0; u < 4; ++u)
        dl[c0 + u] = f2bf(src[(size_t)(c0 + u) * Kh + i]);
}

// ---------------------------------------------------------------------------
// Token-shift mix -> bf16 A-matrices for r/k/v projections and w/a/g LoRA.
// ---------------------------------------------------------------------------
__global__ __launch_bounds__(256) void xcvt(
    const float* __restrict__ x, const float* __restrict__ xprev,
    const float* __restrict__ x_r, const float* __restrict__ x_k,
    const float* __restrict__ x_v, const float* __restrict__ x_w,
    const float* __restrict__ x_a, const float* __restrict__ x_g,
    unsigned short* __restrict__ xr16, unsigned short* __restrict__ xk16,
    unsigned short* __restrict__ xv16, unsigned short* __restrict__ xw16,
    unsigned short* __restrict__ xa16, unsigned short* __restrict__ xg16)
{
    const int t = blockIdx.x;
    const int c0 = threadIdx.x * 4;
    const size_t base = (size_t)t * C_DIM + c0;
    float4 xv = *(const float4*)(x + base);
    float4 pv = (t == 0) ? *(const float4*)(xprev + c0)
                         : *(const float4*)(x + base - C_DIM);
    float4 dx = {pv.x - xv.x, pv.y - xv.y, pv.z - xv.z, pv.w - xv.w};
#define MIXOUT(mixp, dstp)                                                    \
    {                                                                          \
        float4 mv = *(const float4*)(mixp + c0);                               \
        ushort4 o = {f2bf(xv.x + dx.x * mv.x), f2bf(xv.y + dx.y * mv.y),       \
                     f2bf(xv.z + dx.z * mv.z), f2bf(xv.w + dx.w * mv.w)};      \
        *(ushort4*)(dstp + base) = o;                                          \
    }
    MIXOUT(x_r, xr16) MIXOUT(x_k, xk16) MIXOUT(x_v, xv16)
    MIXOUT(x_w, xw16) MIXOUT(x_a, xa16) MIXOUT(x_g, xg16)
#undef MIXOUT
}

// ---------------------------------------------------------------------------
// bf16 MFMA NT GEMM core: out[t,i] = sum_c A[t,c]*W[i,c], fp32 accumulate.
// ---------------------------------------------------------------------------
static __device__ __forceinline__ void gemm_core(
    const unsigned short* __restrict__ A, const unsigned short* __restrict__ W,
    float* __restrict__ out)
{
    __shared__ unsigned short Ab[2][128 * 32];
    __shared__ unsigned short Bb[2][64 * 32];
    const int tid = threadIdx.x;
    const int lane = tid & 63;
    const int w = tid >> 6;
    const int n0 = blockIdx.x * 64;
    const int t0 = blockIdx.y * 128;
    const int wm = (w & 1) * 64;
    const int wn = (w >> 1) * 32;
    const int srow = lane >> 2;
    const int scol = (lane & 3) * 8;

    f4_t acc[4][2];
#pragma unroll
    for (int i = 0; i < 4; ++i)
#pragma unroll
        for (int j = 0; j < 2; ++j)
            acc[i][j] = (f4_t){0.f, 0.f, 0.f, 0.f};

#pragma unroll
    for (int s = 0; s < 2; ++s) {
        const int i = 2 * w + s;
        __builtin_amdgcn_global_load_lds(
            (const AS1 unsigned int*)(A + (size_t)(t0 + i * 16 + srow) * 1024 + scol),
            (AS3 unsigned int*)(&Ab[0][i * 512 + lane * 8]), 16, 0, 0);
    }
    __builtin_amdgcn_global_load_lds(
        (const AS1 unsigned int*)(W + (size_t)(n0 + w * 16 + srow) * 1024 + scol),
        (AS3 unsigned int*)(&Bb[0][w * 512 + lane * 8]), 16, 0, 0);

    const int mrow = lane & 15;
    const int kq = (lane >> 4) * 8;
    for (int k0 = 0; k0 < 1024; k0 += 32) {
        const int cur = (k0 >> 5) & 1, nxt = cur ^ 1;
        __syncthreads();
        if (k0 + 32 < 1024) {
            const int k1 = k0 + 32;
#pragma unroll
            for (int s = 0; s < 2; ++s) {
                const int i = 2 * w + s;
                __builtin_amdgcn_global_load_lds(
                    (const AS1 unsigned int*)(A + (size_t)(t0 + i * 16 + srow) * 1024 + k1 + scol),
                    (AS3 unsigned int*)(&Ab[nxt][i * 512 + lane * 8]), 16, 0, 0);
            }
            __builtin_amdgcn_global_load_lds(
                (const AS1 unsigned int*)(W + (size_t)(n0 + w * 16 + srow) * 1024 + k1 + scol),
                (AS3 unsigned int*)(&Bb[nxt][w * 512 + lane * 8]), 16, 0, 0);
        }
        bf8_t af[4], bfr[2];
#pragma unroll
        for (int i = 0; i < 4; ++i)
            af[i] = *(const bf8_t*)(&Ab[cur][(wm + 16 * i + mrow) * 32 + kq]);
#pragma unroll
        for (int j = 0; j < 2; ++j)
            bfr[j] = *(const bf8_t*)(&Bb[cur][(wn + 16 * j + mrow) * 32 + kq]);
#pragma unroll
        for (int i = 0; i < 4; ++i)
#pragma unroll
            for (int j = 0; j < 2; ++j)
                acc[i][j] = __builtin_amdgcn_mfma_f32_16x16x32_bf16(
                    af[i], bfr[j], acc[i][j], 0, 0, 0);
    }
    const int crow = (lane >> 4) * 4;
    const int ccol = lane & 15;
#pragma unroll
    for (int i = 0; i < 4; ++i)
#pragma unroll
        for (int j = 0; j < 2; ++j)
#pragma unroll
            for (int u = 0; u < 4; ++u)
                out[(size_t)(t0 + wm + 16 * i + crow + u) * 1024
                    + n0 + wn + 16 * j + ccol] = acc[i][j][u];
}

__global__ __launch_bounds__(256) void gemm_bf16_3(
    const unsigned short* __restrict__ xr, const unsigned short* __restrict__ xk,
    const unsigned short* __restrict__ xv,
    const unsigned short* __restrict__ Wr, const unsigned short* __restrict__ Wk,
    const unsigned short* __restrict__ Wv,
    float* __restrict__ rB, float* __restrict__ kB, float* __restrict__ vB)
{
    const int z = blockIdx.z;
    const unsigned short* A = z == 0 ? xr : z == 1 ? xk : xv;
    const unsigned short* W = z == 0 ? Wr : z == 1 ? Wk : Wv;
    float* out = z == 0 ? rB : z == 1 ? kB : vB;
    gemm_core(A, W, out);
}

__global__ __launch_bounds__(256) void gemm_bf16(
    const unsigned short* __restrict__ A, const unsigned short* __restrict__ W,
    float* __restrict__ out)
{
    gemm_core(A, W, out);
}

// ---------------------------------------------------------------------------
// Fused LoRA stage-1 via MFMA: z = 0:w(tanh,N=64) 1:a(N=64) 2:v(N=32) 3:g(sig,N=128)
// ---------------------------------------------------------------------------
__global__ __launch_bounds__(256) void lora1m(
    const unsigned short* __restrict__ xw, const unsigned short* __restrict__ xa,
    const unsigned short* __restrict__ xv, const unsigned short* __restrict__ xg,
    const unsigned short* __restrict__ lw16,
    float* __restrict__ hw, float* __restrict__ ha, float* __restrict__ hv,
    float* __restrict__ hg)
{
    const int z = blockIdx.z;
    const unsigned short* A = z == 0 ? xw : z == 1 ? xa : z == 2 ? xv : xg;
    const unsigned short* W = lw16 + (size_t)(z == 0 ? 0 : z == 1 ? 64 : z == 2 ? 128 : 192) * 1024;
    float* out = z == 0 ? hw : z == 1 ? ha : z == 2 ? hv : hg;
    const int N  = z == 3 ? 128 : z == 2 ? 32 : 64;
    const int Ns = z == 3 ? 128 : 64;
    const int n0 = blockIdx.x * 64;
    if (n0 >= Ns) return;

    __shared__ unsigned short Ab[2][128 * 32];
    __shared__ unsigned short Bb[2][64 * 32];
    const int tid = threadIdx.x;
    const int lane = tid & 63;
    const int w = tid >> 6;
    const int t0 = blockIdx.y * 128;
    const int wm = (w & 1) * 64;
    const int wn = (w >> 1) * 32;
    const int srow = lane >> 2;
    const int scol = (lane & 3) * 8;

    f4_t acc[4][2];
#pragma unroll
    for (int i = 0; i < 4; ++i)
#pragma unroll
        for (int j = 0; j < 2; ++j)
            acc[i][j] = (f4_t){0.f, 0.f, 0.f, 0.f};

#pragma unroll
    for (int s = 0; s < 2; ++s) {
        const int i = 2 * w + s;
        __builtin_amdgcn_global_load_lds(
            (const AS1 unsigned int*)(A + (size_t)(t0 + i * 16 + srow) * 1024 + scol),
            (AS3 unsigned int*)(&Ab[0][i * 512 + lane * 8]), 16, 0, 0);
    }
    __builtin_amdgcn_global_load_lds(
        (const AS1 unsigned int*)(W + (size_t)(n0 + w * 16 + srow) * 1024 + scol),
        (AS3 unsigned int*)(&Bb[0][w * 512 + lane * 8]), 16, 0, 0);

    const int mrow = lane & 15;
    const int kq = (lane >> 4) * 8;
    for (int k0 = 0; k0 < 1024; k0 += 32) {
        const int cur = (k0 >> 5) & 1, nxt = cur ^ 1;
        __syncthreads();
        if (k0 + 32 < 1024) {
            const int k1 = k0 + 32;
#pragma unroll
            for (int s = 0; s < 2; ++s) {
                const int i = 2 * w + s;
                __builtin_amdgcn_global_load_lds(
                    (const AS1 unsigned int*)(A + (size_t)(t0 + i * 16 + srow) * 1024 + k1 + scol),
                    (AS3 unsigned int*)(&Ab[nxt][i * 512 + lane * 8]), 16, 0, 0);
            }
            __builtin_amdgcn_global_load_lds(
                (const AS1 unsigned int*)(W + (size_t)(n0 + w * 16 + srow) * 1024 + k1 + scol),
                (AS3 unsigned int*)(&Bb[nxt][w * 512 + lane * 8]), 16, 0, 0);
        }
        bf8_t af[4], bfr[2];
#pragma unroll
        for (int i = 0; i < 4; ++i)
            af[i] = *(const bf8_t*)(&Ab[cur][(wm + 16 * i + mrow) * 32 + kq]);
#pragma unroll
        for (int j = 0; j < 2; ++j)
            bfr[j] = *(const bf8_t*)(&Bb[cur][(wn + 16 * j + mrow) * 32 + kq]);
#pragma unroll
        for (int i = 0; i < 4; ++i)
#pragma unroll
            for (int j = 0; j < 2; ++j)
                acc[i][j] = __builtin_amdgcn_mfma_f32_16x16x32_bf16(
                    af[i], bfr[j], acc[i][j], 0, 0, 0);
    }
    const int crow = (lane >> 4) * 4;
    const int ccol = lane & 15;
#pragma unroll
    for (int i = 0; i < 4; ++i)
#pragma unroll
        for (int j = 0; j < 2; ++j) {
            const int col = n0 + wn + 16 * j + ccol;
            if (col < N) {
#pragma unroll
                for (int u = 0; u < 4; ++u) {
                    float vv = acc[i][j][u];
                    if (z == 0) vv = tanhf(vv);
                    else if (z == 3) vv = sigf(vv);
                    out[(size_t)(t0 + wm + 16 * i + crow + u) * N + col] = vv;
                }
            }
        }
}

// ---------------------------------------------------------------------------
// Fused LoRA-2 (w/a/v/g) + k post-process + PAIR-COMPOSED packet packing.
// Packet layout (768 floats) unchanged from r4.
// ---------------------------------------------------------------------------
__global__ __launch_bounds__(256) void lora2f(
    const float* __restrict__ hwB, const float* __restrict__ haB,
    const float* __restrict__ hvB, const float* __restrict__ hgB,
    const float* __restrict__ w2, const float* __restrict__ a2,
    const float* __restrict__ v2, const float* __restrict__ g2,
    const float* __restrict__ w0, const float* __restrict__ a0,
    const float* __restrict__ v0,
    const float* __restrict__ k_k, const float* __restrict__ k_a,
    const float* __restrict__ v_first, const float* __restrict__ rB,
    float* __restrict__ kB, float* __restrict__ vB, float* __restrict__ gB,
    float* __restrict__ pk)
{
    __shared__ __align__(16) float hsW[16 * 64], hsA[16 * 64];
    __shared__ __align__(16) float hsV[16 * 32], hsG[16 * 128];
    const int tid = threadIdx.x;
    const int t0 = blockIdx.y * 16;
    const int i  = blockIdx.x * 256 + tid;
    const int h  = i >> 6;
    const int j  = i & 63;
    for (int idx = tid; idx < 16 * 64; idx += 256) {
        hsW[idx] = hwB[(size_t)t0 * 64 + idx];
        hsA[idx] = haB[(size_t)t0 * 64 + idx];
    }
    for (int idx = tid; idx < 16 * 32; idx += 256)
        hsV[idx] = hvB[(size_t)t0 * 32 + idx];
    for (int idx = tid; idx < 16 * 128; idx += 256)
        hsG[idx] = hgB[(size_t)t0 * 128 + idx];
    __syncthreads();

    float av[16], ew[16], vf[16];
    { // a = sigmoid(a0 + ha@a2)
        float acc[16];
        const float b0 = a0[i];
#pragma unroll
        for (int tt = 0; tt < 16; ++tt) acc[tt] = b0;
        for (int jj = 0; jj < 64; jj += 4) {
            const float q0 = a2[(size_t)(jj + 0) * C_DIM + i];
            const float q1 = a2[(size_t)(jj + 1) * C_DIM + i];
            const float q2 = a2[(size_t)(jj + 2) * C_DIM + i];
            const float q3 = a2[(size_t)(jj + 3) * C_DIM + i];
#pragma unroll
            for (int tt = 0; tt < 16; ++tt) {
                float4 h4 = *(const float4*)(hsA + tt * 64 + jj);
                acc[tt] = fmaf(h4.x, q0, acc[tt]);
                acc[tt] = fmaf(h4.y, q1, acc[tt]);
                acc[tt] = fmaf(h4.z, q2, acc[tt]);
                acc[tt] = fmaf(h4.w, q3, acc[tt]);
            }
        }
#pragma unroll
        for (int tt = 0; tt < 16; ++tt) av[tt] = sigf(acc[tt]);
    }
    { // exp(w)
        float acc[16];
        const float b0 = w0[i];
#pragma unroll
        for (int tt = 0; tt < 16; ++tt) acc[tt] = b0;
        for (int jj = 0; jj < 64; jj += 4) {
            const float q0 = w2[(size_t)(jj + 0) * C_DIM + i];
            const float q1 = w2[(size_t)(jj + 1) * C_DIM + i];
            const float q2 = w2[(size_t)(jj + 2) * C_DIM + i];
            const float q3 = w2[(size_t)(jj + 3) * C_DIM + i];
#pragma unroll
            for (int tt = 0; tt < 16; ++tt) {
                float4 h4 = *(const float4*)(hsW + tt * 64 + jj);
                acc[tt] = fmaf(h4.x, q0, acc[tt]);
                acc[tt] = fmaf(h4.y, q1, acc[tt]);
                acc[tt] = fmaf(h4.z, q2, acc[tt]);
                acc[tt] = fmaf(h4.w, q3, acc[tt]);
            }
        }
#pragma unroll
        for (int tt = 0; tt < 16; ++tt)
            ew[tt] = __expf(-0.6065306597126334f * sigf(acc[tt]));
    }
    { // v mix
        float acc[16];
        const float b0 = v0[i];
#pragma unroll
        for (int tt = 0; tt < 16; ++tt) acc[tt] = b0;
        for (int jj = 0; jj < 32; jj += 4) {
            const float q0 = v2[(size_t)(jj + 0) * C_DIM + i];
            const float q1 = v2[(size_t)(jj + 1) * C_DIM + i];
            const float q2 = v2[(size_t)(jj + 2) * C_DIM + i];
            const float q3 = v2[(size_t)(jj + 3) * C_DIM + i];
#pragma unroll
            for (int tt = 0; tt < 16; ++tt) {
                float4 h4 = *(const float4*)(hsV + tt * 32 + jj);
                acc[tt] = fmaf(h4.x, q0, acc[tt]);
                acc[tt] = fmaf(h4.y, q1, acc[tt]);
                acc[tt] = fmaf(h4.z, q2, acc[tt]);
                acc[tt] = fmaf(h4.w, q3, acc[tt]);
            }
        }
#pragma unroll
        for (int tt = 0; tt < 16; ++tt) {
            const size_t gi = (size_t)(t0 + tt) * C_DIM + i;
            const float s = sigf(acc[tt]);
            const float vr = vB[gi];
            vf[tt] = vr + (v_first[gi] - vr) * s;
            vB[gi] = vf[tt];
        }
    }
    { // g
        float acc[16];
#pragma unroll
        for (int tt = 0; tt < 16; ++tt) acc[tt] = 0.f;
        for (int jj = 0; jj < 128; jj += 4) {
            const float q0 = g2[(size_t)(jj + 0) * C_DIM + i];
            const float q1 = g2[(size_t)(jj + 1) * C_DIM + i];
            const float q2 = g2[(size_t)(jj + 2) * C_DIM + i];
            const float q3 = g2[(size_t)(jj + 3) * C_DIM + i];
#pragma unroll
            for (int tt = 0; tt < 16; ++tt) {
                float4 h4 = *(const float4*)(hsG + tt * 128 + jj);
                acc[tt] = fmaf(h4.x, q0, acc[tt]);
                acc[tt] = fmaf(h4.y, q1, acc[tt]);
                acc[tt] = fmaf(h4.z, q2, acc[tt]);
                acc[tt] = fmaf(h4.w, q3, acc[tt]);
            }
        }
#pragma unroll
        for (int tt = 0; tt < 16; ++tt)
            gB[(size_t)(t0 + tt) * C_DIM + i] = acc[tt];
    }
    // k post-process + pair-composed packing
    const float kkw = k_k[i], kaw = k_a[i];
    const size_t pbase = (size_t)h * 1024 * PAIR_F;
    for (int pt = 0; pt < 8; ++pt) {
        float r_[2], e_[2], kf_[2], v_[2], aa_[2], bb_[2];
#pragma unroll
        for (int u = 0; u < 2; ++u) {
            const int tt = 2 * pt + u;
            const size_t gi = (size_t)(t0 + tt) * C_DIM + i;
            const float kraw = kB[gi];
            const float kn = kraw * kkw;
            float ss = kn * kn;
#pragma unroll
            for (int m = 1; m <= 32; m <<= 1) ss += __shfl_xor(ss, m);
            const float sc = 1.f / fmaxf(sqrtf(ss), 1e-12f);
            const float kk = kn * sc;
            const float a_ = av[tt];
            const float kf = kraw * (1.f + (a_ - 1.f) * kaw);
            kB[gi] = kf;
            r_[u] = rB[gi];
            e_[u] = ew[tt];
            kf_[u] = kf;
            v_[u] = vf[tt];
            aa_[u] = -kk;
            bb_[u] = kk * a_;
        }
        const float E   = e_[0] * e_[1];
        const float A2e = e_[0] * aa_[1];
        const float B1e = bb_[0] * e_[1];
        const float K1e = kf_[0] * e_[1];
        const float R1e = e_[0] * r_[0];
        float cba = bb_[0] * aa_[1];
        float cka = kf_[0] * aa_[1];
        float cbr = bb_[0] * r_[0];
        float ckr = kf_[0] * r_[0];
        float cbr2  = B1e * r_[1];
        float ckr2  = K1e * r_[1];
        float cb2r2 = bb_[1] * r_[1];
        float ck2r2 = kf_[1] * r_[1];
#pragma unroll
        for (int m = 1; m <= 32; m <<= 1) {
            cba += __shfl_xor(cba, m);
            cka += __shfl_xor(cka, m);
            cbr += __shfl_xor(cbr, m);
            ckr += __shfl_xor(ckr, m);
            cbr2  += __shfl_xor(cbr2, m);
            ckr2  += __shfl_xor(ckr2, m);
            cb2r2 += __shfl_xor(cb2r2, m);
            ck2r2 += __shfl_xor(ck2r2, m);
        }
        float* p = pk + pbase + (size_t)(blockIdx.y * 8 + pt) * PAIR_F;
        p[j]        = E;
        p[64 + j]   = aa_[0];
        p[128 + j]  = A2e;
        p[192 + j]  = B1e;
        p[256 + j]  = K1e;
        p[320 + j]  = bb_[1];
        p[384 + j]  = kf_[1];
        p[448 + j]  = R1e;
        p[512 + j]  = E * r_[1];          // R2e = E ⊙ R2
        p[576 + 2 * j]     = v_[0];       // vv interleaved
        p[576 + 2 * j + 1] = v_[1];
        if (j == 0) {
            p[704] = cba;  p[705] = cka;  p[706] = cbr;  p[707] = ckr;
            p[708] = cbr2; p[709] = ckr2; p[710] = cb2r2; p[711] = ck2r2;
        }
    }
}

// ---------------------------------------------------------------------------
// CHUNKED SCAN, r6: 4 ROWS PER LANE-GROUP (4x arithmetic intensity) and
// P+C fused in one kernel (shared loads). Per (h,c): 4 waves instead of 32
// -> pk traffic 2.3GB -> 384MB total. Blocks 1024 x 64thr per phase.
// r5 diagnosis: phases were L2/L3-BW bound at ~8.3 TB/s from 16x cross-block
// + 4x intra-wave read duplication; VALU issue was only 25% of time.
// ---------------------------------------------------------------------------
static __device__ __forceinline__ float red16(float x) {
    int xi;
    xi = __builtin_amdgcn_mov_dpp(__float_as_int(x), 0x128, 0xf, 0xf, true);
    x += __int_as_float(xi);
    xi = __builtin_amdgcn_mov_dpp(__float_as_int(x), 0x124, 0xf, 0xf, true);
    x += __int_as_float(xi);
    xi = __builtin_amdgcn_mov_dpp(__float_as_int(x), 0x122, 0xf, 0xf, true);
    x += __int_as_float(xi);
    xi = __builtin_amdgcn_mov_dpp(__float_as_int(x), 0x121, 0xf, 0xf, true);
    x += __int_as_float(xi);
    return x;
}

static __device__ __forceinline__ f2_t f2bc(float s) { return (f2_t){s, s}; }
static __device__ __forceinline__ f2_t fma2(f2_t a, f2_t b, f2_t c) {
    return __builtin_elementwise_fma(a, b, c);
}
static __device__ __forceinline__ f2_t lo2(const float4& v) { return (f2_t){v.x, v.y}; }
static __device__ __forceinline__ f2_t hi2(const float4& v) { return (f2_t){v.z, v.w}; }

static __device__ __forceinline__ float dot4pk(f2_t Sl, f2_t Sh, const float4& A) {
    f2_t m = Sl * lo2(A);
    m = fma2(Sh, hi2(A), m);
    return m.x + m.y;
}

// ---- fused P+C chunk kernel -----------------------------------------------
struct SlotPC {
    float4 E, A1, A2e, B1e, K1e, B2, K2;
    float4 vva, vvb;   // {v1,v2} for rows rbase..rbase+3
    float4 sc;         // cba, cka, cbr, ckr (only x,y used here)
};

static __device__ __forceinline__ void slot_load_pc(
    SlotPC& K, const float* __restrict__ p, int j0, int rb2)
{
    K.E   = *(const float4*)(p + j0);
    K.A1  = *(const float4*)(p + 64 + j0);
    K.A2e = *(const float4*)(p + 128 + j0);
    K.B1e = *(const float4*)(p + 192 + j0);
    K.K1e = *(const float4*)(p + 256 + j0);
    K.B2  = *(const float4*)(p + 320 + j0);
    K.K2  = *(const float4*)(p + 384 + j0);
    K.vva = *(const float4*)(p + 576 + rb2);
    K.vvb = *(const float4*)(p + 576 + rb2 + 4);
    K.sc  = *(const float4*)(p + 704);
}

static __device__ __forceinline__ void pair_pc(
    f2_t* PSl, f2_t* PSh, f2_t* CSl, f2_t* CSh, const SlotPC& K)
{
    float pu1[4], pu2[4], cu1[4], cu2[4];
#pragma unroll
    for (int r = 0; r < 4; ++r) {
        pu1[r] = red16(dot4pk(PSl[r], PSh[r], K.A1));
        pu2[r] = red16(dot4pk(PSl[r], PSh[r], K.A2e));
        cu1[r] = red16(dot4pk(CSl[r], CSh[r], K.A1));
        cu2[r] = red16(dot4pk(CSl[r], CSh[r], K.A2e));
    }
#pragma unroll
    for (int r = 0; r < 4; ++r) {
        { // P update: v-terms exactly zero -> dropped (bitwise identical)
            const float sa1 = pu1[r];
            const float sa2 = fmaf(sa1, K.sc.x, pu2[r]);
            const f2_t sa1v = f2bc(sa1), sa2v = f2bc(sa2);
            f2_t nl = PSl[r] * lo2(K.E), nh = PSh[r] * hi2(K.E);
            nl = fma2(sa1v, lo2(K.B1e), nl); nh = fma2(sa1v, hi2(K.B1e), nh);
            nl = fma2(sa2v, lo2(K.B2), nl);  nh = fma2(sa2v, hi2(K.B2), nh);
            PSl[r] = nl; PSh[r] = nh;
        }
        { // C update: full recurrence from zero init
            const float v1 = r == 0 ? K.vva.x : r == 1 ? K.vva.z
                           : r == 2 ? K.vvb.x : K.vvb.z;
            const float v2 = r == 0 ? K.vva.y : r == 1 ? K.vva.w
                           : r == 2 ? K.vvb.y : K.vvb.w;
            const float sa1 = cu1[r];
            const float sa2 = fmaf(v1, K.sc.y, fmaf(sa1, K.sc.x, cu2[r]));
            const f2_t sa1v = f2bc(sa1), sa2v = f2bc(sa2);
            const f2_t v1v = f2bc(v1), v2v = f2bc(v2);
            f2_t nl = CSl[r] * lo2(K.E), nh = CSh[r] * hi2(K.E);
            nl = fma2(sa1v, lo2(K.B1e), nl); nh = fma2(sa1v, hi2(K.B1e), nh);
            nl = fma2(v1v, lo2(K.K1e), nl);  nh = fma2(v1v, hi2(K.K1e), nh);
            nl = fma2(sa2v, lo2(K.B2), nl);  nh = fma2(sa2v, hi2(K.B2), nh);
            nl = fma2(v2v, lo2(K.K2), nl);   nh = fma2(v2v, hi2(K.K2), nh);
            CSl[r] = nl; CSh[r] = nh;
        }
    }
}

// grid: b = h + 16*w + 64*c  (w stride 16 => same (h,c) on same XCD mod 8)
__global__ __launch_bounds__(64, 1) void pc_fused(
    const float* __restrict__ pk, float* __restrict__ Pbuf,
    float* __restrict__ Cbuf)
{
    const int b = blockIdx.x;
    const int h = b & 15;
    const int w = (b >> 4) & 3;
    const int c = b >> 6;
    const int l = threadIdx.x;
    const int q = l >> 4;
    const int j0 = (l & 15) * 4;
    const int rbase = w * 16 + q * 4;
    const int rb2 = 2 * rbase;
    const float* hbase = pk + ((size_t)h * 1024 + (size_t)c * CPAIR) * PAIR_F;

    f2_t PSl[4], PSh[4], CSl[4], CSh[4];
#pragma unroll
    for (int r = 0; r < 4; ++r) {
        const int row = rbase + r;
        PSl[r] = (f2_t){j0 == row ? 1.f : 0.f, j0 + 1 == row ? 1.f : 0.f};
        PSh[r] = (f2_t){j0 + 2 == row ? 1.f : 0.f, j0 + 3 == row ? 1.f : 0.f};
        CSl[r] = (f2_t){0.f, 0.f};
        CSh[r] = (f2_t){0.f, 0.f};
    }

    SlotPC s0, s1, s2, s3;
    slot_load_pc(s0, hbase + 0 * PAIR_F, j0, rb2);
    slot_load_pc(s1, hbase + 1 * PAIR_F, j0, rb2);
    slot_load_pc(s2, hbase + 2 * PAIR_F, j0, rb2);
    slot_load_pc(s3, hbase + 3 * PAIR_F, j0, rb2);

    for (int i = 0; i < CPAIR - 4; i += 4) {
        const float* pl = hbase + (size_t)(i + 4) * PAIR_F;
        pair_pc(PSl, PSh, CSl, CSh, s0); slot_load_pc(s0, pl + 0 * PAIR_F, j0, rb2);
        pair_pc(PSl, PSh, CSl, CSh, s1); slot_load_pc(s1, pl + 1 * PAIR_F, j0, rb2);
        pair_pc(PSl, PSh, CSl, CSh, s2); slot_load_pc(s2, pl + 2 * PAIR_F, j0, rb2);
        pair_pc(PSl, PSh, CSl, CSh, s3); slot_load_pc(s3, pl + 3 * PAIR_F, j0, rb2);
    }
    pair_pc(PSl, PSh, CSl, CSh, s0);
    pair_pc(PSl, PSh, CSl, CSh, s1);
    pair_pc(PSl, PSh, CSl, CSh, s2);
    pair_pc(PSl, PSh, CSl, CSh, s3);

    const size_t cb64 = ((size_t)h * NCH + c) * 4096;
#pragma unroll
    for (int r = 0; r < 4; ++r) {
        *(float4*)(Pbuf + cb64 + (size_t)(rbase + r) * 64 + j0) =
            (float4){PSl[r].x, PSl[r].y, PSh[r].x, PSh[r].y};
        *(float4*)(Cbuf + cb64 + (size_t)(rbase + r) * 64 + j0) =
            (float4){CSl[r].x, CSl[r].y, CSh[r].x, CSh[r].y};
    }
}

// Phase 2: serial chunk combine S <- S*P_c + C_c; stores each chunk's
// START state to Scbuf. 256 blocks (16 heads x 16 v-groups) x 64 thr.
__global__ __launch_bounds__(64) void combine(
    const float* __restrict__ Pbuf, const float* __restrict__ Cbuf,
    const float* __restrict__ init_state, float* __restrict__ Scbuf)
{
    const int b = blockIdx.x;
    const int h = b & 15;
    const int g = b >> 4;
    const int l = threadIdx.x;
    const int vl = l >> 4;
    const int vidx = g * 4 + vl;
    const int j0 = (l & 15) * 4;
    __shared__ __align__(16) float Pl[64 * 64];
    __shared__ __align__(16) float sl[4 * 64];

    float4 s = *(const float4*)(init_state + h * 4096 + vidx * 64 + j0);
    for (int c = 0; c < NCH; ++c) {
        const size_t cbase = ((size_t)h * NCH + c) * 4096;
        *(float4*)(Scbuf + cbase + (size_t)vidx * 64 + j0) = s;
        const float* Psrc = Pbuf + cbase;
#pragma unroll
        for (int t = 0; t < 16; ++t)
            *(float4*)(&Pl[t * 256 + l * 4]) = *(const float4*)(Psrc + t * 256 + l * 4);
        *(float4*)(&sl[vl * 64 + j0]) = s;
        __syncthreads();
        float4 Cv = *(const float4*)(Cbuf + cbase + (size_t)vidx * 64 + j0);
        f2_t al = {Cv.x, Cv.y}, ah = {Cv.z, Cv.w};
        for (int k = 0; k < 64; ++k) {
            const float sk = sl[vl * 64 + k];
            float4 Pr = *(const float4*)(&Pl[k * 64 + j0]);
            al = fma2(f2bc(sk), lo2(Pr), al);
            ah = fma2(f2bc(sk), hi2(Pr), ah);
        }
        s = (float4){al.x, al.y, ah.x, ah.y};
        __syncthreads();
    }
}

// ---- output scan: 4 rows/lane-group, init from Scbuf ----------------------
struct SlotO {
    float4 E, A1, A2e, B1e, K1e, B2, K2, R1e, R2e;
    float4 vva, vvb;
    float4 sc, sc2;
};

static __device__ __forceinline__ void slot_load_o(
    SlotO& K, const float* __restrict__ p, int j0, int rb2)
{
    K.E   = *(const float4*)(p + j0);
    K.A1  = *(const float4*)(p + 64 + j0);
    K.A2e = *(const float4*)(p + 128 + j0);
    K.B1e = *(const float4*)(p + 192 + j0);
    K.K1e = *(const float4*)(p + 256 + j0);
    K.B2  = *(const float4*)(p + 320 + j0);
    K.K2  = *(const float4*)(p + 384 + j0);
    K.R1e = *(const float4*)(p + 448 + j0);
    K.R2e = *(const float4*)(p + 512 + j0);
    K.vva = *(const float4*)(p + 576 + rb2);
    K.vvb = *(const float4*)(p + 576 + rb2 + 4);
    K.sc  = *(const float4*)(p + 704);
    K.sc2 = *(const float4*)(p + 708);
}

static __device__ __forceinline__ void pair_out(
    f2_t* Sl, f2_t* Sh, const SlotO& K, float4& o1v, float4& o2v)
{
    float u1[4], u2[4], op[4], oz[4];
#pragma unroll
    for (int r = 0; r < 4; ++r) {
        u1[r] = red16(dot4pk(Sl[r], Sh[r], K.A1));
        u2[r] = red16(dot4pk(Sl[r], Sh[r], K.A2e));
        op[r] = red16(dot4pk(Sl[r], Sh[r], K.R1e));
        oz[r] = red16(dot4pk(Sl[r], Sh[r], K.R2e));
    }
    float o1a[4], o2a[4];
#pragma unroll
    for (int r = 0; r < 4; ++r) {
        const float v1 = r == 0 ? K.vva.x : r == 1 ? K.vva.z
                       : r == 2 ? K.vvb.x : K.vvb.z;
        const float v2 = r == 0 ? K.vva.y : r == 1 ? K.vva.w
                       : r == 2 ? K.vvb.y : K.vvb.w;
        const float sa1 = u1[r];
        const float sa2 = fmaf(v1, K.sc.y, fmaf(sa1, K.sc.x, u2[r]));
        o1a[r] = fmaf(v1, K.sc.w, fmaf(sa1, K.sc.z, op[r]));
        o2a[r] = fmaf(v2, K.sc2.w, fmaf(sa2, K.sc2.z,
                 fmaf(v1, K.sc2.y, fmaf(sa1, K.sc2.x, oz[r]))));
        const f2_t sa1v = f2bc(sa1), sa2v = f2bc(sa2);
        const f2_t v1v = f2bc(v1), v2v = f2bc(v2);
        f2_t nl = Sl[r] * lo2(K.E), nh = Sh[r] * hi2(K.E);
        nl = fma2(sa1v, lo2(K.B1e), nl); nh = fma2(sa1v, hi2(K.B1e), nh);
        nl = fma2(v1v, lo2(K.K1e), nl);  nh = fma2(v1v, hi2(K.K1e), nh);
        nl = fma2(sa2v, lo2(K.B2), nl);  nh = fma2(sa2v, hi2(K.B2), nh);
        nl = fma2(v2v, lo2(K.K2), nl);   nh = fma2(v2v, hi2(K.K2), nh);
        Sl[r] = nl; Sh[r] = nh;
    }
    o1v = (float4){o1a[0], o1a[1], o1a[2], o1a[3]};
    o2v = (float4){o2a[0], o2a[1], o2a[2], o2a[3]};
}

__global__ __launch_bounds__(64, 1) void out_scan(
    const float* __restrict__ pk, const float* __restrict__ Scbuf,
    float* __restrict__ y)
{
    const int b = blockIdx.x;
    const int h = b & 15;
    const int w = (b >> 4) & 3;
    const int c = b >> 6;
    const int l = threadIdx.x;
    const int q = l >> 4;
    const int j0 = (l & 15) * 4;
    const int rbase = w * 16 + q * 4;
    const int rb2 = 2 * rbase;
    const int cb = h * 64;
    const float* hbase = pk + ((size_t)h * 1024 + (size_t)c * CPAIR) * PAIR_F;
    const size_t cb64 = ((size_t)h * NCH + c) * 4096;

    f2_t Sl[4], Sh[4];
#pragma unroll
    for (int r = 0; r < 4; ++r) {
        float4 S4 = *(const float4*)(Scbuf + cb64 + (size_t)(rbase + r) * 64 + j0);
        Sl[r] = (f2_t){S4.x, S4.y};
        Sh[r] = (f2_t){S4.z, S4.w};
    }

    SlotO s0, s1, s2, s3;
    slot_load_o(s0, hbase + 0 * PAIR_F, j0, rb2);
    slot_load_o(s1, hbase + 1 * PAIR_F, j0, rb2);
    slot_load_o(s2, hbase + 2 * PAIR_F, j0, rb2);
    slot_load_o(s3, hbase + 3 * PAIR_F, j0, rb2);

    const bool wr = (l & 15) == 0;
    const int pi0 = c * CPAIR;
    float4 o1v, o2v;
#define OUT_STORE(pidx)                                                       \
    if (wr) {                                                                 \
        float* yp = y + (size_t)(2 * (pidx)) * C_DIM + cb + rbase;            \
        *(float4*)yp = o1v;                                                   \
        *(float4*)(yp + C_DIM) = o2v;                                         \
    }
    for (int i = 0; i < CPAIR - 4; i += 4) {
        const float* pl = hbase + (size_t)(i + 4) * PAIR_F;
        pair_out(Sl, Sh, s0, o1v, o2v);
        slot_load_o(s0, pl + 0 * PAIR_F, j0, rb2);
        OUT_STORE(pi0 + i)
        pair_out(Sl, Sh, s1, o1v, o2v);
        slot_load_o(s1, pl + 1 * PAIR_F, j0, rb2);
        OUT_STORE(pi0 + i + 1)
        pair_out(Sl, Sh, s2, o1v, o2v);
        slot_load_o(s2, pl + 2 * PAIR_F, j0, rb2);
        OUT_STORE(pi0 + i + 2)
        pair_out(Sl, Sh, s3, o1v, o2v);
        slot_load_o(s3, pl + 3 * PAIR_F, j0, rb2);
        OUT_STORE(pi0 + i + 3)
    }
    pair_out(Sl, Sh, s0, o1v, o2v); OUT_STORE(pi0 + CPAIR - 4)
    pair_out(Sl, Sh, s1, o1v, o2v); OUT_STORE(pi0 + CPAIR - 3)
    pair_out(Sl, Sh, s2, o1v, o2v); OUT_STORE(pi0 + CPAIR - 2)
    pair_out(Sl, Sh, s3, o1v, o2v); OUT_STORE(pi0 + CPAIR - 1)
#undef OUT_STORE
}

// ---------------------------------------------------------------------------
// GroupNorm + bonus + *g ; writes bf16 (xo*g) for the final MFMA GEMM.
// ---------------------------------------------------------------------------
__global__ __launch_bounds__(256) void gn_bonus(
    const float* __restrict__ y, const float* __restrict__ rb,
    const float* __restrict__ kb, const float* __restrict__ vb,
    const float* __restrict__ gb, const float* __restrict__ r_k,
    const float* __restrict__ lnw, const float* __restrict__ lnb,
    unsigned short* __restrict__ yg)
{
    const int t = blockIdx.x, tid = threadIdx.x;
    const int c0 = tid << 2;
    const size_t base = (size_t)t * C_DIM + c0;
    float4 yv = *(const float4*)(y + base);
    float sum = yv.x + yv.y + yv.z + yv.w;
    float ss  = yv.x * yv.x + yv.y * yv.y + yv.z * yv.z + yv.w * yv.w;
    float4 rv = *(const float4*)(rb + base);
    float4 kv = *(const float4*)(kb + base);
    float4 rkv = *(const float4*)(r_k + c0);
    float dot = rv.x * kv.x * rkv.x + rv.y * kv.y * rkv.y +
                rv.z * kv.z * rkv.z + rv.w * kv.w * rkv.w;
#pragma unroll
    for (int m = 1; m <= 8; m <<= 1) {
        sum += __shfl_xor(sum, m);
        ss  += __shfl_xor(ss, m);
        dot += __shfl_xor(dot, m);
    }
    const float mu = sum * 0.015625f;
    const float var = ss * 0.015625f - mu * mu;
    const float rstd = rsqrtf(var + 0.00064f);
    float4 wv = *(const float4*)(lnw + c0);
    float4 bv = *(const float4*)(lnb + c0);
    float4 vv = *(const float4*)(vb + base);
    float4 gv = *(const float4*)(gb + base);
    ushort4 o;
    o.x = f2bf(((yv.x - mu) * rstd * wv.x + bv.x + dot * vv.x) * gv.x);
    o.y = f2bf(((yv.y - mu) * rstd * wv.y + bv.y + dot * vv.y) * gv.y);
    o.z = f2bf(((yv.z - mu) * rstd * wv.z + bv.z + dot * vv.z) * gv.z);
    o.w = f2bf(((yv.w - mu) * rstd * wv.w + bv.w + dot * vv.w) * gv.w);
    *(ushort4*)(yg + base) = o;
}

// ---------------------------------------------------------------------------
extern "C" void kernel_launch(void* const* d_in, const int* in_sizes, int n_in,
                              void* d_out, int out_size, void* d_ws, size_t ws_size,
                              hipStream_t stream)
{
    (void)in_sizes; (void)n_in; (void)out_size; (void)ws_size;
    const float* x       = (const float*)d_in[0];
    const float* v_first = (const float*)d_in[1];
    const float* x_prev  = (const float*)d_in[2];
    const float* init_st = (const float*)d_in[3];
    const float* x_r = (const float*)d_in[4];
    const float* x_w = (const float*)d_in[5];
    const float* x_k = (const float*)d_in[6];
    const float* x_v = (const float*)d_in[7];
    const float* x_a = (const float*)d_in[8];
    const float* x_g = (const float*)d_in[9];
    const float* w0  = (const float*)d_in[10];
    const float* a0  = (const float*)d_in[11];
    const float* v0  = (const float*)d_in[12];
    const float* k_k = (const float*)d_in[13];
    const float* k_a = (const float*)d_in[14];
    const float* w1  = (const float*)d_in[15];
    const float* w2  = (const float*)d_in[16];
    const float* a1  = (const float*)d_in[17];
    const float* a2  = (const float*)d_in[18];
    const float* v1  = (const float*)d_in[19];
    const float* v2  = (const float*)d_in[20];
    const float* g1  = (const float*)d_in[21];
    const float* g2  = (const float*)d_in[22];
    const float* r_k = (const float*)d_in[23];
    const float* Wr  = (const float*)d_in[24];
    const float* Wk  = (const float*)d_in[25];
    const float* Wv  = (const float*)d_in[26];
    const float* Wo  = (const float*)d_in[27];
    const float* ln_w = (const float*)d_in[28];
    const float* ln_b = (const float*)d_in[29];

    float* out = (float*)d_out;
    float* ws  = (float*)d_ws;
    const size_t NE = (size_t)T_LEN * C_DIM;   // 2M
    const size_t WE = (size_t)C_DIM * C_DIM;   // 1M
    float* rB  = ws;
    float* kB  = ws + NE;
    float* vB  = ws + 2 * NE;
    float* gB  = ws + 3 * NE;
    float* hwB = ws + 4 * NE;                  // T*64
    float* haB = hwB + (size_t)T_LEN * 64;
    float* hvB = haB + (size_t)T_LEN * 64;
    float* hgB = hvB + (size_t)T_LEN * 32;     // h region < NE/2
    float* pk  = ws + 4 * NE + NE / 2;         // 6*NE floats (16*1024*768)
    unsigned short* b16 = (unsigned short*)(ws + 10 * NE + NE / 2);
    unsigned short* xr16 = b16;                // NE shorts
    unsigned short* xk16 = b16 + NE;
    unsigned short* xv16 = b16 + 2 * NE;
    unsigned short* Wr16 = b16 + 3 * NE;       // 4*WE shorts
    unsigned short* Wk16 = Wr16 + WE;
    unsigned short* Wv16 = Wr16 + 2 * WE;
    unsigned short* Wo16 = Wr16 + 3 * WE;
    unsigned short* yg16 = b16 + 3 * NE + 4 * WE;  // NE shorts
    unsigned short* lw16 = yg16 + NE;              // 320K shorts (LoRA weights)
    // xw/xa/xg bf16 live in the pk region (pk written later by lora2f)
    unsigned short* xw16 = (unsigned short*)pk;
    unsigned short* xa16 = xw16 + NE;
    unsigned short* xg16 = xw16 + 2 * NE;
    // yB aliases xr16/xk16 (consumed by gemms before the scan writes it)
    float* yB = (float*)xr16;
    // Chunk-scan buffers, aliased into regions dead by scan time:
    //   Pbuf  <- xv16   (dead after gemm3/lora1m)
    //   Cbuf  <- Wr16+Wk16 (dead after gemm3)
    //   Scbuf <- yg16   (gn_bonus writes it LATER)
    float* Pbuf  = (float*)xv16;   // 16h x 16c x 64 x 64
    float* Cbuf  = (float*)Wr16;
    float* Scbuf = (float*)yg16;

    wcvtall<<<4384, 256, 0, stream>>>(Wr, Wk, Wv, Wo, w1, a1, v1, g1,
                                      Wr16, lw16);
    xcvt<<<T_LEN, 256, 0, stream>>>(x, x_prev, x_r, x_k, x_v, x_w, x_a, x_g,
                                    xr16, xk16, xv16, xw16, xa16, xg16);

    gemm_bf16_3<<<dim3(16, 16, 3), 256, 0, stream>>>(
        xr16, xk16, xv16, Wr16, Wk16, Wv16, rB, kB, vB);

    lora1m<<<dim3(2, 16, 4), 256, 0, stream>>>(
        xw16, xa16, xv16, xg16, lw16, hwB, haB, hvB, hgB);

    lora2f<<<dim3(4, 128), 256, 0, stream>>>(
        hwB, haB, hvB, hgB, w2, a2, v2, g2, w0, a0, v0,
        k_k, k_a, v_first, rB, kB, vB, gB, pk);

    pc_fused<<<1024, 64, 0, stream>>>(pk, Pbuf, Cbuf);
    combine<<<256, 64, 0, stream>>>(Pbuf, Cbuf, init_st, Scbuf);
    out_scan<<<1024, 64, 0, stream>>>(pk, Scbuf, yB);

    gn_bonus<<<T_LEN, 256, 0, stream>>>(yB, rB, kB, vB, gB, r_k, ln_w, ln_b, yg16);
    gemm_bf16<<<dim3(16, 16), 256, 0, stream>>>(yg16, Wo16, out);
}

// Round 7
// 399.226 us; speedup vs baseline: 1.2908x; 1.0703x over previous
//
#include <hip/hip_runtime.h>

#define T_LEN 2048
#define C_DIM 1024
#define PAIR_F 768          // floats per (head, step-pair) packet
#define NCH 16              // chunks
#define CPAIR 64            // pairs per chunk (NCH*CPAIR = 1024)

#define AS1 __attribute__((address_space(1)))
#define AS3 __attribute__((address_space(3)))

typedef __attribute__((ext_vector_type(8))) short bf8_t;
typedef __attribute__((ext_vector_type(4))) float f4_t;
typedef __attribute__((ext_vector_type(2))) float f2_t;

static __device__ __forceinline__ float sigf(float x) {
    return 1.f / (1.f + __expf(-x));
}
static __device__ __forceinline__ unsigned short f2bf(float f) {
    unsigned u = __float_as_uint(f);
    u += 0x7fff + ((u >> 16) & 1);
    return (unsigned short)(u >> 16);
}

// ---- cross-lane reduction helpers (defined early; used by lora2f + scans) --
static __device__ __forceinline__ float red16(float x) {
    int xi;
    xi = __builtin_amdgcn_mov_dpp(__float_as_int(x), 0x128, 0xf, 0xf, true);
    x += __int_as_float(xi);
    xi = __builtin_amdgcn_mov_dpp(__float_as_int(x), 0x124, 0xf, 0xf, true);
    x += __int_as_float(xi);
    xi = __builtin_amdgcn_mov_dpp(__float_as_int(x), 0x122, 0xf, 0xf, true);
    x += __int_as_float(xi);
    xi = __builtin_amdgcn_mov_dpp(__float_as_int(x), 0x121, 0xf, 0xf, true);
    x += __int_as_float(xi);
    return x;
}
// full 64-lane sum: DPP within 16 (VALU pipe), then only 2 DS-ops
static __device__ __forceinline__ float red64(float x) {
    x = red16(x);
    x += __shfl_xor(x, 16);
    x += __shfl_xor(x, 32);
    return x;
}

static __device__ __forceinline__ f2_t f2bc(float s) { return (f2_t){s, s}; }
static __device__ __forceinline__ f2_t fma2(f2_t a, f2_t b, f2_t c) {
    return __builtin_elementwise_fma(a, b, c);
}
static __device__ __forceinline__ f2_t lo2(const float4& v) { return (f2_t){v.x, v.y}; }
static __device__ __forceinline__ f2_t hi2(const float4& v) { return (f2_t){v.z, v.w}; }

static __device__ __forceinline__ float dot4pk(f2_t Sl, f2_t Sh, const float4& A) {
    f2_t m = Sl * lo2(A);
    m = fma2(Sh, hi2(A), m);
    return m.x + m.y;
}

// ---------------------------------------------------------------------------
// Convert the four 1024x1024 fp32 weights into one bf16 block (1M strides),
// plus the transposed LoRA stage-1 weights (blocks 4096..4383).
// ---------------------------------------------------------------------------
__global__ __launch_bounds__(256) void wcvtall(
    const float* __restrict__ Wr, const float* __restrict__ Wk,
    const float* __restrict__ Wv, const float* __restrict__ Wo,
    const float* __restrict__ w1, const float* __restrict__ a1,
    const float* __restrict__ v1, const float* __restrict__ g1,
    unsigned short* __restrict__ dst, unsigned short* __restrict__ lw16)
{
    const int b = blockIdx.x;
    if (b < 4096) {
        const size_t idx = ((size_t)b * 256 + threadIdx.x) * 4;
        const int sel = (int)(idx >> 20);
        const float* src = sel == 0 ? Wr : sel == 1 ? Wk : sel == 2 ? Wv : Wo;
        float4 v = *(const float4*)(src + (idx & 0xFFFFF));
        ushort4 o = {f2bf(v.x), f2bf(v.y), f2bf(v.z), f2bf(v.w)};
        *(ushort4*)(dst + idx) = o;
        return;
    }
    const int row = b - 4096;         // 0..287
    const float* src; int Kh, i; unsigned short* dl;
    if (row < 64)       { src = w1; Kh = 64;  i = row;       dl = lw16 + (size_t)row * 1024; }
    else if (row < 128) { src = a1; Kh = 64;  i = row - 64;  dl = lw16 + (size_t)row * 1024; }
    else if (row < 160) { src = v1; Kh = 32;  i = row - 128; dl = lw16 + (size_t)(row - 128 + 128) * 1024; }
    else                { src = g1; Kh = 128; i = row - 160; dl = lw16 + (size_t)(row - 160 + 192) * 1024; }
    const int c0 = threadIdx.x * 4;
#pragma unroll
    for (int u = 0; u < 4; ++u)
        dl[c0 + u] = f2bf(src[(size_t)(c0 + u) * Kh + i]);
}

// ---------------------------------------------------------------------------
// Token-shift mix -> bf16 A-matrices for r/k/v projections and w/a/g LoRA.
// ---------------------------------------------------------------------------
__global__ __launch_bounds__(256) void xcvt(
    const float* __restrict__ x, const float* __restrict__ xprev,
    const float* __restrict__ x_r, const float* __restrict__ x_k,
    const float* __restrict__ x_v, const float* __restrict__ x_w,
    const float* __restrict__ x_a, const float* __restrict__ x_g,
    unsigned short* __restrict__ xr16, unsigned short* __restrict__ xk16,
    unsigned short* __restrict__ xv16, unsigned short* __restrict__ xw16,
    unsigned short* __restrict__ xa16, unsigned short* __restrict__ xg16)
{
    const int t = blockIdx.x;
    const int c0 = threadIdx.x * 4;
    const size_t base = (size_t)t * C_DIM + c0;
    float4 xv = *(const float4*)(x + base);
    float4 pv = (t == 0) ? *(const float4*)(xprev + c0)
                         : *(const float4*)(x + base - C_DIM);
    float4 dx = {pv.x - xv.x, pv.y - xv.y, pv.z - xv.z, pv.w - xv.w};
#define MIXOUT(mixp, dstp)                                                    \
    {                                                                          \
        float4 mv = *(const float4*)(mixp + c0);                               \
        ushort4 o = {f2bf(xv.x + dx.x * mv.x), f2bf(xv.y + dx.y * mv.y),       \
                     f2bf(xv.z + dx.z * mv.z), f2bf(xv.w + dx.w * mv.w)};      \
        *(ushort4*)(dstp + base) = o;                                          \
    }
    MIXOUT(x_r, xr16) MIXOUT(x_k, xk16) MIXOUT(x_v, xv16)
    MIXOUT(x_w, xw16) MIXOUT(x_a, xa16) MIXOUT(x_g, xg16)
#undef MIXOUT
}

// ---------------------------------------------------------------------------
// bf16 MFMA NT GEMM core: out[t,i] = sum_c A[t,c]*W[i,c], fp32 accumulate.
// ---------------------------------------------------------------------------
static __device__ __forceinline__ void gemm_core(
    const unsigned short* __restrict__ A, const unsigned short* __restrict__ W,
    float* __restrict__ out)
{
    __shared__ unsigned short Ab[2][128 * 32];
    __shared__ unsigned short Bb[2][64 * 32];
    const int tid = threadIdx.x;
    const int lane = tid & 63;
    const int w = tid >> 6;
    const int n0 = blockIdx.x * 64;
    const int t0 = blockIdx.y * 128;
    const int wm = (w & 1) * 64;
    const int wn = (w >> 1) * 32;
    const int srow = lane >> 2;
    const int scol = (lane & 3) * 8;

    f4_t acc[4][2];
#pragma unroll
    for (int i = 0; i < 4; ++i)
#pragma unroll
        for (int j = 0; j < 2; ++j)
            acc[i][j] = (f4_t){0.f, 0.f, 0.f, 0.f};

#pragma unroll
    for (int s = 0; s < 2; ++s) {
        const int i = 2 * w + s;
        __builtin_amdgcn_global_load_lds(
            (const AS1 unsigned int*)(A + (size_t)(t0 + i * 16 + srow) * 1024 + scol),
            (AS3 unsigned int*)(&Ab[0][i * 512 + lane * 8]), 16, 0, 0);
    }
    __builtin_amdgcn_global_load_lds(
        (const AS1 unsigned int*)(W + (size_t)(n0 + w * 16 + srow) * 1024 + scol),
        (AS3 unsigned int*)(&Bb[0][w * 512 + lane * 8]), 16, 0, 0);

    const int mrow = lane & 15;
    const int kq = (lane >> 4) * 8;
    for (int k0 = 0; k0 < 1024; k0 += 32) {
        const int cur = (k0 >> 5) & 1, nxt = cur ^ 1;
        __syncthreads();
        if (k0 + 32 < 1024) {
            const int k1 = k0 + 32;
#pragma unroll
            for (int s = 0; s < 2; ++s) {
                const int i = 2 * w + s;
                __builtin_amdgcn_global_load_lds(
                    (const AS1 unsigned int*)(A + (size_t)(t0 + i * 16 + srow) * 1024 + k1 + scol),
                    (AS3 unsigned int*)(&Ab[nxt][i * 512 + lane * 8]), 16, 0, 0);
            }
            __builtin_amdgcn_global_load_lds(
                (const AS1 unsigned int*)(W + (size_t)(n0 + w * 16 + srow) * 1024 + k1 + scol),
                (AS3 unsigned int*)(&Bb[nxt][w * 512 + lane * 8]), 16, 0, 0);
        }
        bf8_t af[4], bfr[2];
#pragma unroll
        for (int i = 0; i < 4; ++i)
            af[i] = *(const bf8_t*)(&Ab[cur][(wm + 16 * i + mrow) * 32 + kq]);
#pragma unroll
        for (int j = 0; j < 2; ++j)
            bfr[j] = *(const bf8_t*)(&Bb[cur][(wn + 16 * j + mrow) * 32 + kq]);
#pragma unroll
        for (int i = 0; i < 4; ++i)
#pragma unroll
            for (int j = 0; j < 2; ++j)
                acc[i][j] = __builtin_amdgcn_mfma_f32_16x16x32_bf16(
                    af[i], bfr[j], acc[i][j], 0, 0, 0);
    }
    const int crow = (lane >> 4) * 4;
    const int ccol = lane & 15;
#pragma unroll
    for (int i = 0; i < 4; ++i)
#pragma unroll
        for (int j = 0; j < 2; ++j)
#pragma unroll
            for (int u = 0; u < 4; ++u)
                out[(size_t)(t0 + wm + 16 * i + crow + u) * 1024
                    + n0 + wn + 16 * j + ccol] = acc[i][j][u];
}

__global__ __launch_bounds__(256) void gemm_bf16_3(
    const unsigned short* __restrict__ xr, const unsigned short* __restrict__ xk,
    const unsigned short* __restrict__ xv,
    const unsigned short* __restrict__ Wr, const unsigned short* __restrict__ Wk,
    const unsigned short* __restrict__ Wv,
    float* __restrict__ rB, float* __restrict__ kB, float* __restrict__ vB)
{
    const int z = blockIdx.z;
    const unsigned short* A = z == 0 ? xr : z == 1 ? xk : xv;
    const unsigned short* W = z == 0 ? Wr : z == 1 ? Wk : Wv;
    float* out = z == 0 ? rB : z == 1 ? kB : vB;
    gemm_core(A, W, out);
}

__global__ __launch_bounds__(256) void gemm_bf16(
    const unsigned short* __restrict__ A, const unsigned short* __restrict__ W,
    float* __restrict__ out)
{
    gemm_core(A, W, out);
}

// ---------------------------------------------------------------------------
// Fused LoRA stage-1 via MFMA: z = 0:w(tanh,N=64) 1:a(N=64) 2:v(N=32) 3:g(sig,N=128)
// ---------------------------------------------------------------------------
__global__ __launch_bounds__(256) void lora1m(
    const unsigned short* __restrict__ xw, const unsigned short* __restrict__ xa,
    const unsigned short* __restrict__ xv, const unsigned short* __restrict__ xg,
    const unsigned short* __restrict__ lw16,
    float* __restrict__ hw, float* __restrict__ ha, float* __restrict__ hv,
    float* __restrict__ hg)
{
    const int z = blockIdx.z;
    const unsigned short* A = z == 0 ? xw : z == 1 ? xa : z == 2 ? xv : xg;
    const unsigned short* W = lw16 + (size_t)(z == 0 ? 0 : z == 1 ? 64 : z == 2 ? 128 : 192) * 1024;
    float* out = z == 0 ? hw : z == 1 ? ha : z == 2 ? hv : hg;
    const int N  = z == 3 ? 128 : z == 2 ? 32 : 64;
    const int Ns = z == 3 ? 128 : 64;
    const int n0 = blockIdx.x * 64;
    if (n0 >= Ns) return;

    __shared__ unsigned short Ab[2][128 * 32];
    __shared__ unsigned short Bb[2][64 * 32];
    const int tid = threadIdx.x;
    const int lane = tid & 63;
    const int w = tid >> 6;
    const int t0 = blockIdx.y * 128;
    const int wm = (w & 1) * 64;
    const int wn = (w >> 1) * 32;
    const int srow = lane >> 2;
    const int scol = (lane & 3) * 8;

    f4_t acc[4][2];
#pragma unroll
    for (int i = 0; i < 4; ++i)
#pragma unroll
        for (int j = 0; j < 2; ++j)
            acc[i][j] = (f4_t){0.f, 0.f, 0.f, 0.f};

#pragma unroll
    for (int s = 0; s < 2; ++s) {
        const int i = 2 * w + s;
        __builtin_amdgcn_global_load_lds(
            (const AS1 unsigned int*)(A + (size_t)(t0 + i * 16 + srow) * 1024 + scol),
            (AS3 unsigned int*)(&Ab[0][i * 512 + lane * 8]), 16, 0, 0);
    }
    __builtin_amdgcn_global_load_lds(
        (const AS1 unsigned int*)(W + (size_t)(n0 + w * 16 + srow) * 1024 + scol),
        (AS3 unsigned int*)(&Bb[0][w * 512 + lane * 8]), 16, 0, 0);

    const int mrow = lane & 15;
    const int kq = (lane >> 4) * 8;
    for (int k0 = 0; k0 < 1024; k0 += 32) {
        const int cur = (k0 >> 5) & 1, nxt = cur ^ 1;
        __syncthreads();
        if (k0 + 32 < 1024) {
            const int k1 = k0 + 32;
#pragma unroll
            for (int s = 0; s < 2; ++s) {
                const int i = 2 * w + s;
                __builtin_amdgcn_global_load_lds(
                    (const AS1 unsigned int*)(A + (size_t)(t0 + i * 16 + srow) * 1024 + k1 + scol),
                    (AS3 unsigned int*)(&Ab[nxt][i * 512 + lane * 8]), 16, 0, 0);
            }
            __builtin_amdgcn_global_load_lds(
                (const AS1 unsigned int*)(W + (size_t)(n0 + w * 16 + srow) * 1024 + k1 + scol),
                (AS3 unsigned int*)(&Bb[nxt][w * 512 + lane * 8]), 16, 0, 0);
        }
        bf8_t af[4], bfr[2];
#pragma unroll
        for (int i = 0; i < 4; ++i)
            af[i] = *(const bf8_t*)(&Ab[cur][(wm + 16 * i + mrow) * 32 + kq]);
#pragma unroll
        for (int j = 0; j < 2; ++j)
            bfr[j] = *(const bf8_t*)(&Bb[cur][(wn + 16 * j + mrow) * 32 + kq]);
#pragma unroll
        for (int i = 0; i < 4; ++i)
#pragma unroll
            for (int j = 0; j < 2; ++j)
                acc[i][j] = __builtin_amdgcn_mfma_f32_16x16x32_bf16(
                    af[i], bfr[j], acc[i][j], 0, 0, 0);
    }
    const int crow = (lane >> 4) * 4;
    const int ccol = lane & 15;
#pragma unroll
    for (int i = 0; i < 4; ++i)
#pragma unroll
        for (int j = 0; j < 2; ++j) {
            const int col = n0 + wn + 16 * j + ccol;
            if (col < N) {
#pragma unroll
                for (int u = 0; u < 4; ++u) {
                    float vv = acc[i][j][u];
                    if (z == 0) vv = tanhf(vv);
                    else if (z == 3) vv = sigf(vv);
                    out[(size_t)(t0 + wm + 16 * i + crow + u) * N + col] = vv;
                }
            }
        }
}

// ---------------------------------------------------------------------------
// Fused LoRA-2 (w/a/v/g) + k post-process + PAIR-COMPOSED packet packing.
// r7: NO LDS. The h-tiles (hwB/haB/hvB/hgB rows) are BLOCK-UNIFORM operands
// -> read directly from global with uniform addresses (compiler emits
// s_load_dwordx4 into SGPRs; fma takes the SGPR operand directly). This
// removes 1152 ds_read_b128/thread that made r6's lora2f DS-pipe-bound
// (84us, VALUBusy 30%). Butterfly reduces use red64 (DPP + 2 shfl) instead
// of 6-level shfl_xor: ~480 -> ~80 DS-ops/thread. TOK 16->8 doubles
// occupancy (grid (4,256), 4 blocks/CU).
// Packet layout (768 floats) unchanged from r4.
// ---------------------------------------------------------------------------
#define TOK 8
__global__ __launch_bounds__(256) void lora2f(
    const float* __restrict__ hwB, const float* __restrict__ haB,
    const float* __restrict__ hvB, const float* __restrict__ hgB,
    const float* __restrict__ w2, const float* __restrict__ a2,
    const float* __restrict__ v2, const float* __restrict__ g2,
    const float* __restrict__ w0, const float* __restrict__ a0,
    const float* __restrict__ v0,
    const float* __restrict__ k_k, const float* __restrict__ k_a,
    const float* __restrict__ v_first, const float* __restrict__ rB,
    float* __restrict__ kB, float* __restrict__ vB, float* __restrict__ gB,
    float* __restrict__ pk)
{
    const int tid = threadIdx.x;
    const int t0 = blockIdx.y * TOK;
    const int i  = blockIdx.x * 256 + tid;
    const int h  = i >> 6;
    const int j  = i & 63;

    float av[TOK], ew[TOK], vf[TOK];
    { // a = sigmoid(a0 + ha@a2)
        float acc[TOK];
        const float b0 = a0[i];
#pragma unroll
        for (int tt = 0; tt < TOK; ++tt) acc[tt] = b0;
        for (int jj = 0; jj < 64; jj += 4) {
            const float q0 = a2[(size_t)(jj + 0) * C_DIM + i];
            const float q1 = a2[(size_t)(jj + 1) * C_DIM + i];
            const float q2 = a2[(size_t)(jj + 2) * C_DIM + i];
            const float q3 = a2[(size_t)(jj + 3) * C_DIM + i];
#pragma unroll
            for (int tt = 0; tt < TOK; ++tt) {
                float4 h4 = *(const float4*)(haB + (size_t)(t0 + tt) * 64 + jj);
                acc[tt] = fmaf(h4.x, q0, acc[tt]);
                acc[tt] = fmaf(h4.y, q1, acc[tt]);
                acc[tt] = fmaf(h4.z, q2, acc[tt]);
                acc[tt] = fmaf(h4.w, q3, acc[tt]);
            }
        }
#pragma unroll
        for (int tt = 0; tt < TOK; ++tt) av[tt] = sigf(acc[tt]);
    }
    { // exp(w)
        float acc[TOK];
        const float b0 = w0[i];
#pragma unroll
        for (int tt = 0; tt < TOK; ++tt) acc[tt] = b0;
        for (int jj = 0; jj < 64; jj += 4) {
            const float q0 = w2[(size_t)(jj + 0) * C_DIM + i];
            const float q1 = w2[(size_t)(jj + 1) * C_DIM + i];
            const float q2 = w2[(size_t)(jj + 2) * C_DIM + i];
            const float q3 = w2[(size_t)(jj + 3) * C_DIM + i];
#pragma unroll
            for (int tt = 0; tt < TOK; ++tt) {
                float4 h4 = *(const float4*)(hwB + (size_t)(t0 + tt) * 64 + jj);
                acc[tt] = fmaf(h4.x, q0, acc[tt]);
                acc[tt] = fmaf(h4.y, q1, acc[tt]);
                acc[tt] = fmaf(h4.z, q2, acc[tt]);
                acc[tt] = fmaf(h4.w, q3, acc[tt]);
            }
        }
#pragma unroll
        for (int tt = 0; tt < TOK; ++tt)
            ew[tt] = __expf(-0.6065306597126334f * sigf(acc[tt]));
    }
    { // v mix
        float acc[TOK];
        const float b0 = v0[i];
#pragma unroll
        for (int tt = 0; tt < TOK; ++tt) acc[tt] = b0;
        for (int jj = 0; jj < 32; jj += 4) {
            const float q0 = v2[(size_t)(jj + 0) * C_DIM + i];
            const float q1 = v2[(size_t)(jj + 1) * C_DIM + i];
            const float q2 = v2[(size_t)(jj + 2) * C_DIM + i];
            const float q3 = v2[(size_t)(jj + 3) * C_DIM + i];
#pragma unroll
            for (int tt = 0; tt < TOK; ++tt) {
                float4 h4 = *(const float4*)(hvB + (size_t)(t0 + tt) * 32 + jj);
                acc[tt] = fmaf(h4.x, q0, acc[tt]);
                acc[tt] = fmaf(h4.y, q1, acc[tt]);
                acc[tt] = fmaf(h4.z, q2, acc[tt]);
                acc[tt] = fmaf(h4.w, q3, acc[tt]);
            }
        }
#pragma unroll
        for (int tt = 0; tt < TOK; ++tt) {
            const size_t gi = (size_t)(t0 + tt) * C_DIM + i;
            const float s = sigf(acc[tt]);
            const float vr = vB[gi];
            vf[tt] = vr + (v_first[gi] - vr) * s;
            vB[gi] = vf[tt];
        }
    }
    { // g
        float acc[TOK];
#pragma unroll
        for (int tt = 0; tt < TOK; ++tt) acc[tt] = 0.f;
        for (int jj = 0; jj < 128; jj += 4) {
            const float q0 = g2[(size_t)(jj + 0) * C_DIM + i];
            const float q1 = g2[(size_t)(jj + 1) * C_DIM + i];
            const float q2 = g2[(size_t)(jj + 2) * C_DIM + i];
            const float q3 = g2[(size_t)(jj + 3) * C_DIM + i];
#pragma unroll
            for (int tt = 0; tt < TOK; ++tt) {
                float4 h4 = *(const float4*)(hgB + (size_t)(t0 + tt) * 128 + jj);
                acc[tt] = fmaf(h4.x, q0, acc[tt]);
                acc[tt] = fmaf(h4.y, q1, acc[tt]);
                acc[tt] = fmaf(h4.z, q2, acc[tt]);
                acc[tt] = fmaf(h4.w, q3, acc[tt]);
            }
        }
#pragma unroll
        for (int tt = 0; tt < TOK; ++tt)
            gB[(size_t)(t0 + tt) * C_DIM + i] = acc[tt];
    }
    // k post-process + pair-composed packing
    const float kkw = k_k[i], kaw = k_a[i];
    const size_t pbase = (size_t)h * 1024 * PAIR_F;
    for (int pt = 0; pt < TOK / 2; ++pt) {
        float r_[2], e_[2], kf_[2], v_[2], aa_[2], bb_[2];
#pragma unroll
        for (int u = 0; u < 2; ++u) {
            const int tt = 2 * pt + u;
            const size_t gi = (size_t)(t0 + tt) * C_DIM + i;
            const float kraw = kB[gi];
            const float kn = kraw * kkw;
            const float ss = red64(kn * kn);
            const float sc = 1.f / fmaxf(sqrtf(ss), 1e-12f);
            const float kk = kn * sc;
            const float a_ = av[tt];
            const float kf = kraw * (1.f + (a_ - 1.f) * kaw);
            kB[gi] = kf;
            r_[u] = rB[gi];
            e_[u] = ew[tt];
            kf_[u] = kf;
            v_[u] = vf[tt];
            aa_[u] = -kk;
            bb_[u] = kk * a_;
        }
        const float E   = e_[0] * e_[1];
        const float A2e = e_[0] * aa_[1];
        const float B1e = bb_[0] * e_[1];
        const float K1e = kf_[0] * e_[1];
        const float R1e = e_[0] * r_[0];
        const float cba = red64(bb_[0] * aa_[1]);
        const float cka = red64(kf_[0] * aa_[1]);
        const float cbr = red64(bb_[0] * r_[0]);
        const float ckr = red64(kf_[0] * r_[0]);
        const float cbr2  = red64(B1e * r_[1]);
        const float ckr2  = red64(K1e * r_[1]);
        const float cb2r2 = red64(bb_[1] * r_[1]);
        const float ck2r2 = red64(kf_[1] * r_[1]);
        float* p = pk + pbase + (size_t)(blockIdx.y * (TOK / 2) + pt) * PAIR_F;
        p[j]        = E;
        p[64 + j]   = aa_[0];
        p[128 + j]  = A2e;
        p[192 + j]  = B1e;
        p[256 + j]  = K1e;
        p[320 + j]  = bb_[1];
        p[384 + j]  = kf_[1];
        p[448 + j]  = R1e;
        p[512 + j]  = E * r_[1];          // R2e = E ⊙ R2
        p[576 + 2 * j]     = v_[0];       // vv interleaved
        p[576 + 2 * j + 1] = v_[1];
        if (j == 0) {
            p[704] = cba;  p[705] = cka;  p[706] = cbr;  p[707] = ckr;
            p[708] = cbr2; p[709] = ckr2; p[710] = cb2r2; p[711] = ck2r2;
        }
    }
}

// ---------------------------------------------------------------------------
// CHUNKED SCAN (r6 structure, unchanged): pc_fused computes per-chunk P and C
// with 4 rows/lane-group; combine runs the 16-step serial chunk recursion;
// out_scan replays chunks in parallel with outputs.
// ---------------------------------------------------------------------------
struct SlotPC {
    float4 E, A1, A2e, B1e, K1e, B2, K2;
    float4 vva, vvb;   // {v1,v2} for rows rbase..rbase+3
    float4 sc;         // cba, cka, cbr, ckr (only x,y used here)
};

static __device__ __forceinline__ void slot_load_pc(
    SlotPC& K, const float* __restrict__ p, int j0, int rb2)
{
    K.E   = *(const float4*)(p + j0);
    K.A1  = *(const float4*)(p + 64 + j0);
    K.A2e = *(const float4*)(p + 128 + j0);
    K.B1e = *(const float4*)(p + 192 + j0);
    K.K1e = *(const float4*)(p + 256 + j0);
    K.B2  = *(const float4*)(p + 320 + j0);
    K.K2  = *(const float4*)(p + 384 + j0);
    K.vva = *(const float4*)(p + 576 + rb2);
    K.vvb = *(const float4*)(p + 576 + rb2 + 4);
    K.sc  = *(const float4*)(p + 704);
}

static __device__ __forceinline__ void pair_pc(
    f2_t* PSl, f2_t* PSh, f2_t* CSl, f2_t* CSh, const SlotPC& K)
{
    float pu1[4], pu2[4], cu1[4], cu2[4];
#pragma unroll
    for (int r = 0; r < 4; ++r) {
        pu1[r] = red16(dot4pk(PSl[r], PSh[r], K.A1));
        pu2[r] = red16(dot4pk(PSl[r], PSh[r], K.A2e));
        cu1[r] = red16(dot4pk(CSl[r], CSh[r], K.A1));
        cu2[r] = red16(dot4pk(CSl[r], CSh[r], K.A2e));
    }
#pragma unroll
    for (int r = 0; r < 4; ++r) {
        { // P update: v-terms exactly zero -> dropped (bitwise identical)
            const float sa1 = pu1[r];
            const float sa2 = fmaf(sa1, K.sc.x, pu2[r]);
            const f2_t sa1v = f2bc(sa1), sa2v = f2bc(sa2);
            f2_t nl = PSl[r] * lo2(K.E), nh = PSh[r] * hi2(K.E);
            nl = fma2(sa1v, lo2(K.B1e), nl); nh = fma2(sa1v, hi2(K.B1e), nh);
            nl = fma2(sa2v, lo2(K.B2), nl);  nh = fma2(sa2v, hi2(K.B2), nh);
            PSl[r] = nl; PSh[r] = nh;
        }
        { // C update: full recurrence from zero init
            const float v1 = r == 0 ? K.vva.x : r == 1 ? K.vva.z
                           : r == 2 ? K.vvb.x : K.vvb.z;
            const float v2 = r == 0 ? K.vva.y : r == 1 ? K.vva.w
                           : r == 2 ? K.vvb.y : K.vvb.w;
            const float sa1 = cu1[r];
            const float sa2 = fmaf(v1, K.sc.y, fmaf(sa1, K.sc.x, cu2[r]));
            const f2_t sa1v = f2bc(sa1), sa2v = f2bc(sa2);
            const f2_t v1v = f2bc(v1), v2v = f2bc(v2);
            f2_t nl = CSl[r] * lo2(K.E), nh = CSh[r] * hi2(K.E);
            nl = fma2(sa1v, lo2(K.B1e), nl); nh = fma2(sa1v, hi2(K.B1e), nh);
            nl = fma2(v1v, lo2(K.K1e), nl);  nh = fma2(v1v, hi2(K.K1e), nh);
            nl = fma2(sa2v, lo2(K.B2), nl);  nh = fma2(sa2v, hi2(K.B2), nh);
            nl = fma2(v2v, lo2(K.K2), nl);   nh = fma2(v2v, hi2(K.K2), nh);
            CSl[r] = nl; CSh[r] = nh;
        }
    }
}

// grid: b = h + 16*w + 64*c  (w stride 16 => same (h,c) on same XCD mod 8)
__global__ __launch_bounds__(64, 1) void pc_fused(
    const float* __restrict__ pk, float* __restrict__ Pbuf,
    float* __restrict__ Cbuf)
{
    const int b = blockIdx.x;
    const int h = b & 15;
    const int w = (b >> 4) & 3;
    const int c = b >> 6;
    const int l = threadIdx.x;
    const int q = l >> 4;
    const int j0 = (l & 15) * 4;
    const int rbase = w * 16 + q * 4;
    const int rb2 = 2 * rbase;
    const float* hbase = pk + ((size_t)h * 1024 + (size_t)c * CPAIR) * PAIR_F;

    f2_t PSl[4], PSh[4], CSl[4], CSh[4];
#pragma unroll
    for (int r = 0; r < 4; ++r) {
        const int row = rbase + r;
        PSl[r] = (f2_t){j0 == row ? 1.f : 0.f, j0 + 1 == row ? 1.f : 0.f};
        PSh[r] = (f2_t){j0 + 2 == row ? 1.f : 0.f, j0 + 3 == row ? 1.f : 0.f};
        CSl[r] = (f2_t){0.f, 0.f};
        CSh[r] = (f2_t){0.f, 0.f};
    }

    SlotPC s0, s1, s2, s3;
    slot_load_pc(s0, hbase + 0 * PAIR_F, j0, rb2);
    slot_load_pc(s1, hbase + 1 * PAIR_F, j0, rb2);
    slot_load_pc(s2, hbase + 2 * PAIR_F, j0, rb2);
    slot_load_pc(s3, hbase + 3 * PAIR_F, j0, rb2);

    for (int i = 0; i < CPAIR - 4; i += 4) {
        const float* pl = hbase + (size_t)(i + 4) * PAIR_F;
        pair_pc(PSl, PSh, CSl, CSh, s0); slot_load_pc(s0, pl + 0 * PAIR_F, j0, rb2);
        pair_pc(PSl, PSh, CSl, CSh, s1); slot_load_pc(s1, pl + 1 * PAIR_F, j0, rb2);
        pair_pc(PSl, PSh, CSl, CSh, s2); slot_load_pc(s2, pl + 2 * PAIR_F, j0, rb2);
        pair_pc(PSl, PSh, CSl, CSh, s3); slot_load_pc(s3, pl + 3 * PAIR_F, j0, rb2);
    }
    pair_pc(PSl, PSh, CSl, CSh, s0);
    pair_pc(PSl, PSh, CSl, CSh, s1);
    pair_pc(PSl, PSh, CSl, CSh, s2);
    pair_pc(PSl, PSh, CSl, CSh, s3);

    const size_t cb64 = ((size_t)h * NCH + c) * 4096;
#pragma unroll
    for (int r = 0; r < 4; ++r) {
        *(float4*)(Pbuf + cb64 + (size_t)(rbase + r) * 64 + j0) =
            (float4){PSl[r].x, PSl[r].y, PSh[r].x, PSh[r].y};
        *(float4*)(Cbuf + cb64 + (size_t)(rbase + r) * 64 + j0) =
            (float4){CSl[r].x, CSl[r].y, CSh[r].x, CSh[r].y};
    }
}

// Phase 2: serial chunk combine S <- S*P_c + C_c; stores each chunk's
// START state to Scbuf. 256 blocks (16 heads x 16 v-groups) x 64 thr.
__global__ __launch_bounds__(64) void combine(
    const float* __restrict__ Pbuf, const float* __restrict__ Cbuf,
    const float* __restrict__ init_state, float* __restrict__ Scbuf)
{
    const int b = blockIdx.x;
    const int h = b & 15;
    const int g = b >> 4;
    const int l = threadIdx.x;
    const int vl = l >> 4;
    const int vidx = g * 4 + vl;
    const int j0 = (l & 15) * 4;
    __shared__ __align__(16) float Pl[64 * 64];
    __shared__ __align__(16) float sl[4 * 64];

    float4 s = *(const float4*)(init_state + h * 4096 + vidx * 64 + j0);
    for (int c = 0; c < NCH; ++c) {
        const size_t cbase = ((size_t)h * NCH + c) * 4096;
        *(float4*)(Scbuf + cbase + (size_t)vidx * 64 + j0) = s;
        const float* Psrc = Pbuf + cbase;
#pragma unroll
        for (int t = 0; t < 16; ++t)
            *(float4*)(&Pl[t * 256 + l * 4]) = *(const float4*)(Psrc + t * 256 + l * 4);
        *(float4*)(&sl[vl * 64 + j0]) = s;
        __syncthreads();
        float4 Cv = *(const float4*)(Cbuf + cbase + (size_t)vidx * 64 + j0);
        f2_t al = {Cv.x, Cv.y}, ah = {Cv.z, Cv.w};
        for (int k = 0; k < 64; ++k) {
            const float sk = sl[vl * 64 + k];
            float4 Pr = *(const float4*)(&Pl[k * 64 + j0]);
            al = fma2(f2bc(sk), lo2(Pr), al);
            ah = fma2(f2bc(sk), hi2(Pr), ah);
        }
        s = (float4){al.x, al.y, ah.x, ah.y};
        __syncthreads();
    }
}

// ---- output scan: 4 rows/lane-group, init from Scbuf ----------------------
struct SlotO {
    float4 E, A1, A2e, B1e, K1e, B2, K2, R1e, R2e;
    float4 vva, vvb;
    float4 sc, sc2;
};

static __device__ __forceinline__ void slot_load_o(
    SlotO& K, const float* __restrict__ p, int j0, int rb2)
{
    K.E   = *(const float4*)(p + j0);
    K.A1  = *(const float4*)(p + 64 + j0);
    K.A2e = *(const float4*)(p + 128 + j0);
    K.B1e = *(const float4*)(p + 192 + j0);
    K.K1e = *(const float4*)(p + 256 + j0);
    K.B2  = *(const float4*)(p + 320 + j0);
    K.K2  = *(const float4*)(p + 384 + j0);
    K.R1e = *(const float4*)(p + 448 + j0);
    K.R2e = *(const float4*)(p + 512 + j0);
    K.vva = *(const float4*)(p + 576 + rb2);
    K.vvb = *(const float4*)(p + 576 + rb2 + 4);
    K.sc  = *(const float4*)(p + 704);
    K.sc2 = *(const float4*)(p + 708);
}

static __device__ __forceinline__ void pair_out(
    f2_t* Sl, f2_t* Sh, const SlotO& K, float4& o1v, float4& o2v)
{
    float u1[4], u2[4], op[4], oz[4];
#pragma unroll
    for (int r = 0; r < 4; ++r) {
        u1[r] = red16(dot4pk(Sl[r], Sh[r], K.A1));
        u2[r] = red16(dot4pk(Sl[r], Sh[r], K.A2e));
        op[r] = red16(dot4pk(Sl[r], Sh[r], K.R1e));
        oz[r] = red16(dot4pk(Sl[r], Sh[r], K.R2e));
    }
    float o1a[4], o2a[4];
#pragma unroll
    for (int r = 0; r < 4; ++r) {
        const float v1 = r == 0 ? K.vva.x : r == 1 ? K.vva.z
                       : r == 2 ? K.vvb.x : K.vvb.z;
        const float v2 = r == 0 ? K.vva.y : r == 1 ? K.vva.w
                       : r == 2 ? K.vvb.y : K.vvb.w;
        const float sa1 = u1[r];
        const float sa2 = fmaf(v1, K.sc.y, fmaf(sa1, K.sc.x, u2[r]));
        o1a[r] = fmaf(v1, K.sc.w, fmaf(sa1, K.sc.z, op[r]));
        o2a[r] = fmaf(v2, K.sc2.w, fmaf(sa2, K.sc2.z,
                 fmaf(v1, K.sc2.y, fmaf(sa1, K.sc2.x, oz[r]))));
        const f2_t sa1v = f2bc(sa1), sa2v = f2bc(sa2);
        const f2_t v1v = f2bc(v1), v2v = f2bc(v2);
        f2_t nl = Sl[r] * lo2(K.E), nh = Sh[r] * hi2(K.E);
        nl = fma2(sa1v, lo2(K.B1e), nl); nh = fma2(sa1v, hi2(K.B1e), nh);
        nl = fma2(v1v, lo2(K.K1e), nl);  nh = fma2(v1v, hi2(K.K1e), nh);
        nl = fma2(sa2v, lo2(K.B2), nl);  nh = fma2(sa2v, hi2(K.B2), nh);
        nl = fma2(v2v, lo2(K.K2), nl);   nh = fma2(v2v, hi2(K.K2), nh);
        Sl[r] = nl; Sh[r] = nh;
    }
    o1v = (float4){o1a[0], o1a[1], o1a[2], o1a[3]};
    o2v = (float4){o2a[0], o2a[1], o2a[2], o2a[3]};
}

__global__ __launch_bounds__(64, 1) void out_scan(
    const float* __restrict__ pk, const float* __restrict__ Scbuf,
    float* __restrict__ y)
{
    const int b = blockIdx.x;
    const int h = b & 15;
    const int w = (b >> 4) & 3;
    const int c = b >> 6;
    const int l = threadIdx.x;
    const int q = l >> 4;
    const int j0 = (l & 15) * 4;
    const int rbase = w * 16 + q * 4;
    const int rb2 = 2 * rbase;
    const int cb = h * 64;
    const float* hbase = pk + ((size_t)h * 1024 + (size_t)c * CPAIR) * PAIR_F;
    const size_t cb64 = ((size_t)h * NCH + c) * 4096;

    f2_t Sl[4], Sh[4];
#pragma unroll
    for (int r = 0; r < 4; ++r) {
        float4 S4 = *(const float4*)(Scbuf + cb64 + (size_t)(rbase + r) * 64 + j0);
        Sl[r] = (f2_t){S4.x, S4.y};
        Sh[r] = (f2_t){S4.z, S4.w};
    }

    SlotO s0, s1, s2, s3;
    slot_load_o(s0, hbase + 0 * PAIR_F, j0, rb2);
    slot_load_o(s1, hbase + 1 * PAIR_F, j0, rb2);
    slot_load_o(s2, hbase + 2 * PAIR_F, j0, rb2);
    slot_load_o(s3, hbase + 3 * PAIR_F, j0, rb2);

    const bool wr = (l & 15) == 0;
    const int pi0 = c * CPAIR;
    float4 o1v, o2v;
#define OUT_STORE(pidx)                                                       \
    if (wr) {                                                                 \
        float* yp = y + (size_t)(2 * (pidx)) * C_DIM + cb + rbase;            \
        *(float4*)yp = o1v;                                                   \
        *(float4*)(yp + C_DIM) = o2v;                                         \
    }
    for (int i = 0; i < CPAIR - 4; i += 4) {
        const float* pl = hbase + (size_t)(i + 4) * PAIR_F;
        pair_out(Sl, Sh, s0, o1v, o2v);
        slot_load_o(s0, pl + 0 * PAIR_F, j0, rb2);
        OUT_STORE(pi0 + i)
        pair_out(Sl, Sh, s1, o1v, o2v);
        slot_load_o(s1, pl + 1 * PAIR_F, j0, rb2);
        OUT_STORE(pi0 + i + 1)
        pair_out(Sl, Sh, s2, o1v, o2v);
        slot_load_o(s2, pl + 2 * PAIR_F, j0, rb2);
        OUT_STORE(pi0 + i + 2)
        pair_out(Sl, Sh, s3, o1v, o2v);
        slot_load_o(s3, pl + 3 * PAIR_F, j0, rb2);
        OUT_STORE(pi0 + i + 3)
    }
    pair_out(Sl, Sh, s0, o1v, o2v); OUT_STORE(pi0 + CPAIR - 4)
    pair_out(Sl, Sh, s1, o1v, o2v); OUT_STORE(pi0 + CPAIR - 3)
    pair_out(Sl, Sh, s2, o1v, o2v); OUT_STORE(pi0 + CPAIR - 2)
    pair_out(Sl, Sh, s3, o1v, o2v); OUT_STORE(pi0 + CPAIR - 1)
#undef OUT_STORE
}

// ---------------------------------------------------------------------------
// GroupNorm + bonus + *g ; writes bf16 (xo*g) for the final MFMA GEMM.
// ---------------------------------------------------------------------------
__global__ __launch_bounds__(256) void gn_bonus(
    const float* __restrict__ y, const float* __restrict__ rb,
    const float* __restrict__ kb, const float* __restrict__ vb,
    const float* __restrict__ gb, const float* __restrict__ r_k,
    const float* __restrict__ lnw, const float* __restrict__ lnb,
    unsigned short* __restrict__ yg)
{
    const int t = blockIdx.x, tid = threadIdx.x;
    const int c0 = tid << 2;
    const size_t base = (size_t)t * C_DIM + c0;
    float4 yv = *(const float4*)(y + base);
    float sum = yv.x + yv.y + yv.z + yv.w;
    float ss  = yv.x * yv.x + yv.y * yv.y + yv.z * yv.z + yv.w * yv.w;
    float4 rv = *(const float4*)(rb + base);
    float4 kv = *(const float4*)(kb + base);
    float4 rkv = *(const float4*)(r_k + c0);
    float dot = rv.x * kv.x * rkv.x + rv.y * kv.y * rkv.y +
                rv.z * kv.z * rkv.z + rv.w * kv.w * rkv.w;
#pragma unroll
    for (int m = 1; m <= 8; m <<= 1) {
        sum += __shfl_xor(sum, m);
        ss  += __shfl_xor(ss, m);
        dot += __shfl_xor(dot, m);
    }
    const float mu = sum * 0.015625f;
    const float var = ss * 0.015625f - mu * mu;
    const float rstd = rsqrtf(var + 0.00064f);
    float4 wv = *(const float4*)(lnw + c0);
    float4 bv = *(const float4*)(lnb + c0);
    float4 vv = *(const float4*)(vb + base);
    float4 gv = *(const float4*)(gb + base);
    ushort4 o;
    o.x = f2bf(((yv.x - mu) * rstd * wv.x + bv.x + dot * vv.x) * gv.x);
    o.y = f2bf(((yv.y - mu) * rstd * wv.y + bv.y + dot * vv.y) * gv.y);
    o.z = f2bf(((yv.z - mu) * rstd * wv.z + bv.z + dot * vv.z) * gv.z);
    o.w = f2bf(((yv.w - mu) * rstd * wv.w + bv.w + dot * vv.w) * gv.w);
    *(ushort4*)(yg + base) = o;
}

// ---------------------------------------------------------------------------
extern "C" void kernel_launch(void* const* d_in, const int* in_sizes, int n_in,
                              void* d_out, int out_size, void* d_ws, size_t ws_size,
                              hipStream_t stream)
{
    (void)in_sizes; (void)n_in; (void)out_size; (void)ws_size;
    const float* x       = (const float*)d_in[0];
    const float* v_first = (const float*)d_in[1];
    const float* x_prev  = (const float*)d_in[2];
    const float* init_st = (const float*)d_in[3];
    const float* x_r = (const float*)d_in[4];
    const float* x_w = (const float*)d_in[5];
    const float* x_k = (const float*)d_in[6];
    const float* x_v = (const float*)d_in[7];
    const float* x_a = (const float*)d_in[8];
    const float* x_g = (const float*)d_in[9];
    const float* w0  = (const float*)d_in[10];
    const float* a0  = (const float*)d_in[11];
    const float* v0  = (const float*)d_in[12];
    const float* k_k = (const float*)d_in[13];
    const float* k_a = (const float*)d_in[14];
    const float* w1  = (const float*)d_in[15];
    const float* w2  = (const float*)d_in[16];
    const float* a1  = (const float*)d_in[17];
    const float* a2  = (const float*)d_in[18];
    const float* v1  = (const float*)d_in[19];
    const float* v2  = (const float*)d_in[20];
    const float* g1  = (const float*)d_in[21];
    const float* g2  = (const float*)d_in[22];
    const float* r_k = (const float*)d_in[23];
    const float* Wr  = (const float*)d_in[24];
    const float* Wk  = (const float*)d_in[25];
    const float* Wv  = (const float*)d_in[26];
    const float* Wo  = (const float*)d_in[27];
    const float* ln_w = (const float*)d_in[28];
    const float* ln_b = (const float*)d_in[29];

    float* out = (float*)d_out;
    float* ws  = (float*)d_ws;
    const size_t NE = (size_t)T_LEN * C_DIM;   // 2M
    const size_t WE = (size_t)C_DIM * C_DIM;   // 1M
    float* rB  = ws;
    float* kB  = ws + NE;
    float* vB  = ws + 2 * NE;
    float* gB  = ws + 3 * NE;
    float* hwB = ws + 4 * NE;                  // T*64
    float* haB = hwB + (size_t)T_LEN * 64;
    float* hvB = haB + (size_t)T_LEN * 64;
    float* hgB = hvB + (size_t)T_LEN * 32;     // h region < NE/2
    float* pk  = ws + 4 * NE + NE / 2;         // 6*NE floats (16*1024*768)
    unsigned short* b16 = (unsigned short*)(ws + 10 * NE + NE / 2);
    unsigned short* xr16 = b16;                // NE shorts
    unsigned short* xk16 = b16 + NE;
    unsigned short* xv16 = b16 + 2 * NE;
    unsigned short* Wr16 = b16 + 3 * NE;       // 4*WE shorts
    unsigned short* Wk16 = Wr16 + WE;
    unsigned short* Wv16 = Wr16 + 2 * WE;
    unsigned short* Wo16 = Wr16 + 3 * WE;
    unsigned short* yg16 = b16 + 3 * NE + 4 * WE;  // NE shorts
    unsigned short* lw16 = yg16 + NE;              // 320K shorts (LoRA weights)
    // xw/xa/xg bf16 live in the pk region (pk written later by lora2f)
    unsigned short* xw16 = (unsigned short*)pk;
    unsigned short* xa16 = xw16 + NE;
    unsigned short* xg16 = xw16 + 2 * NE;
    // yB aliases xr16/xk16 (consumed by gemms before the scan writes it)
    float* yB = (float*)xr16;
    // Chunk-scan buffers, aliased into regions dead by scan time:
    //   Pbuf  <- xv16   (dead after gemm3/lora1m)
    //   Cbuf  <- Wr16+Wk16 (dead after gemm3)
    //   Scbuf <- yg16   (gn_bonus writes it LATER)
    float* Pbuf  = (float*)xv16;   // 16h x 16c x 64 x 64
    float* Cbuf  = (float*)Wr16;
    float* Scbuf = (float*)yg16;

    wcvtall<<<4384, 256, 0, stream>>>(Wr, Wk, Wv, Wo, w1, a1, v1, g1,
                                      Wr16, lw16);
    xcvt<<<T_LEN, 256, 0, stream>>>(x, x_prev, x_r, x_k, x_v, x_w, x_a, x_g,
                                    xr16, xk16, xv16, xw16, xa16, xg16);

    gemm_bf16_3<<<dim3(16, 16, 3), 256, 0, stream>>>(
        xr16, xk16, xv16, Wr16, Wk16, Wv16, rB, kB, vB);

    lora1m<<<dim3(2, 16, 4), 256, 0, stream>>>(
        xw16, xa16, xv16, xg16, lw16, hwB, haB, hvB, hgB);

    lora2f<<<dim3(4, 256), 256, 0, stream>>>(
        hwB, haB, hvB, hgB, w2, a2, v2, g2, w0, a0, v0,
        k_k, k_a, v_first, rB, kB, vB, gB, pk);

    pc_fused<<<1024, 64, 0, stream>>>(pk, Pbuf, Cbuf);
    combine<<<256, 64, 0, stream>>>(Pbuf, Cbuf, init_st, Scbuf);
    out_scan<<<1024, 64, 0, stream>>>(pk, Scbuf, yB);

    gn_bonus<<<T_LEN, 256, 0, stream>>>(yB, rB, kB, vB, gB, r_k, ln_w, ln_b, yg16);
    gemm_bf16<<<dim3(16, 16), 256, 0, stream>>>(yg16, Wo16, out);
}

// Round 8
// 395.723 us; speedup vs baseline: 1.3023x; 1.0089x over previous
//
#include <hip/hip_runtime.h>

#define T_LEN 2048
#define C_DIM 1024
#define PAIR_F 768          // floats per (head, step-pair) packet
#define NCH 16              // chunks
#define CPAIR 64            // pairs per chunk (NCH*CPAIR = 1024)

#define AS1 __attribute__((address_space(1)))
#define AS3 __attribute__((address_space(3)))

typedef __attribute__((ext_vector_type(8))) short bf8_t;
typedef __attribute__((ext_vector_type(4))) float f4_t;
typedef __attribute__((ext_vector_type(2))) float f2_t;

static __device__ __forceinline__ float sigf(float x) {
    return 1.f / (1.f + __expf(-x));
}
static __device__ __forceinline__ unsigned short f2bf(float f) {
    unsigned u = __float_as_uint(f);
    u += 0x7fff + ((u >> 16) & 1);
    return (unsigned short)(u >> 16);
}

// ---- cross-lane reduction helpers (defined early; used by lora2f + scans) --
static __device__ __forceinline__ float red16(float x) {
    int xi;
    xi = __builtin_amdgcn_mov_dpp(__float_as_int(x), 0x128, 0xf, 0xf, true);
    x += __int_as_float(xi);
    xi = __builtin_amdgcn_mov_dpp(__float_as_int(x), 0x124, 0xf, 0xf, true);
    x += __int_as_float(xi);
    xi = __builtin_amdgcn_mov_dpp(__float_as_int(x), 0x122, 0xf, 0xf, true);
    x += __int_as_float(xi);
    xi = __builtin_amdgcn_mov_dpp(__float_as_int(x), 0x121, 0xf, 0xf, true);
    x += __int_as_float(xi);
    return x;
}
// full 64-lane sum: DPP within 16 (VALU pipe), then only 2 DS-ops
static __device__ __forceinline__ float red64(float x) {
    x = red16(x);
    x += __shfl_xor(x, 16);
    x += __shfl_xor(x, 32);
    return x;
}

static __device__ __forceinline__ f2_t f2bc(float s) { return (f2_t){s, s}; }
static __device__ __forceinline__ f2_t fma2(f2_t a, f2_t b, f2_t c) {
    return __builtin_elementwise_fma(a, b, c);
}
static __device__ __forceinline__ f2_t lo2(const float4& v) { return (f2_t){v.x, v.y}; }
static __device__ __forceinline__ f2_t hi2(const float4& v) { return (f2_t){v.z, v.w}; }

static __device__ __forceinline__ float dot4pk(f2_t Sl, f2_t Sh, const float4& A) {
    f2_t m = Sl * lo2(A);
    m = fma2(Sh, hi2(A), m);
    return m.x + m.y;
}

// ---------------------------------------------------------------------------
// Convert the four 1024x1024 fp32 weights into one bf16 block (1M strides),
// plus the transposed LoRA stage-1 weights (blocks 4096..4383).
// ---------------------------------------------------------------------------
__global__ __launch_bounds__(256) void wcvtall(
    const float* __restrict__ Wr, const float* __restrict__ Wk,
    const float* __restrict__ Wv, const float* __restrict__ Wo,
    const float* __restrict__ w1, const float* __restrict__ a1,
    const float* __restrict__ v1, const float* __restrict__ g1,
    unsigned short* __restrict__ dst, unsigned short* __restrict__ lw16)
{
    const int b = blockIdx.x;
    if (b < 4096) {
        const size_t idx = ((size_t)b * 256 + threadIdx.x) * 4;
        const int sel = (int)(idx >> 20);
        const float* src = sel == 0 ? Wr : sel == 1 ? Wk : sel == 2 ? Wv : Wo;
        float4 v = *(const float4*)(src + (idx & 0xFFFFF));
        ushort4 o = {f2bf(v.x), f2bf(v.y), f2bf(v.z), f2bf(v.w)};
        *(ushort4*)(dst + idx) = o;
        return;
    }
    const int row = b - 4096;         // 0..287
    const float* src; int Kh, i; unsigned short* dl;
    if (row < 64)       { src = w1; Kh = 64;  i = row;       dl = lw16 + (size_t)row * 1024; }
    else if (row < 128) { src = a1; Kh = 64;  i = row - 64;  dl = lw16 + (size_t)row * 1024; }
    else if (row < 160) { src = v1; Kh = 32;  i = row - 128; dl = lw16 + (size_t)(row - 128 + 128) * 1024; }
    else                { src = g1; Kh = 128; i = row - 160; dl = lw16 + (size_t)(row - 160 + 192) * 1024; }
    const int c0 = threadIdx.x * 4;
#pragma unroll
    for (int u = 0; u < 4; ++u)
        dl[c0 + u] = f2bf(src[(size_t)(c0 + u) * Kh + i]);
}

// ---------------------------------------------------------------------------
// Token-shift mix -> bf16 A-matrices for r/k/v projections and w/a/g LoRA.
// ---------------------------------------------------------------------------
__global__ __launch_bounds__(256) void xcvt(
    const float* __restrict__ x, const float* __restrict__ xprev,
    const float* __restrict__ x_r, const float* __restrict__ x_k,
    const float* __restrict__ x_v, const float* __restrict__ x_w,
    const float* __restrict__ x_a, const float* __restrict__ x_g,
    unsigned short* __restrict__ xr16, unsigned short* __restrict__ xk16,
    unsigned short* __restrict__ xv16, unsigned short* __restrict__ xw16,
    unsigned short* __restrict__ xa16, unsigned short* __restrict__ xg16)
{
    const int t = blockIdx.x;
    const int c0 = threadIdx.x * 4;
    const size_t base = (size_t)t * C_DIM + c0;
    float4 xv = *(const float4*)(x + base);
    float4 pv = (t == 0) ? *(const float4*)(xprev + c0)
                         : *(const float4*)(x + base - C_DIM);
    float4 dx = {pv.x - xv.x, pv.y - xv.y, pv.z - xv.z, pv.w - xv.w};
#define MIXOUT(mixp, dstp)                                                    \
    {                                                                          \
        float4 mv = *(const float4*)(mixp + c0);                               \
        ushort4 o = {f2bf(xv.x + dx.x * mv.x), f2bf(xv.y + dx.y * mv.y),       \
                     f2bf(xv.z + dx.z * mv.z), f2bf(xv.w + dx.w * mv.w)};      \
        *(ushort4*)(dstp + base) = o;                                          \
    }
    MIXOUT(x_r, xr16) MIXOUT(x_k, xk16) MIXOUT(x_v, xv16)
    MIXOUT(x_w, xw16) MIXOUT(x_a, xa16) MIXOUT(x_g, xg16)
#undef MIXOUT
}

// ---------------------------------------------------------------------------
// bf16 MFMA NT GEMM core: out[t,i] = sum_c A[t,c]*W[i,c], fp32 accumulate.
// ---------------------------------------------------------------------------
static __device__ __forceinline__ void gemm_core(
    const unsigned short* __restrict__ A, const unsigned short* __restrict__ W,
    float* __restrict__ out)
{
    __shared__ unsigned short Ab[2][128 * 32];
    __shared__ unsigned short Bb[2][64 * 32];
    const int tid = threadIdx.x;
    const int lane = tid & 63;
    const int w = tid >> 6;
    const int n0 = blockIdx.x * 64;
    const int t0 = blockIdx.y * 128;
    const int wm = (w & 1) * 64;
    const int wn = (w >> 1) * 32;
    const int srow = lane >> 2;
    const int scol = (lane & 3) * 8;

    f4_t acc[4][2];
#pragma unroll
    for (int i = 0; i < 4; ++i)
#pragma unroll
        for (int j = 0; j < 2; ++j)
            acc[i][j] = (f4_t){0.f, 0.f, 0.f, 0.f};

#pragma unroll
    for (int s = 0; s < 2; ++s) {
        const int i = 2 * w + s;
        __builtin_amdgcn_global_load_lds(
            (const AS1 unsigned int*)(A + (size_t)(t0 + i * 16 + srow) * 1024 + scol),
            (AS3 unsigned int*)(&Ab[0][i * 512 + lane * 8]), 16, 0, 0);
    }
    __builtin_amdgcn_global_load_lds(
        (const AS1 unsigned int*)(W + (size_t)(n0 + w * 16 + srow) * 1024 + scol),
        (AS3 unsigned int*)(&Bb[0][w * 512 + lane * 8]), 16, 0, 0);

    const int mrow = lane & 15;
    const int kq = (lane >> 4) * 8;
    for (int k0 = 0; k0 < 1024; k0 += 32) {
        const int cur = (k0 >> 5) & 1, nxt = cur ^ 1;
        __syncthreads();
        if (k0 + 32 < 1024) {
            const int k1 = k0 + 32;
#pragma unroll
            for (int s = 0; s < 2; ++s) {
                const int i = 2 * w + s;
                __builtin_amdgcn_global_load_lds(
                    (const AS1 unsigned int*)(A + (size_t)(t0 + i * 16 + srow) * 1024 + k1 + scol),
                    (AS3 unsigned int*)(&Ab[nxt][i * 512 + lane * 8]), 16, 0, 0);
            }
            __builtin_amdgcn_global_load_lds(
                (const AS1 unsigned int*)(W + (size_t)(n0 + w * 16 + srow) * 1024 + k1 + scol),
                (AS3 unsigned int*)(&Bb[nxt][w * 512 + lane * 8]), 16, 0, 0);
        }
        bf8_t af[4], bfr[2];
#pragma unroll
        for (int i = 0; i < 4; ++i)
            af[i] = *(const bf8_t*)(&Ab[cur][(wm + 16 * i + mrow) * 32 + kq]);
#pragma unroll
        for (int j = 0; j < 2; ++j)
            bfr[j] = *(const bf8_t*)(&Bb[cur][(wn + 16 * j + mrow) * 32 + kq]);
#pragma unroll
        for (int i = 0; i < 4; ++i)
#pragma unroll
            for (int j = 0; j < 2; ++j)
                acc[i][j] = __builtin_amdgcn_mfma_f32_16x16x32_bf16(
                    af[i], bfr[j], acc[i][j], 0, 0, 0);
    }
    const int crow = (lane >> 4) * 4;
    const int ccol = lane & 15;
#pragma unroll
    for (int i = 0; i < 4; ++i)
#pragma unroll
        for (int j = 0; j < 2; ++j)
#pragma unroll
            for (int u = 0; u < 4; ++u)
                out[(size_t)(t0 + wm + 16 * i + crow + u) * 1024
                    + n0 + wn + 16 * j + ccol] = acc[i][j][u];
}

__global__ __launch_bounds__(256) void gemm_bf16_3(
    const unsigned short* __restrict__ xr, const unsigned short* __restrict__ xk,
    const unsigned short* __restrict__ xv,
    const unsigned short* __restrict__ Wr, const unsigned short* __restrict__ Wk,
    const unsigned short* __restrict__ Wv,
    float* __restrict__ rB, float* __restrict__ kB, float* __restrict__ vB)
{
    const int z = blockIdx.z;
    const unsigned short* A = z == 0 ? xr : z == 1 ? xk : xv;
    const unsigned short* W = z == 0 ? Wr : z == 1 ? Wk : Wv;
    float* out = z == 0 ? rB : z == 1 ? kB : vB;
    gemm_core(A, W, out);
}

__global__ __launch_bounds__(256) void gemm_bf16(
    const unsigned short* __restrict__ A, const unsigned short* __restrict__ W,
    float* __restrict__ out)
{
    gemm_core(A, W, out);
}

// ---------------------------------------------------------------------------
// Fused LoRA stage-1 via MFMA: z = 0:w(tanh,N=64) 1:a(N=64) 2:v(N=32) 3:g(sig,N=128)
// ---------------------------------------------------------------------------
__global__ __launch_bounds__(256) void lora1m(
    const unsigned short* __restrict__ xw, const unsigned short* __restrict__ xa,
    const unsigned short* __restrict__ xv, const unsigned short* __restrict__ xg,
    const unsigned short* __restrict__ lw16,
    float* __restrict__ hw, float* __restrict__ ha, float* __restrict__ hv,
    float* __restrict__ hg)
{
    const int z = blockIdx.z;
    const unsigned short* A = z == 0 ? xw : z == 1 ? xa : z == 2 ? xv : xg;
    const unsigned short* W = lw16 + (size_t)(z == 0 ? 0 : z == 1 ? 64 : z == 2 ? 128 : 192) * 1024;
    float* out = z == 0 ? hw : z == 1 ? ha : z == 2 ? hv : hg;
    const int N  = z == 3 ? 128 : z == 2 ? 32 : 64;
    const int Ns = z == 3 ? 128 : 64;
    const int n0 = blockIdx.x * 64;
    if (n0 >= Ns) return;

    __shared__ unsigned short Ab[2][128 * 32];
    __shared__ unsigned short Bb[2][64 * 32];
    const int tid = threadIdx.x;
    const int lane = tid & 63;
    const int w = tid >> 6;
    const int t0 = blockIdx.y * 128;
    const int wm = (w & 1) * 64;
    const int wn = (w >> 1) * 32;
    const int srow = lane >> 2;
    const int scol = (lane & 3) * 8;

    f4_t acc[4][2];
#pragma unroll
    for (int i = 0; i < 4; ++i)
#pragma unroll
        for (int j = 0; j < 2; ++j)
            acc[i][j] = (f4_t){0.f, 0.f, 0.f, 0.f};

#pragma unroll
    for (int s = 0; s < 2; ++s) {
        const int i = 2 * w + s;
        __builtin_amdgcn_global_load_lds(
            (const AS1 unsigned int*)(A + (size_t)(t0 + i * 16 + srow) * 1024 + scol),
            (AS3 unsigned int*)(&Ab[0][i * 512 + lane * 8]), 16, 0, 0);
    }
    __builtin_amdgcn_global_load_lds(
        (const AS1 unsigned int*)(W + (size_t)(n0 + w * 16 + srow) * 1024 + scol),
        (AS3 unsigned int*)(&Bb[0][w * 512 + lane * 8]), 16, 0, 0);

    const int mrow = lane & 15;
    const int kq = (lane >> 4) * 8;
    for (int k0 = 0; k0 < 1024; k0 += 32) {
        const int cur = (k0 >> 5) & 1, nxt = cur ^ 1;
        __syncthreads();
        if (k0 + 32 < 1024) {
            const int k1 = k0 + 32;
#pragma unroll
            for (int s = 0; s < 2; ++s) {
                const int i = 2 * w + s;
                __builtin_amdgcn_global_load_lds(
                    (const AS1 unsigned int*)(A + (size_t)(t0 + i * 16 + srow) * 1024 + k1 + scol),
                    (AS3 unsigned int*)(&Ab[nxt][i * 512 + lane * 8]), 16, 0, 0);
            }
            __builtin_amdgcn_global_load_lds(
                (const AS1 unsigned int*)(W + (size_t)(n0 + w * 16 + srow) * 1024 + k1 + scol),
                (AS3 unsigned int*)(&Bb[nxt][w * 512 + lane * 8]), 16, 0, 0);
        }
        bf8_t af[4], bfr[2];
#pragma unroll
        for (int i = 0; i < 4; ++i)
            af[i] = *(const bf8_t*)(&Ab[cur][(wm + 16 * i + mrow) * 32 + kq]);
#pragma unroll
        for (int j = 0; j < 2; ++j)
            bfr[j] = *(const bf8_t*)(&Bb[cur][(wn + 16 * j + mrow) * 32 + kq]);
#pragma unroll
        for (int i = 0; i < 4; ++i)
#pragma unroll
            for (int j = 0; j < 2; ++j)
                acc[i][j] = __builtin_amdgcn_mfma_f32_16x16x32_bf16(
                    af[i], bfr[j], acc[i][j], 0, 0, 0);
    }
    const int crow = (lane >> 4) * 4;
    const int ccol = lane & 15;
#pragma unroll
    for (int i = 0; i < 4; ++i)
#pragma unroll
        for (int j = 0; j < 2; ++j) {
            const int col = n0 + wn + 16 * j + ccol;
            if (col < N) {
#pragma unroll
                for (int u = 0; u < 4; ++u) {
                    float vv = acc[i][j][u];
                    if (z == 0) vv = tanhf(vv);
                    else if (z == 3) vv = sigf(vv);
                    out[(size_t)(t0 + wm + 16 * i + crow + u) * N + col] = vv;
                }
            }
        }
}

// ---------------------------------------------------------------------------
// Fused LoRA-2 (w/a/v/g) + k post-process + PAIR-COMPOSED packet packing.
// r7 design (kept): no LDS; block-uniform h-reads via SMEM; red64 reduces.
// Packet layout (768 floats) unchanged from r4.
// ---------------------------------------------------------------------------
#define TOK 8
__global__ __launch_bounds__(256) void lora2f(
    const float* __restrict__ hwB, const float* __restrict__ haB,
    const float* __restrict__ hvB, const float* __restrict__ hgB,
    const float* __restrict__ w2, const float* __restrict__ a2,
    const float* __restrict__ v2, const float* __restrict__ g2,
    const float* __restrict__ w0, const float* __restrict__ a0,
    const float* __restrict__ v0,
    const float* __restrict__ k_k, const float* __restrict__ k_a,
    const float* __restrict__ v_first, const float* __restrict__ rB,
    float* __restrict__ kB, float* __restrict__ vB, float* __restrict__ gB,
    float* __restrict__ pk)
{
    const int tid = threadIdx.x;
    const int t0 = blockIdx.y * TOK;
    const int i  = blockIdx.x * 256 + tid;
    const int h  = i >> 6;
    const int j  = i & 63;

    float av[TOK], ew[TOK], vf[TOK];
    { // a = sigmoid(a0 + ha@a2)
        float acc[TOK];
        const float b0 = a0[i];
#pragma unroll
        for (int tt = 0; tt < TOK; ++tt) acc[tt] = b0;
        for (int jj = 0; jj < 64; jj += 4) {
            const float q0 = a2[(size_t)(jj + 0) * C_DIM + i];
            const float q1 = a2[(size_t)(jj + 1) * C_DIM + i];
            const float q2 = a2[(size_t)(jj + 2) * C_DIM + i];
            const float q3 = a2[(size_t)(jj + 3) * C_DIM + i];
#pragma unroll
            for (int tt = 0; tt < TOK; ++tt) {
                float4 h4 = *(const float4*)(haB + (size_t)(t0 + tt) * 64 + jj);
                acc[tt] = fmaf(h4.x, q0, acc[tt]);
                acc[tt] = fmaf(h4.y, q1, acc[tt]);
                acc[tt] = fmaf(h4.z, q2, acc[tt]);
                acc[tt] = fmaf(h4.w, q3, acc[tt]);
            }
        }
#pragma unroll
        for (int tt = 0; tt < TOK; ++tt) av[tt] = sigf(acc[tt]);
    }
    { // exp(w)
        float acc[TOK];
        const float b0 = w0[i];
#pragma unroll
        for (int tt = 0; tt < TOK; ++tt) acc[tt] = b0;
        for (int jj = 0; jj < 64; jj += 4) {
            const float q0 = w2[(size_t)(jj + 0) * C_DIM + i];
            const float q1 = w2[(size_t)(jj + 1) * C_DIM + i];
            const float q2 = w2[(size_t)(jj + 2) * C_DIM + i];
            const float q3 = w2[(size_t)(jj + 3) * C_DIM + i];
#pragma unroll
            for (int tt = 0; tt < TOK; ++tt) {
                float4 h4 = *(const float4*)(hwB + (size_t)(t0 + tt) * 64 + jj);
                acc[tt] = fmaf(h4.x, q0, acc[tt]);
                acc[tt] = fmaf(h4.y, q1, acc[tt]);
                acc[tt] = fmaf(h4.z, q2, acc[tt]);
                acc[tt] = fmaf(h4.w, q3, acc[tt]);
            }
        }
#pragma unroll
        for (int tt = 0; tt < TOK; ++tt)
            ew[tt] = __expf(-0.6065306597126334f * sigf(acc[tt]));
    }
    { // v mix
        float acc[TOK];
        const float b0 = v0[i];
#pragma unroll
        for (int tt = 0; tt < TOK; ++tt) acc[tt] = b0;
        for (int jj = 0; jj < 32; jj += 4) {
            const float q0 = v2[(size_t)(jj + 0) * C_DIM + i];
            const float q1 = v2[(size_t)(jj + 1) * C_DIM + i];
            const float q2 = v2[(size_t)(jj + 2) * C_DIM + i];
            const float q3 = v2[(size_t)(jj + 3) * C_DIM + i];
#pragma unroll
            for (int tt = 0; tt < TOK; ++tt) {
                float4 h4 = *(const float4*)(hvB + (size_t)(t0 + tt) * 32 + jj);
                acc[tt] = fmaf(h4.x, q0, acc[tt]);
                acc[tt] = fmaf(h4.y, q1, acc[tt]);
                acc[tt] = fmaf(h4.z, q2, acc[tt]);
                acc[tt] = fmaf(h4.w, q3, acc[tt]);
            }
        }
#pragma unroll
        for (int tt = 0; tt < TOK; ++tt) {
            const size_t gi = (size_t)(t0 + tt) * C_DIM + i;
            const float s = sigf(acc[tt]);
            const float vr = vB[gi];
            vf[tt] = vr + (v_first[gi] - vr) * s;
            vB[gi] = vf[tt];
        }
    }
    { // g
        float acc[TOK];
#pragma unroll
        for (int tt = 0; tt < TOK; ++tt) acc[tt] = 0.f;
        for (int jj = 0; jj < 128; jj += 4) {
            const float q0 = g2[(size_t)(jj + 0) * C_DIM + i];
            const float q1 = g2[(size_t)(jj + 1) * C_DIM + i];
            const float q2 = g2[(size_t)(jj + 2) * C_DIM + i];
            const float q3 = g2[(size_t)(jj + 3) * C_DIM + i];
#pragma unroll
            for (int tt = 0; tt < TOK; ++tt) {
                float4 h4 = *(const float4*)(hgB + (size_t)(t0 + tt) * 128 + jj);
                acc[tt] = fmaf(h4.x, q0, acc[tt]);
                acc[tt] = fmaf(h4.y, q1, acc[tt]);
                acc[tt] = fmaf(h4.z, q2, acc[tt]);
                acc[tt] = fmaf(h4.w, q3, acc[tt]);
            }
        }
#pragma unroll
        for (int tt = 0; tt < TOK; ++tt)
            gB[(size_t)(t0 + tt) * C_DIM + i] = acc[tt];
    }
    // k post-process + pair-composed packing
    const float kkw = k_k[i], kaw = k_a[i];
    const size_t pbase = (size_t)h * 1024 * PAIR_F;
    for (int pt = 0; pt < TOK / 2; ++pt) {
        float r_[2], e_[2], kf_[2], v_[2], aa_[2], bb_[2];
#pragma unroll
        for (int u = 0; u < 2; ++u) {
            const int tt = 2 * pt + u;
            const size_t gi = (size_t)(t0 + tt) * C_DIM + i;
            const float kraw = kB[gi];
            const float kn = kraw * kkw;
            const float ss = red64(kn * kn);
            const float sc = 1.f / fmaxf(sqrtf(ss), 1e-12f);
            const float kk = kn * sc;
            const float a_ = av[tt];
            const float kf = kraw * (1.f + (a_ - 1.f) * kaw);
            kB[gi] = kf;
            r_[u] = rB[gi];
            e_[u] = ew[tt];
            kf_[u] = kf;
            v_[u] = vf[tt];
            aa_[u] = -kk;
            bb_[u] = kk * a_;
        }
        const float E   = e_[0] * e_[1];
        const float A2e = e_[0] * aa_[1];
        const float B1e = bb_[0] * e_[1];
        const float K1e = kf_[0] * e_[1];
        const float R1e = e_[0] * r_[0];
        const float cba = red64(bb_[0] * aa_[1]);
        const float cka = red64(kf_[0] * aa_[1]);
        const float cbr = red64(bb_[0] * r_[0]);
        const float ckr = red64(kf_[0] * r_[0]);
        const float cbr2  = red64(B1e * r_[1]);
        const float ckr2  = red64(K1e * r_[1]);
        const float cb2r2 = red64(bb_[1] * r_[1]);
        const float ck2r2 = red64(kf_[1] * r_[1]);
        float* p = pk + pbase + (size_t)(blockIdx.y * (TOK / 2) + pt) * PAIR_F;
        p[j]        = E;
        p[64 + j]   = aa_[0];
        p[128 + j]  = A2e;
        p[192 + j]  = B1e;
        p[256 + j]  = K1e;
        p[320 + j]  = bb_[1];
        p[384 + j]  = kf_[1];
        p[448 + j]  = R1e;
        p[512 + j]  = E * r_[1];          // R2e = E ⊙ R2
        p[576 + 2 * j]     = v_[0];       // vv interleaved
        p[576 + 2 * j + 1] = v_[1];
        if (j == 0) {
            p[704] = cba;  p[705] = cka;  p[706] = cbr;  p[707] = ckr;
            p[708] = cbr2; p[709] = ckr2; p[710] = cb2r2; p[711] = ck2r2;
        }
    }
}

// ---------------------------------------------------------------------------
// CHUNKED SCAN (r6 structure). r8: the prefetch rings are PINNED with
// sched_barrier(0) after each slot_load — r7 PMC showed VGPR=124 (< 4-slot
// ring's ~216), proving the compiler remat'd loads at use and collapsed the
// prefetch distance (the r0/r1 pathology). pc_fused keeps the 4-slot ring
// (fits ~216 VGPR); out_scan drops to a 2-slot ring (4-slot would need ~278
// -> spill) with the same pinning.
// ---------------------------------------------------------------------------
struct SlotPC {
    float4 E, A1, A2e, B1e, K1e, B2, K2;
    float4 vva, vvb;   // {v1,v2} for rows rbase..rbase+3
    float4 sc;         // cba, cka, cbr, ckr (only x,y used here)
};

static __device__ __forceinline__ void slot_load_pc(
    SlotPC& K, const float* __restrict__ p, int j0, int rb2)
{
    K.E   = *(const float4*)(p + j0);
    K.A1  = *(const float4*)(p + 64 + j0);
    K.A2e = *(const float4*)(p + 128 + j0);
    K.B1e = *(const float4*)(p + 192 + j0);
    K.K1e = *(const float4*)(p + 256 + j0);
    K.B2  = *(const float4*)(p + 320 + j0);
    K.K2  = *(const float4*)(p + 384 + j0);
    K.vva = *(const float4*)(p + 576 + rb2);
    K.vvb = *(const float4*)(p + 576 + rb2 + 4);
    K.sc  = *(const float4*)(p + 704);
}

static __device__ __forceinline__ void pair_pc(
    f2_t* PSl, f2_t* PSh, f2_t* CSl, f2_t* CSh, const SlotPC& K)
{
    float pu1[4], pu2[4], cu1[4], cu2[4];
#pragma unroll
    for (int r = 0; r < 4; ++r) {
        pu1[r] = red16(dot4pk(PSl[r], PSh[r], K.A1));
        pu2[r] = red16(dot4pk(PSl[r], PSh[r], K.A2e));
        cu1[r] = red16(dot4pk(CSl[r], CSh[r], K.A1));
        cu2[r] = red16(dot4pk(CSl[r], CSh[r], K.A2e));
    }
#pragma unroll
    for (int r = 0; r < 4; ++r) {
        { // P update: v-terms exactly zero -> dropped (bitwise identical)
            const float sa1 = pu1[r];
            const float sa2 = fmaf(sa1, K.sc.x, pu2[r]);
            const f2_t sa1v = f2bc(sa1), sa2v = f2bc(sa2);
            f2_t nl = PSl[r] * lo2(K.E), nh = PSh[r] * hi2(K.E);
            nl = fma2(sa1v, lo2(K.B1e), nl); nh = fma2(sa1v, hi2(K.B1e), nh);
            nl = fma2(sa2v, lo2(K.B2), nl);  nh = fma2(sa2v, hi2(K.B2), nh);
            PSl[r] = nl; PSh[r] = nh;
        }
        { // C update: full recurrence from zero init
            const float v1 = r == 0 ? K.vva.x : r == 1 ? K.vva.z
                           : r == 2 ? K.vvb.x : K.vvb.z;
            const float v2 = r == 0 ? K.vva.y : r == 1 ? K.vva.w
                           : r == 2 ? K.vvb.y : K.vvb.w;
            const float sa1 = cu1[r];
            const float sa2 = fmaf(v1, K.sc.y, fmaf(sa1, K.sc.x, cu2[r]));
            const f2_t sa1v = f2bc(sa1), sa2v = f2bc(sa2);
            const f2_t v1v = f2bc(v1), v2v = f2bc(v2);
            f2_t nl = CSl[r] * lo2(K.E), nh = CSh[r] * hi2(K.E);
            nl = fma2(sa1v, lo2(K.B1e), nl); nh = fma2(sa1v, hi2(K.B1e), nh);
            nl = fma2(v1v, lo2(K.K1e), nl);  nh = fma2(v1v, hi2(K.K1e), nh);
            nl = fma2(sa2v, lo2(K.B2), nl);  nh = fma2(sa2v, hi2(K.B2), nh);
            nl = fma2(v2v, lo2(K.K2), nl);   nh = fma2(v2v, hi2(K.K2), nh);
            CSl[r] = nl; CSh[r] = nh;
        }
    }
}

// grid: b = h + 16*w + 64*c  (w stride 16 => same (h,c) on same XCD mod 8)
__global__ __launch_bounds__(64, 1) void pc_fused(
    const float* __restrict__ pk, float* __restrict__ Pbuf,
    float* __restrict__ Cbuf)
{
    const int b = blockIdx.x;
    const int h = b & 15;
    const int w = (b >> 4) & 3;
    const int c = b >> 6;
    const int l = threadIdx.x;
    const int q = l >> 4;
    const int j0 = (l & 15) * 4;
    const int rbase = w * 16 + q * 4;
    const int rb2 = 2 * rbase;
    const float* hbase = pk + ((size_t)h * 1024 + (size_t)c * CPAIR) * PAIR_F;

    f2_t PSl[4], PSh[4], CSl[4], CSh[4];
#pragma unroll
    for (int r = 0; r < 4; ++r) {
        const int row = rbase + r;
        PSl[r] = (f2_t){j0 == row ? 1.f : 0.f, j0 + 1 == row ? 1.f : 0.f};
        PSh[r] = (f2_t){j0 + 2 == row ? 1.f : 0.f, j0 + 3 == row ? 1.f : 0.f};
        CSl[r] = (f2_t){0.f, 0.f};
        CSh[r] = (f2_t){0.f, 0.f};
    }

    SlotPC s0, s1, s2, s3;
    slot_load_pc(s0, hbase + 0 * PAIR_F, j0, rb2);
    slot_load_pc(s1, hbase + 1 * PAIR_F, j0, rb2);
    slot_load_pc(s2, hbase + 2 * PAIR_F, j0, rb2);
    slot_load_pc(s3, hbase + 3 * PAIR_F, j0, rb2);
    __builtin_amdgcn_sched_barrier(0);

    for (int i = 0; i < CPAIR - 4; i += 4) {
        const float* pl = hbase + (size_t)(i + 4) * PAIR_F;
        // Pinned ring: loads for pair i+4 issue right after compute of pair i
        // and may NOT sink into later computes (keeps ~3.75-pair prefetch).
        pair_pc(PSl, PSh, CSl, CSh, s0); slot_load_pc(s0, pl + 0 * PAIR_F, j0, rb2);
        __builtin_amdgcn_sched_barrier(0);
        pair_pc(PSl, PSh, CSl, CSh, s1); slot_load_pc(s1, pl + 1 * PAIR_F, j0, rb2);
        __builtin_amdgcn_sched_barrier(0);
        pair_pc(PSl, PSh, CSl, CSh, s2); slot_load_pc(s2, pl + 2 * PAIR_F, j0, rb2);
        __builtin_amdgcn_sched_barrier(0);
        pair_pc(PSl, PSh, CSl, CSh, s3); slot_load_pc(s3, pl + 3 * PAIR_F, j0, rb2);
        __builtin_amdgcn_sched_barrier(0);
    }
    pair_pc(PSl, PSh, CSl, CSh, s0);
    pair_pc(PSl, PSh, CSl, CSh, s1);
    pair_pc(PSl, PSh, CSl, CSh, s2);
    pair_pc(PSl, PSh, CSl, CSh, s3);

    const size_t cb64 = ((size_t)h * NCH + c) * 4096;
#pragma unroll
    for (int r = 0; r < 4; ++r) {
        *(float4*)(Pbuf + cb64 + (size_t)(rbase + r) * 64 + j0) =
            (float4){PSl[r].x, PSl[r].y, PSh[r].x, PSh[r].y};
        *(float4*)(Cbuf + cb64 + (size_t)(rbase + r) * 64 + j0) =
            (float4){CSl[r].x, CSl[r].y, CSh[r].x, CSh[r].y};
    }
}

// Phase 2: serial chunk combine S <- S*P_c + C_c; stores each chunk's
// START state to Scbuf. 256 blocks (16 heads x 16 v-groups) x 64 thr.
__global__ __launch_bounds__(64) void combine(
    const float* __restrict__ Pbuf, const float* __restrict__ Cbuf,
    const float* __restrict__ init_state, float* __restrict__ Scbuf)
{
    const int b = blockIdx.x;
    const int h = b & 15;
    const int g = b >> 4;
    const int l = threadIdx.x;
    const int vl = l >> 4;
    const int vidx = g * 4 + vl;
    const int j0 = (l & 15) * 4;
    __shared__ __align__(16) float Pl[64 * 64];
    __shared__ __align__(16) float sl[4 * 64];

    float4 s = *(const float4*)(init_state + h * 4096 + vidx * 64 + j0);
    for (int c = 0; c < NCH; ++c) {
        const size_t cbase = ((size_t)h * NCH + c) * 4096;
        *(float4*)(Scbuf + cbase + (size_t)vidx * 64 + j0) = s;
        const float* Psrc = Pbuf + cbase;
#pragma unroll
        for (int t = 0; t < 16; ++t)
            *(float4*)(&Pl[t * 256 + l * 4]) = *(const float4*)(Psrc + t * 256 + l * 4);
        *(float4*)(&sl[vl * 64 + j0]) = s;
        __syncthreads();
        float4 Cv = *(const float4*)(Cbuf + cbase + (size_t)vidx * 64 + j0);
        f2_t al = {Cv.x, Cv.y}, ah = {Cv.z, Cv.w};
        for (int k = 0; k < 64; ++k) {
            const float sk = sl[vl * 64 + k];
            float4 Pr = *(const float4*)(&Pl[k * 64 + j0]);
            al = fma2(f2bc(sk), lo2(Pr), al);
            ah = fma2(f2bc(sk), hi2(Pr), ah);
        }
        s = (float4){al.x, al.y, ah.x, ah.y};
        __syncthreads();
    }
}

// ---- output scan: 4 rows/lane-group, 2-slot pinned ring -------------------
struct SlotO {
    float4 E, A1, A2e, B1e, K1e, B2, K2, R1e, R2e;
    float4 vva, vvb;
    float4 sc, sc2;
};

static __device__ __forceinline__ void slot_load_o(
    SlotO& K, const float* __restrict__ p, int j0, int rb2)
{
    K.E   = *(const float4*)(p + j0);
    K.A1  = *(const float4*)(p + 64 + j0);
    K.A2e = *(const float4*)(p + 128 + j0);
    K.B1e = *(const float4*)(p + 192 + j0);
    K.K1e = *(const float4*)(p + 256 + j0);
    K.B2  = *(const float4*)(p + 320 + j0);
    K.K2  = *(const float4*)(p + 384 + j0);
    K.R1e = *(const float4*)(p + 448 + j0);
    K.R2e = *(const float4*)(p + 512 + j0);
    K.vva = *(const float4*)(p + 576 + rb2);
    K.vvb = *(const float4*)(p + 576 + rb2 + 4);
    K.sc  = *(const float4*)(p + 704);
    K.sc2 = *(const float4*)(p + 708);
}

static __device__ __forceinline__ void pair_out(
    f2_t* Sl, f2_t* Sh, const SlotO& K, float4& o1v, float4& o2v)
{
    float u1[4], u2[4], op[4], oz[4];
#pragma unroll
    for (int r = 0; r < 4; ++r) {
        u1[r] = red16(dot4pk(Sl[r], Sh[r], K.A1));
        u2[r] = red16(dot4pk(Sl[r], Sh[r], K.A2e));
        op[r] = red16(dot4pk(Sl[r], Sh[r], K.R1e));
        oz[r] = red16(dot4pk(Sl[r], Sh[r], K.R2e));
    }
    float o1a[4], o2a[4];
#pragma unroll
    for (int r = 0; r < 4; ++r) {
        const float v1 = r == 0 ? K.vva.x : r == 1 ? K.vva.z
                       : r == 2 ? K.vvb.x : K.vvb.z;
        const float v2 = r == 0 ? K.vva.y : r == 1 ? K.vva.w
                       : r == 2 ? K.vvb.y : K.vvb.w;
        const float sa1 = u1[r];
        const float sa2 = fmaf(v1, K.sc.y, fmaf(sa1, K.sc.x, u2[r]));
        o1a[r] = fmaf(v1, K.sc.w, fmaf(sa1, K.sc.z, op[r]));
        o2a[r] = fmaf(v2, K.sc2.w, fmaf(sa2, K.sc2.z,
                 fmaf(v1, K.sc2.y, fmaf(sa1, K.sc2.x, oz[r]))));
        const f2_t sa1v = f2bc(sa1), sa2v = f2bc(sa2);
        const f2_t v1v = f2bc(v1), v2v = f2bc(v2);
        f2_t nl = Sl[r] * lo2(K.E), nh = Sh[r] * hi2(K.E);
        nl = fma2(sa1v, lo2(K.B1e), nl); nh = fma2(sa1v, hi2(K.B1e), nh);
        nl = fma2(v1v, lo2(K.K1e), nl);  nh = fma2(v1v, hi2(K.K1e), nh);
        nl = fma2(sa2v, lo2(K.B2), nl);  nh = fma2(sa2v, hi2(K.B2), nh);
        nl = fma2(v2v, lo2(K.K2), nl);   nh = fma2(v2v, hi2(K.K2), nh);
        Sl[r] = nl; Sh[r] = nh;
    }
    o1v = (float4){o1a[0], o1a[1], o1a[2], o1a[3]};
    o2v = (float4){o2a[0], o2a[1], o2a[2], o2a[3]};
}

__global__ __launch_bounds__(64, 1) void out_scan(
    const float* __restrict__ pk, const float* __restrict__ Scbuf,
    float* __restrict__ y)
{
    const int b = blockIdx.x;
    const int h = b & 15;
    const int w = (b >> 4) & 3;
    const int c = b >> 6;
    const int l = threadIdx.x;
    const int q = l >> 4;
    const int j0 = (l & 15) * 4;
    const int rbase = w * 16 + q * 4;
    const int rb2 = 2 * rbase;
    const int cb = h * 64;
    const float* hbase = pk + ((size_t)h * 1024 + (size_t)c * CPAIR) * PAIR_F;
    const size_t cb64 = ((size_t)h * NCH + c) * 4096;

    f2_t Sl[4], Sh[4];
#pragma unroll
    for (int r = 0; r < 4; ++r) {
        float4 S4 = *(const float4*)(Scbuf + cb64 + (size_t)(rbase + r) * 64 + j0);
        Sl[r] = (f2_t){S4.x, S4.y};
        Sh[r] = (f2_t){S4.z, S4.w};
    }

    SlotO s0, s1;
    slot_load_o(s0, hbase + 0 * PAIR_F, j0, rb2);
    slot_load_o(s1, hbase + 1 * PAIR_F, j0, rb2);
    __builtin_amdgcn_sched_barrier(0);

    const bool wr = (l & 15) == 0;
    const int pi0 = c * CPAIR;
    float4 o1v, o2v;
#define OUT_STORE(pidx)                                                       \
    if (wr) {                                                                 \
        float* yp = y + (size_t)(2 * (pidx)) * C_DIM + cb + rbase;            \
        *(float4*)yp = o1v;                                                   \
        *(float4*)(yp + C_DIM) = o2v;                                         \
    }
    for (int i = 0; i < CPAIR - 2; i += 2) {
        // 2-slot pinned ring: load for pair i+2 issues right after compute
        // of pair i; sched_barrier stops it sinking into pair i+1's compute.
        pair_out(Sl, Sh, s0, o1v, o2v);
        slot_load_o(s0, hbase + (size_t)(i + 2) * PAIR_F, j0, rb2);
        __builtin_amdgcn_sched_barrier(0);
        OUT_STORE(pi0 + i)
        pair_out(Sl, Sh, s1, o1v, o2v);
        if (i + 3 < CPAIR)
            slot_load_o(s1, hbase + (size_t)(i + 3) * PAIR_F, j0, rb2);
        __builtin_amdgcn_sched_barrier(0);
        OUT_STORE(pi0 + i + 1)
    }
    pair_out(Sl, Sh, s0, o1v, o2v);
    OUT_STORE(pi0 + CPAIR - 2)
    pair_out(Sl, Sh, s1, o1v, o2v);
    OUT_STORE(pi0 + CPAIR - 1)
#undef OUT_STORE
}

// ---------------------------------------------------------------------------
// GroupNorm + bonus + *g ; writes bf16 (xo*g) for the final MFMA GEMM.
// ---------------------------------------------------------------------------
__global__ __launch_bounds__(256) void gn_bonus(
    const float* __restrict__ y, const float* __restrict__ rb,
    const float* __restrict__ kb, const float* __restrict__ vb,
    const float* __restrict__ gb, const float* __restrict__ r_k,
    const float* __restrict__ lnw, const float* __restrict__ lnb,
    unsigned short* __restrict__ yg)
{
    const int t = blockIdx.x, tid = threadIdx.x;
    const int c0 = tid << 2;
    const size_t base = (size_t)t * C_DIM + c0;
    float4 yv = *(const float4*)(y + base);
    float sum = yv.x + yv.y + yv.z + yv.w;
    float ss  = yv.x * yv.x + yv.y * yv.y + yv.z * yv.z + yv.w * yv.w;
    float4 rv = *(const float4*)(rb + base);
    float4 kv = *(const float4*)(kb + base);
    float4 rkv = *(const float4*)(r_k + c0);
    float dot = rv.x * kv.x * rkv.x + rv.y * kv.y * rkv.y +
                rv.z * kv.z * rkv.z + rv.w * kv.w * rkv.w;
#pragma unroll
    for (int m = 1; m <= 8; m <<= 1) {
        sum += __shfl_xor(sum, m);
        ss  += __shfl_xor(ss, m);
        dot += __shfl_xor(dot, m);
    }
    const float mu = sum * 0.015625f;
    const float var = ss * 0.015625f - mu * mu;
    const float rstd = rsqrtf(var + 0.00064f);
    float4 wv = *(const float4*)(lnw + c0);
    float4 bv = *(const float4*)(lnb + c0);
    float4 vv = *(const float4*)(vb + base);
    float4 gv = *(const float4*)(gb + base);
    ushort4 o;
    o.x = f2bf(((yv.x - mu) * rstd * wv.x + bv.x + dot * vv.x) * gv.x);
    o.y = f2bf(((yv.y - mu) * rstd * wv.y + bv.y + dot * vv.y) * gv.y);
    o.z = f2bf(((yv.z - mu) * rstd * wv.z + bv.z + dot * vv.z) * gv.z);
    o.w = f2bf(((yv.w - mu) * rstd * wv.w + bv.w + dot * vv.w) * gv.w);
    *(ushort4*)(yg + base) = o;
}

// ---------------------------------------------------------------------------
extern "C" void kernel_launch(void* const* d_in, const int* in_sizes, int n_in,
                              void* d_out, int out_size, void* d_ws, size_t ws_size,
                              hipStream_t stream)
{
    (void)in_sizes; (void)n_in; (void)out_size; (void)ws_size;
    const float* x       = (const float*)d_in[0];
    const float* v_first = (const float*)d_in[1];
    const float* x_prev  = (const float*)d_in[2];
    const float* init_st = (const float*)d_in[3];
    const float* x_r = (const float*)d_in[4];
    const float* x_w = (const float*)d_in[5];
    const float* x_k = (const float*)d_in[6];
    const float* x_v = (const float*)d_in[7];
    const float* x_a = (const float*)d_in[8];
    const float* x_g = (const float*)d_in[9];
    const float* w0  = (const float*)d_in[10];
    const float* a0  = (const float*)d_in[11];
    const float* v0  = (const float*)d_in[12];
    const float* k_k = (const float*)d_in[13];
    const float* k_a = (const float*)d_in[14];
    const float* w1  = (const float*)d_in[15];
    const float* w2  = (const float*)d_in[16];
    const float* a1  = (const float*)d_in[17];
    const float* a2  = (const float*)d_in[18];
    const float* v1  = (const float*)d_in[19];
    const float* v2  = (const float*)d_in[20];
    const float* g1  = (const float*)d_in[21];
    const float* g2  = (const float*)d_in[22];
    const float* r_k = (const float*)d_in[23];
    const float* Wr  = (const float*)d_in[24];
    const float* Wk  = (const float*)d_in[25];
    const float* Wv  = (const float*)d_in[26];
    const float* Wo  = (const float*)d_in[27];
    const float* ln_w = (const float*)d_in[28];
    const float* ln_b = (const float*)d_in[29];

    float* out = (float*)d_out;
    float* ws  = (float*)d_ws;
    const size_t NE = (size_t)T_LEN * C_DIM;   // 2M
    const size_t WE = (size_t)C_DIM * C_DIM;   // 1M
    float* rB  = ws;
    float* kB  = ws + NE;
    float* vB  = ws + 2 * NE;
    float* gB  = ws + 3 * NE;
    float* hwB = ws + 4 * NE;                  // T*64
    float* haB = hwB + (size_t)T_LEN * 64;
    float* hvB = haB + (size_t)T_LEN * 64;
    float* hgB = hvB + (size_t)T_LEN * 32;     // h region < NE/2
    float* pk  = ws + 4 * NE + NE / 2;         // 6*NE floats (16*1024*768)
    unsigned short* b16 = (unsigned short*)(ws + 10 * NE + NE / 2);
    unsigned short* xr16 = b16;                // NE shorts
    unsigned short* xk16 = b16 + NE;
    unsigned short* xv16 = b16 + 2 * NE;
    unsigned short* Wr16 = b16 + 3 * NE;       // 4*WE shorts
    unsigned short* Wk16 = Wr16 + WE;
    unsigned short* Wv16 = Wr16 + 2 * WE;
    unsigned short* Wo16 = Wr16 + 3 * WE;
    unsigned short* yg16 = b16 + 3 * NE + 4 * WE;  // NE shorts
    unsigned short* lw16 = yg16 + NE;              // 320K shorts (LoRA weights)
    // xw/xa/xg bf16 live in the pk region (pk written later by lora2f)
    unsigned short* xw16 = (unsigned short*)pk;
    unsigned short* xa16 = xw16 + NE;
    unsigned short* xg16 = xw16 + 2 * NE;
    // yB aliases xr16/xk16 (consumed by gemms before the scan writes it)
    float* yB = (float*)xr16;
    // Chunk-scan buffers, aliased into regions dead by scan time:
    //   Pbuf  <- xv16   (dead after gemm3/lora1m)
    //   Cbuf  <- Wr16+Wk16 (dead after gemm3)
    //   Scbuf <- yg16   (gn_bonus writes it LATER)
    float* Pbuf  = (float*)xv16;   // 16h x 16c x 64 x 64
    float* Cbuf  = (float*)Wr16;
    float* Scbuf = (float*)yg16;

    wcvtall<<<4384, 256, 0, stream>>>(Wr, Wk, Wv, Wo, w1, a1, v1, g1,
                                      Wr16, lw16);
    xcvt<<<T_LEN, 256, 0, stream>>>(x, x_prev, x_r, x_k, x_v, x_w, x_a, x_g,
                                    xr16, xk16, xv16, xw16, xa16, xg16);

    gemm_bf16_3<<<dim3(16, 16, 3), 256, 0, stream>>>(
        xr16, xk16, xv16, Wr16, Wk16, Wv16, rB, kB, vB);

    lora1m<<<dim3(2, 16, 4), 256, 0, stream>>>(
        xw16, xa16, xv16, xg16, lw16, hwB, haB, hvB, hgB);

    lora2f<<<dim3(4, 256), 256, 0, stream>>>(
        hwB, haB, hvB, hgB, w2, a2, v2, g2, w0, a0, v0,
        k_k, k_a, v_first, rB, kB, vB, gB, pk);

    pc_fused<<<1024, 64, 0, stream>>>(pk, Pbuf, Cbuf);
    combine<<<256, 64, 0, stream>>>(Pbuf, Cbuf, init_st, Scbuf);
    out_scan<<<1024, 64, 0, stream>>>(pk, Scbuf, yB);

    gn_bonus<<<T_LEN, 256, 0, stream>>>(yB, rB, kB, vB, gB, r_k, ln_w, ln_b, yg16);
    gemm_bf16<<<dim3(16, 16), 256, 0, stream>>>(yg16, Wo16, out);
}

// Round 9
// 394.137 us; speedup vs baseline: 1.3075x; 1.0040x over previous
//
#include <hip/hip_runtime.h>

#define T_LEN 2048
#define C_DIM 1024
#define PAIR_F 768          // floats per (head, step-pair) packet
#define NCH 32              // chunks (r9: 16->32, doubles scan-phase waves)
#define CPAIR 32            // pairs per chunk (NCH*CPAIR = 1024)

#define AS1 __attribute__((address_space(1)))
#define AS3 __attribute__((address_space(3)))

typedef __attribute__((ext_vector_type(8))) short bf8_t;
typedef __attribute__((ext_vector_type(4))) float f4_t;
typedef __attribute__((ext_vector_type(2))) float f2_t;

static __device__ __forceinline__ float sigf(float x) {
    return 1.f / (1.f + __expf(-x));
}
static __device__ __forceinline__ unsigned short f2bf(float f) {
    unsigned u = __float_as_uint(f);
    u += 0x7fff + ((u >> 16) & 1);
    return (unsigned short)(u >> 16);
}

// ---- cross-lane reduction helpers (defined early; used by lora2f + scans) --
static __device__ __forceinline__ float red16(float x) {
    int xi;
    xi = __builtin_amdgcn_mov_dpp(__float_as_int(x), 0x128, 0xf, 0xf, true);
    x += __int_as_float(xi);
    xi = __builtin_amdgcn_mov_dpp(__float_as_int(x), 0x124, 0xf, 0xf, true);
    x += __int_as_float(xi);
    xi = __builtin_amdgcn_mov_dpp(__float_as_int(x), 0x122, 0xf, 0xf, true);
    x += __int_as_float(xi);
    xi = __builtin_amdgcn_mov_dpp(__float_as_int(x), 0x121, 0xf, 0xf, true);
    x += __int_as_float(xi);
    return x;
}
// full 64-lane sum: DPP within 16 (VALU pipe), then only 2 DS-ops
static __device__ __forceinline__ float red64(float x) {
    x = red16(x);
    x += __shfl_xor(x, 16);
    x += __shfl_xor(x, 32);
    return x;
}

static __device__ __forceinline__ f2_t f2bc(float s) { return (f2_t){s, s}; }
static __device__ __forceinline__ f2_t fma2(f2_t a, f2_t b, f2_t c) {
    return __builtin_elementwise_fma(a, b, c);
}
static __device__ __forceinline__ f2_t lo2(const float4& v) { return (f2_t){v.x, v.y}; }
static __device__ __forceinline__ f2_t hi2(const float4& v) { return (f2_t){v.z, v.w}; }

static __device__ __forceinline__ float dot4pk(f2_t Sl, f2_t Sh, const float4& A) {
    f2_t m = Sl * lo2(A);
    m = fma2(Sh, hi2(A), m);
    return m.x + m.y;
}

// ---------------------------------------------------------------------------
// Convert the four 1024x1024 fp32 weights into one bf16 block (1M strides),
// plus the transposed LoRA stage-1 weights (blocks 4096..4383).
// ---------------------------------------------------------------------------
__global__ __launch_bounds__(256) void wcvtall(
    const float* __restrict__ Wr, const float* __restrict__ Wk,
    const float* __restrict__ Wv, const float* __restrict__ Wo,
    const float* __restrict__ w1, const float* __restrict__ a1,
    const float* __restrict__ v1, const float* __restrict__ g1,
    unsigned short* __restrict__ dst, unsigned short* __restrict__ lw16)
{
    const int b = blockIdx.x;
    if (b < 4096) {
        const size_t idx = ((size_t)b * 256 + threadIdx.x) * 4;
        const int sel = (int)(idx >> 20);
        const float* src = sel == 0 ? Wr : sel == 1 ? Wk : sel == 2 ? Wv : Wo;
        float4 v = *(const float4*)(src + (idx & 0xFFFFF));
        ushort4 o = {f2bf(v.x), f2bf(v.y), f2bf(v.z), f2bf(v.w)};
        *(ushort4*)(dst + idx) = o;
        return;
    }
    const int row = b - 4096;         // 0..287
    const float* src; int Kh, i; unsigned short* dl;
    if (row < 64)       { src = w1; Kh = 64;  i = row;       dl = lw16 + (size_t)row * 1024; }
    else if (row < 128) { src = a1; Kh = 64;  i = row - 64;  dl = lw16 + (size_t)row * 1024; }
    else if (row < 160) { src = v1; Kh = 32;  i = row - 128; dl = lw16 + (size_t)(row - 128 + 128) * 1024; }
    else                { src = g1; Kh = 128; i = row - 160; dl = lw16 + (size_t)(row - 160 + 192) * 1024; }
    const int c0 = threadIdx.x * 4;
#pragma unroll
    for (int u = 0; u < 4; ++u)
        dl[c0 + u] = f2bf(src[(size_t)(c0 + u) * Kh + i]);
}

// ---------------------------------------------------------------------------
// Token-shift mix -> bf16 A-matrices for r/k/v projections and w/a/g LoRA.
// ---------------------------------------------------------------------------
__global__ __launch_bounds__(256) void xcvt(
    const float* __restrict__ x, const float* __restrict__ xprev,
    const float* __restrict__ x_r, const float* __restrict__ x_k,
    const float* __restrict__ x_v, const float* __restrict__ x_w,
    const float* __restrict__ x_a, const float* __restrict__ x_g,
    unsigned short* __restrict__ xr16, unsigned short* __restrict__ xk16,
    unsigned short* __restrict__ xv16, unsigned short* __restrict__ xw16,
    unsigned short* __restrict__ xa16, unsigned short* __restrict__ xg16)
{
    const int t = blockIdx.x;
    const int c0 = threadIdx.x * 4;
    const size_t base = (size_t)t * C_DIM + c0;
    float4 xv = *(const float4*)(x + base);
    float4 pv = (t == 0) ? *(const float4*)(xprev + c0)
                         : *(const float4*)(x + base - C_DIM);
    float4 dx = {pv.x - xv.x, pv.y - xv.y, pv.z - xv.z, pv.w - xv.w};
#define MIXOUT(mixp, dstp)                                                    \
    {                                                                          \
        float4 mv = *(const float4*)(mixp + c0);                               \
        ushort4 o = {f2bf(xv.x + dx.x * mv.x), f2bf(xv.y + dx.y * mv.y),       \
                     f2bf(xv.z + dx.z * mv.z), f2bf(xv.w + dx.w * mv.w)};      \
        *(ushort4*)(dstp + base) = o;                                          \
    }
    MIXOUT(x_r, xr16) MIXOUT(x_k, xk16) MIXOUT(x_v, xv16)
    MIXOUT(x_w, xw16) MIXOUT(x_a, xa16) MIXOUT(x_g, xg16)
#undef MIXOUT
}

// ---------------------------------------------------------------------------
// bf16 MFMA NT GEMM core: out[t,i] = sum_c A[t,c]*W[i,c], fp32 accumulate.
// ---------------------------------------------------------------------------
static __device__ __forceinline__ void gemm_core(
    const unsigned short* __restrict__ A, const unsigned short* __restrict__ W,
    float* __restrict__ out)
{
    __shared__ unsigned short Ab[2][128 * 32];
    __shared__ unsigned short Bb[2][64 * 32];
    const int tid = threadIdx.x;
    const int lane = tid & 63;
    const int w = tid >> 6;
    const int n0 = blockIdx.x * 64;
    const int t0 = blockIdx.y * 128;
    const int wm = (w & 1) * 64;
    const int wn = (w >> 1) * 32;
    const int srow = lane >> 2;
    const int scol = (lane & 3) * 8;

    f4_t acc[4][2];
#pragma unroll
    for (int i = 0; i < 4; ++i)
#pragma unroll
        for (int j = 0; j < 2; ++j)
            acc[i][j] = (f4_t){0.f, 0.f, 0.f, 0.f};

#pragma unroll
    for (int s = 0; s < 2; ++s) {
        const int i = 2 * w + s;
        __builtin_amdgcn_global_load_lds(
            (const AS1 unsigned int*)(A + (size_t)(t0 + i * 16 + srow) * 1024 + scol),
            (AS3 unsigned int*)(&Ab[0][i * 512 + lane * 8]), 16, 0, 0);
    }
    __builtin_amdgcn_global_load_lds(
        (const AS1 unsigned int*)(W + (size_t)(n0 + w * 16 + srow) * 1024 + scol),
        (AS3 unsigned int*)(&Bb[0][w * 512 + lane * 8]), 16, 0, 0);

    const int mrow = lane & 15;
    const int kq = (lane >> 4) * 8;
    for (int k0 = 0; k0 < 1024; k0 += 32) {
        const int cur = (k0 >> 5) & 1, nxt = cur ^ 1;
        __syncthreads();
        if (k0 + 32 < 1024) {
            const int k1 = k0 + 32;
#pragma unroll
            for (int s = 0; s < 2; ++s) {
                const int i = 2 * w + s;
                __builtin_amdgcn_global_load_lds(
                    (const AS1 unsigned int*)(A + (size_t)(t0 + i * 16 + srow) * 1024 + k1 + scol),
                    (AS3 unsigned int*)(&Ab[nxt][i * 512 + lane * 8]), 16, 0, 0);
            }
            __builtin_amdgcn_global_load_lds(
                (const AS1 unsigned int*)(W + (size_t)(n0 + w * 16 + srow) * 1024 + k1 + scol),
                (AS3 unsigned int*)(&Bb[nxt][w * 512 + lane * 8]), 16, 0, 0);
        }
        bf8_t af[4], bfr[2];
#pragma unroll
        for (int i = 0; i < 4; ++i)
            af[i] = *(const bf8_t*)(&Ab[cur][(wm + 16 * i + mrow) * 32 + kq]);
#pragma unroll
        for (int j = 0; j < 2; ++j)
            bfr[j] = *(const bf8_t*)(&Bb[cur][(wn + 16 * j + mrow) * 32 + kq]);
#pragma unroll
        for (int i = 0; i < 4; ++i)
#pragma unroll
            for (int j = 0; j < 2; ++j)
                acc[i][j] = __builtin_amdgcn_mfma_f32_16x16x32_bf16(
                    af[i], bfr[j], acc[i][j], 0, 0, 0);
    }
    const int crow = (lane >> 4) * 4;
    const int ccol = lane & 15;
#pragma unroll
    for (int i = 0; i < 4; ++i)
#pragma unroll
        for (int j = 0; j < 2; ++j)
#pragma unroll
            for (int u = 0; u < 4; ++u)
                out[(size_t)(t0 + wm + 16 * i + crow + u) * 1024
                    + n0 + wn + 16 * j + ccol] = acc[i][j][u];
}

__global__ __launch_bounds__(256) void gemm_bf16_3(
    const unsigned short* __restrict__ xr, const unsigned short* __restrict__ xk,
    const unsigned short* __restrict__ xv,
    const unsigned short* __restrict__ Wr, const unsigned short* __restrict__ Wk,
    const unsigned short* __restrict__ Wv,
    float* __restrict__ rB, float* __restrict__ kB, float* __restrict__ vB)
{
    const int z = blockIdx.z;
    const unsigned short* A = z == 0 ? xr : z == 1 ? xk : xv;
    const unsigned short* W = z == 0 ? Wr : z == 1 ? Wk : Wv;
    float* out = z == 0 ? rB : z == 1 ? kB : vB;
    gemm_core(A, W, out);
}

__global__ __launch_bounds__(256) void gemm_bf16(
    const unsigned short* __restrict__ A, const unsigned short* __restrict__ W,
    float* __restrict__ out)
{
    gemm_core(A, W, out);
}

// ---------------------------------------------------------------------------
// Fused LoRA stage-1 via MFMA: z = 0:w(tanh,N=64) 1:a(N=64) 2:v(N=32) 3:g(sig,N=128)
// ---------------------------------------------------------------------------
__global__ __launch_bounds__(256) void lora1m(
    const unsigned short* __restrict__ xw, const unsigned short* __restrict__ xa,
    const unsigned short* __restrict__ xv, const unsigned short* __restrict__ xg,
    const unsigned short* __restrict__ lw16,
    float* __restrict__ hw, float* __restrict__ ha, float* __restrict__ hv,
    float* __restrict__ hg)
{
    const int z = blockIdx.z;
    const unsigned short* A = z == 0 ? xw : z == 1 ? xa : z == 2 ? xv : xg;
    const unsigned short* W = lw16 + (size_t)(z == 0 ? 0 : z == 1 ? 64 : z == 2 ? 128 : 192) * 1024;
    float* out = z == 0 ? hw : z == 1 ? ha : z == 2 ? hv : hg;
    const int N  = z == 3 ? 128 : z == 2 ? 32 : 64;
    const int Ns = z == 3 ? 128 : 64;
    const int n0 = blockIdx.x * 64;
    if (n0 >= Ns) return;

    __shared__ unsigned short Ab[2][128 * 32];
    __shared__ unsigned short Bb[2][64 * 32];
    const int tid = threadIdx.x;
    const int lane = tid & 63;
    const int w = tid >> 6;
    const int t0 = blockIdx.y * 128;
    const int wm = (w & 1) * 64;
    const int wn = (w >> 1) * 32;
    const int srow = lane >> 2;
    const int scol = (lane & 3) * 8;

    f4_t acc[4][2];
#pragma unroll
    for (int i = 0; i < 4; ++i)
#pragma unroll
        for (int j = 0; j < 2; ++j)
            acc[i][j] = (f4_t){0.f, 0.f, 0.f, 0.f};

#pragma unroll
    for (int s = 0; s < 2; ++s) {
        const int i = 2 * w + s;
        __builtin_amdgcn_global_load_lds(
            (const AS1 unsigned int*)(A + (size_t)(t0 + i * 16 + srow) * 1024 + scol),
            (AS3 unsigned int*)(&Ab[0][i * 512 + lane * 8]), 16, 0, 0);
    }
    __builtin_amdgcn_global_load_lds(
        (const AS1 unsigned int*)(W + (size_t)(n0 + w * 16 + srow) * 1024 + scol),
        (AS3 unsigned int*)(&Bb[0][w * 512 + lane * 8]), 16, 0, 0);

    const int mrow = lane & 15;
    const int kq = (lane >> 4) * 8;
    for (int k0 = 0; k0 < 1024; k0 += 32) {
        const int cur = (k0 >> 5) & 1, nxt = cur ^ 1;
        __syncthreads();
        if (k0 + 32 < 1024) {
            const int k1 = k0 + 32;
#pragma unroll
            for (int s = 0; s < 2; ++s) {
                const int i = 2 * w + s;
                __builtin_amdgcn_global_load_lds(
                    (const AS1 unsigned int*)(A + (size_t)(t0 + i * 16 + srow) * 1024 + k1 + scol),
                    (AS3 unsigned int*)(&Ab[nxt][i * 512 + lane * 8]), 16, 0, 0);
            }
            __builtin_amdgcn_global_load_lds(
                (const AS1 unsigned int*)(W + (size_t)(n0 + w * 16 + srow) * 1024 + k1 + scol),
                (AS3 unsigned int*)(&Bb[nxt][w * 512 + lane * 8]), 16, 0, 0);
        }
        bf8_t af[4], bfr[2];
#pragma unroll
        for (int i = 0; i < 4; ++i)
            af[i] = *(const bf8_t*)(&Ab[cur][(wm + 16 * i + mrow) * 32 + kq]);
#pragma unroll
        for (int j = 0; j < 2; ++j)
            bfr[j] = *(const bf8_t*)(&Bb[cur][(wn + 16 * j + mrow) * 32 + kq]);
#pragma unroll
        for (int i = 0; i < 4; ++i)
#pragma unroll
            for (int j = 0; j < 2; ++j)
                acc[i][j] = __builtin_amdgcn_mfma_f32_16x16x32_bf16(
                    af[i], bfr[j], acc[i][j], 0, 0, 0);
    }
    const int crow = (lane >> 4) * 4;
    const int ccol = lane & 15;
#pragma unroll
    for (int i = 0; i < 4; ++i)
#pragma unroll
        for (int j = 0; j < 2; ++j) {
            const int col = n0 + wn + 16 * j + ccol;
            if (col < N) {
#pragma unroll
                for (int u = 0; u < 4; ++u) {
                    float vv = acc[i][j][u];
                    if (z == 0) vv = tanhf(vv);
                    else if (z == 3) vv = sigf(vv);
                    out[(size_t)(t0 + wm + 16 * i + crow + u) * N + col] = vv;
                }
            }
        }
}

// ---------------------------------------------------------------------------
// Fused LoRA-2 (w/a/v/g) + k post-process + PAIR-COMPOSED packet packing.
// r7 design (kept): no LDS; block-uniform h-reads via SMEM; red64 reduces.
// Packet layout (768 floats) unchanged from r4.
// ---------------------------------------------------------------------------
#define TOK 8
__global__ __launch_bounds__(256) void lora2f(
    const float* __restrict__ hwB, const float* __restrict__ haB,
    const float* __restrict__ hvB, const float* __restrict__ hgB,
    const float* __restrict__ w2, const float* __restrict__ a2,
    const float* __restrict__ v2, const float* __restrict__ g2,
    const float* __restrict__ w0, const float* __restrict__ a0,
    const float* __restrict__ v0,
    const float* __restrict__ k_k, const float* __restrict__ k_a,
    const float* __restrict__ v_first, const float* __restrict__ rB,
    float* __restrict__ kB, float* __restrict__ vB, float* __restrict__ gB,
    float* __restrict__ pk)
{
    const int tid = threadIdx.x;
    const int t0 = blockIdx.y * TOK;
    const int i  = blockIdx.x * 256 + tid;
    const int h  = i >> 6;
    const int j  = i & 63;

    float av[TOK], ew[TOK], vf[TOK];
    { // a = sigmoid(a0 + ha@a2)
        float acc[TOK];
        const float b0 = a0[i];
#pragma unroll
        for (int tt = 0; tt < TOK; ++tt) acc[tt] = b0;
        for (int jj = 0; jj < 64; jj += 4) {
            const float q0 = a2[(size_t)(jj + 0) * C_DIM + i];
            const float q1 = a2[(size_t)(jj + 1) * C_DIM + i];
            const float q2 = a2[(size_t)(jj + 2) * C_DIM + i];
            const float q3 = a2[(size_t)(jj + 3) * C_DIM + i];
#pragma unroll
            for (int tt = 0; tt < TOK; ++tt) {
                float4 h4 = *(const float4*)(haB + (size_t)(t0 + tt) * 64 + jj);
                acc[tt] = fmaf(h4.x, q0, acc[tt]);
                acc[tt] = fmaf(h4.y, q1, acc[tt]);
                acc[tt] = fmaf(h4.z, q2, acc[tt]);
                acc[tt] = fmaf(h4.w, q3, acc[tt]);
            }
        }
#pragma unroll
        for (int tt = 0; tt < TOK; ++tt) av[tt] = sigf(acc[tt]);
    }
    { // exp(w)
        float acc[TOK];
        const float b0 = w0[i];
#pragma unroll
        for (int tt = 0; tt < TOK; ++tt) acc[tt] = b0;
        for (int jj = 0; jj < 64; jj += 4) {
            const float q0 = w2[(size_t)(jj + 0) * C_DIM + i];
            const float q1 = w2[(size_t)(jj + 1) * C_DIM + i];
            const float q2 = w2[(size_t)(jj + 2) * C_DIM + i];
            const float q3 = w2[(size_t)(jj + 3) * C_DIM + i];
#pragma unroll
            for (int tt = 0; tt < TOK; ++tt) {
                float4 h4 = *(const float4*)(hwB + (size_t)(t0 + tt) * 64 + jj);
                acc[tt] = fmaf(h4.x, q0, acc[tt]);
                acc[tt] = fmaf(h4.y, q1, acc[tt]);
                acc[tt] = fmaf(h4.z, q2, acc[tt]);
                acc[tt] = fmaf(h4.w, q3, acc[tt]);
            }
        }
#pragma unroll
        for (int tt = 0; tt < TOK; ++tt)
            ew[tt] = __expf(-0.6065306597126334f * sigf(acc[tt]));
    }
    { // v mix
        float acc[TOK];
        const float b0 = v0[i];
#pragma unroll
        for (int tt = 0; tt < TOK; ++tt) acc[tt] = b0;
        for (int jj = 0; jj < 32; jj += 4) {
            const float q0 = v2[(size_t)(jj + 0) * C_DIM + i];
            const float q1 = v2[(size_t)(jj + 1) * C_DIM + i];
            const float q2 = v2[(size_t)(jj + 2) * C_DIM + i];
            const float q3 = v2[(size_t)(jj + 3) * C_DIM + i];
#pragma unroll
            for (int tt = 0; tt < TOK; ++tt) {
                float4 h4 = *(const float4*)(hvB + (size_t)(t0 + tt) * 32 + jj);
                acc[tt] = fmaf(h4.x, q0, acc[tt]);
                acc[tt] = fmaf(h4.y, q1, acc[tt]);
                acc[tt] = fmaf(h4.z, q2, acc[tt]);
                acc[tt] = fmaf(h4.w, q3, acc[tt]);
            }
        }
#pragma unroll
        for (int tt = 0; tt < TOK; ++tt) {
            const size_t gi = (size_t)(t0 + tt) * C_DIM + i;
            const float s = sigf(acc[tt]);
            const float vr = vB[gi];
            vf[tt] = vr + (v_first[gi] - vr) * s;
            vB[gi] = vf[tt];
        }
    }
    { // g
        float acc[TOK];
#pragma unroll
        for (int tt = 0; tt < TOK; ++tt) acc[tt] = 0.f;
        for (int jj = 0; jj < 128; jj += 4) {
            const float q0 = g2[(size_t)(jj + 0) * C_DIM + i];
            const float q1 = g2[(size_t)(jj + 1) * C_DIM + i];
            const float q2 = g2[(size_t)(jj + 2) * C_DIM + i];
            const float q3 = g2[(size_t)(jj + 3) * C_DIM + i];
#pragma unroll
            for (int tt = 0; tt < TOK; ++tt) {
                float4 h4 = *(const float4*)(hgB + (size_t)(t0 + tt) * 128 + jj);
                acc[tt] = fmaf(h4.x, q0, acc[tt]);
                acc[tt] = fmaf(h4.y, q1, acc[tt]);
                acc[tt] = fmaf(h4.z, q2, acc[tt]);
                acc[tt] = fmaf(h4.w, q3, acc[tt]);
            }
        }
#pragma unroll
        for (int tt = 0; tt < TOK; ++tt)
            gB[(size_t)(t0 + tt) * C_DIM + i] = acc[tt];
    }
    // k post-process + pair-composed packing
    const float kkw = k_k[i], kaw = k_a[i];
    const size_t pbase = (size_t)h * 1024 * PAIR_F;
    for (int pt = 0; pt < TOK / 2; ++pt) {
        float r_[2], e_[2], kf_[2], v_[2], aa_[2], bb_[2];
#pragma unroll
        for (int u = 0; u < 2; ++u) {
            const int tt = 2 * pt + u;
            const size_t gi = (size_t)(t0 + tt) * C_DIM + i;
            const float kraw = kB[gi];
            const float kn = kraw * kkw;
            const float ss = red64(kn * kn);
            const float sc = 1.f / fmaxf(sqrtf(ss), 1e-12f);
            const float kk = kn * sc;
            const float a_ = av[tt];
            const float kf = kraw * (1.f + (a_ - 1.f) * kaw);
            kB[gi] = kf;
            r_[u] = rB[gi];
            e_[u] = ew[tt];
            kf_[u] = kf;
            v_[u] = vf[tt];
            aa_[u] = -kk;
            bb_[u] = kk * a_;
        }
        const float E   = e_[0] * e_[1];
        const float A2e = e_[0] * aa_[1];
        const float B1e = bb_[0] * e_[1];
        const float K1e = kf_[0] * e_[1];
        const float R1e = e_[0] * r_[0];
        const float cba = red64(bb_[0] * aa_[1]);
        const float cka = red64(kf_[0] * aa_[1]);
        const float cbr = red64(bb_[0] * r_[0]);
        const float ckr = red64(kf_[0] * r_[0]);
        const float cbr2  = red64(B1e * r_[1]);
        const float ckr2  = red64(K1e * r_[1]);
        const float cb2r2 = red64(bb_[1] * r_[1]);
        const float ck2r2 = red64(kf_[1] * r_[1]);
        float* p = pk + pbase + (size_t)(blockIdx.y * (TOK / 2) + pt) * PAIR_F;
        p[j]        = E;
        p[64 + j]   = aa_[0];
        p[128 + j]  = A2e;
        p[192 + j]  = B1e;
        p[256 + j]  = K1e;
        p[320 + j]  = bb_[1];
        p[384 + j]  = kf_[1];
        p[448 + j]  = R1e;
        p[512 + j]  = E * r_[1];          // R2e = E ⊙ R2
        p[576 + 2 * j]     = v_[0];       // vv interleaved
        p[576 + 2 * j + 1] = v_[1];
        if (j == 0) {
            p[704] = cba;  p[705] = cka;  p[706] = cbr;  p[707] = ckr;
            p[708] = cbr2; p[709] = ckr2; p[710] = cb2r2; p[711] = ck2r2;
        }
    }
}

// ---------------------------------------------------------------------------
// CHUNKED SCAN. r9: NCH 16->32 / CPAIR 64->32 — same total pair-computes and
// pk traffic, but 2048 waves per scan phase (8 waves/CU = 2/SIMD) so
// co-resident waves hide each other's load/DPP latency (the r5->r6
// mechanism; intra-wave scheduling fixes plateaued 3x at ~60% stall).
// Buffers: Pbuf aliases the y region (pc->combine->overwritten by out_scan);
// Cbuf doubles as Scbuf via in-place combine (load C_c, then overwrite the
// slot with the chunk-start state).
// ---------------------------------------------------------------------------
struct SlotPC {
    float4 E, A1, A2e, B1e, K1e, B2, K2;
    float4 vva, vvb;   // {v1,v2} for rows rbase..rbase+3
    float4 sc;         // cba, cka, cbr, ckr (only x,y used here)
};

static __device__ __forceinline__ void slot_load_pc(
    SlotPC& K, const float* __restrict__ p, int j0, int rb2)
{
    K.E   = *(const float4*)(p + j0);
    K.A1  = *(const float4*)(p + 64 + j0);
    K.A2e = *(const float4*)(p + 128 + j0);
    K.B1e = *(const float4*)(p + 192 + j0);
    K.K1e = *(const float4*)(p + 256 + j0);
    K.B2  = *(const float4*)(p + 320 + j0);
    K.K2  = *(const float4*)(p + 384 + j0);
    K.vva = *(const float4*)(p + 576 + rb2);
    K.vvb = *(const float4*)(p + 576 + rb2 + 4);
    K.sc  = *(const float4*)(p + 704);
}

static __device__ __forceinline__ void pair_pc(
    f2_t* PSl, f2_t* PSh, f2_t* CSl, f2_t* CSh, const SlotPC& K)
{
    float pu1[4], pu2[4], cu1[4], cu2[4];
#pragma unroll
    for (int r = 0; r < 4; ++r) {
        pu1[r] = red16(dot4pk(PSl[r], PSh[r], K.A1));
        pu2[r] = red16(dot4pk(PSl[r], PSh[r], K.A2e));
        cu1[r] = red16(dot4pk(CSl[r], CSh[r], K.A1));
        cu2[r] = red16(dot4pk(CSl[r], CSh[r], K.A2e));
    }
#pragma unroll
    for (int r = 0; r < 4; ++r) {
        { // P update: v-terms exactly zero -> dropped (bitwise identical)
            const float sa1 = pu1[r];
            const float sa2 = fmaf(sa1, K.sc.x, pu2[r]);
            const f2_t sa1v = f2bc(sa1), sa2v = f2bc(sa2);
            f2_t nl = PSl[r] * lo2(K.E), nh = PSh[r] * hi2(K.E);
            nl = fma2(sa1v, lo2(K.B1e), nl); nh = fma2(sa1v, hi2(K.B1e), nh);
            nl = fma2(sa2v, lo2(K.B2), nl);  nh = fma2(sa2v, hi2(K.B2), nh);
            PSl[r] = nl; PSh[r] = nh;
        }
        { // C update: full recurrence from zero init
            const float v1 = r == 0 ? K.vva.x : r == 1 ? K.vva.z
                           : r == 2 ? K.vvb.x : K.vvb.z;
            const float v2 = r == 0 ? K.vva.y : r == 1 ? K.vva.w
                           : r == 2 ? K.vvb.y : K.vvb.w;
            const float sa1 = cu1[r];
            const float sa2 = fmaf(v1, K.sc.y, fmaf(sa1, K.sc.x, cu2[r]));
            const f2_t sa1v = f2bc(sa1), sa2v = f2bc(sa2);
            const f2_t v1v = f2bc(v1), v2v = f2bc(v2);
            f2_t nl = CSl[r] * lo2(K.E), nh = CSh[r] * hi2(K.E);
            nl = fma2(sa1v, lo2(K.B1e), nl); nh = fma2(sa1v, hi2(K.B1e), nh);
            nl = fma2(v1v, lo2(K.K1e), nl);  nh = fma2(v1v, hi2(K.K1e), nh);
            nl = fma2(sa2v, lo2(K.B2), nl);  nh = fma2(sa2v, hi2(K.B2), nh);
            nl = fma2(v2v, lo2(K.K2), nl);   nh = fma2(v2v, hi2(K.K2), nh);
            CSl[r] = nl; CSh[r] = nh;
        }
    }
}

// grid: b = h + 16*w + 64*c  (w stride 16 => same (h,c) on same XCD mod 8)
__global__ __launch_bounds__(64, 1) void pc_fused(
    const float* __restrict__ pk, float* __restrict__ Pbuf,
    float* __restrict__ Cbuf)
{
    const int b = blockIdx.x;
    const int h = b & 15;
    const int w = (b >> 4) & 3;
    const int c = b >> 6;
    const int l = threadIdx.x;
    const int q = l >> 4;
    const int j0 = (l & 15) * 4;
    const int rbase = w * 16 + q * 4;
    const int rb2 = 2 * rbase;
    const float* hbase = pk + ((size_t)h * 1024 + (size_t)c * CPAIR) * PAIR_F;

    f2_t PSl[4], PSh[4], CSl[4], CSh[4];
#pragma unroll
    for (int r = 0; r < 4; ++r) {
        const int row = rbase + r;
        PSl[r] = (f2_t){j0 == row ? 1.f : 0.f, j0 + 1 == row ? 1.f : 0.f};
        PSh[r] = (f2_t){j0 + 2 == row ? 1.f : 0.f, j0 + 3 == row ? 1.f : 0.f};
        CSl[r] = (f2_t){0.f, 0.f};
        CSh[r] = (f2_t){0.f, 0.f};
    }

    SlotPC s0, s1, s2, s3;
    slot_load_pc(s0, hbase + 0 * PAIR_F, j0, rb2);
    slot_load_pc(s1, hbase + 1 * PAIR_F, j0, rb2);
    slot_load_pc(s2, hbase + 2 * PAIR_F, j0, rb2);
    slot_load_pc(s3, hbase + 3 * PAIR_F, j0, rb2);
    __builtin_amdgcn_sched_barrier(0);

    for (int i = 0; i < CPAIR - 4; i += 4) {
        const float* pl = hbase + (size_t)(i + 4) * PAIR_F;
        // Pinned ring: loads for pair i+4 issue right after compute of pair i
        // and may NOT sink into later computes.
        pair_pc(PSl, PSh, CSl, CSh, s0); slot_load_pc(s0, pl + 0 * PAIR_F, j0, rb2);
        __builtin_amdgcn_sched_barrier(0);
        pair_pc(PSl, PSh, CSl, CSh, s1); slot_load_pc(s1, pl + 1 * PAIR_F, j0, rb2);
        __builtin_amdgcn_sched_barrier(0);
        pair_pc(PSl, PSh, CSl, CSh, s2); slot_load_pc(s2, pl + 2 * PAIR_F, j0, rb2);
        __builtin_amdgcn_sched_barrier(0);
        pair_pc(PSl, PSh, CSl, CSh, s3); slot_load_pc(s3, pl + 3 * PAIR_F, j0, rb2);
        __builtin_amdgcn_sched_barrier(0);
    }
    pair_pc(PSl, PSh, CSl, CSh, s0);
    pair_pc(PSl, PSh, CSl, CSh, s1);
    pair_pc(PSl, PSh, CSl, CSh, s2);
    pair_pc(PSl, PSh, CSl, CSh, s3);

    const size_t cb64 = ((size_t)h * NCH + c) * 4096;
#pragma unroll
    for (int r = 0; r < 4; ++r) {
        *(float4*)(Pbuf + cb64 + (size_t)(rbase + r) * 64 + j0) =
            (float4){PSl[r].x, PSl[r].y, PSh[r].x, PSh[r].y};
        *(float4*)(Cbuf + cb64 + (size_t)(rbase + r) * 64 + j0) =
            (float4){CSl[r].x, CSl[r].y, CSh[r].x, CSh[r].y};
    }
}

// Phase 2: serial chunk combine S <- S*P_c + C_c. IN-PLACE Scbuf: each
// thread loads its C_c value, then overwrites the slot with the chunk's
// START state (same address, same thread -> no race). 256 blocks x 64 thr.
__global__ __launch_bounds__(64) void combine(
    const float* __restrict__ Pbuf, float* __restrict__ CSbuf,
    const float* __restrict__ init_state)
{
    const int b = blockIdx.x;
    const int h = b & 15;
    const int g = b >> 4;
    const int l = threadIdx.x;
    const int vl = l >> 4;
    const int vidx = g * 4 + vl;
    const int j0 = (l & 15) * 4;
    __shared__ __align__(16) float Pl[64 * 64];
    __shared__ __align__(16) float sl[4 * 64];

    float4 s = *(const float4*)(init_state + h * 4096 + vidx * 64 + j0);
    for (int c = 0; c < NCH; ++c) {
        const size_t cbase = ((size_t)h * NCH + c) * 4096;
        float* cp = CSbuf + cbase + (size_t)vidx * 64 + j0;
        float4 Cv = *(const float4*)cp;   // load C_c FIRST
        *(float4*)cp = s;                 // then store chunk-start state
        const float* Psrc = Pbuf + cbase;
#pragma unroll
        for (int t = 0; t < 16; ++t)
            *(float4*)(&Pl[t * 256 + l * 4]) = *(const float4*)(Psrc + t * 256 + l * 4);
        *(float4*)(&sl[vl * 64 + j0]) = s;
        __syncthreads();
        f2_t al = {Cv.x, Cv.y}, ah = {Cv.z, Cv.w};
        for (int k = 0; k < 64; ++k) {
            const float sk = sl[vl * 64 + k];
            float4 Pr = *(const float4*)(&Pl[k * 64 + j0]);
            al = fma2(f2bc(sk), lo2(Pr), al);
            ah = fma2(f2bc(sk), hi2(Pr), ah);
        }
        s = (float4){al.x, al.y, ah.x, ah.y};
        __syncthreads();
    }
}

// ---- output scan: 4 rows/lane-group, 2-slot pinned ring -------------------
struct SlotO {
    float4 E, A1, A2e, B1e, K1e, B2, K2, R1e, R2e;
    float4 vva, vvb;
    float4 sc, sc2;
};

static __device__ __forceinline__ void slot_load_o(
    SlotO& K, const float* __restrict__ p, int j0, int rb2)
{
    K.E   = *(const float4*)(p + j0);
    K.A1  = *(const float4*)(p + 64 + j0);
    K.A2e = *(const float4*)(p + 128 + j0);
    K.B1e = *(const float4*)(p + 192 + j0);
    K.K1e = *(const float4*)(p + 256 + j0);
    K.B2  = *(const float4*)(p + 320 + j0);
    K.K2  = *(const float4*)(p + 384 + j0);
    K.R1e = *(const float4*)(p + 448 + j0);
    K.R2e = *(const float4*)(p + 512 + j0);
    K.vva = *(const float4*)(p + 576 + rb2);
    K.vvb = *(const float4*)(p + 576 + rb2 + 4);
    K.sc  = *(const float4*)(p + 704);
    K.sc2 = *(const float4*)(p + 708);
}

static __device__ __forceinline__ void pair_out(
    f2_t* Sl, f2_t* Sh, const SlotO& K, float4& o1v, float4& o2v)
{
    float u1[4], u2[4], op[4], oz[4];
#pragma unroll
    for (int r = 0; r < 4; ++r) {
        u1[r] = red16(dot4pk(Sl[r], Sh[r], K.A1));
        u2[r] = red16(dot4pk(Sl[r], Sh[r], K.A2e));
        op[r] = red16(dot4pk(Sl[r], Sh[r], K.R1e));
        oz[r] = red16(dot4pk(Sl[r], Sh[r], K.R2e));
    }
    float o1a[4], o2a[4];
#pragma unroll
    for (int r = 0; r < 4; ++r) {
        const float v1 = r == 0 ? K.vva.x : r == 1 ? K.vva.z
                       : r == 2 ? K.vvb.x : K.vvb.z;
        const float v2 = r == 0 ? K.vva.y : r == 1 ? K.vva.w
                       : r == 2 ? K.vvb.y : K.vvb.w;
        const float sa1 = u1[r];
        const float sa2 = fmaf(v1, K.sc.y, fmaf(sa1, K.sc.x, u2[r]));
        o1a[r] = fmaf(v1, K.sc.w, fmaf(sa1, K.sc.z, op[r]));
        o2a[r] = fmaf(v2, K.sc2.w, fmaf(sa2, K.sc2.z,
                 fmaf(v1, K.sc2.y, fmaf(sa1, K.sc2.x, oz[r]))));
        const f2_t sa1v = f2bc(sa1), sa2v = f2bc(sa2);
        const f2_t v1v = f2bc(v1), v2v = f2bc(v2);
        f2_t nl = Sl[r] * lo2(K.E), nh = Sh[r] * hi2(K.E);
        nl = fma2(sa1v, lo2(K.B1e), nl); nh = fma2(sa1v, hi2(K.B1e), nh);
        nl = fma2(v1v, lo2(K.K1e), nl);  nh = fma2(v1v, hi2(K.K1e), nh);
        nl = fma2(sa2v, lo2(K.B2), nl);  nh = fma2(sa2v, hi2(K.B2), nh);
        nl = fma2(v2v, lo2(K.K2), nl);   nh = fma2(v2v, hi2(K.K2), nh);
        Sl[r] = nl; Sh[r] = nh;
    }
    o1v = (float4){o1a[0], o1a[1], o1a[2], o1a[3]};
    o2v = (float4){o2a[0], o2a[1], o2a[2], o2a[3]};
}

__global__ __launch_bounds__(64, 1) void out_scan(
    const float* __restrict__ pk, const float* __restrict__ Scbuf,
    float* __restrict__ y)
{
    const int b = blockIdx.x;
    const int h = b & 15;
    const int w = (b >> 4) & 3;
    const int c = b >> 6;
    const int l = threadIdx.x;
    const int q = l >> 4;
    const int j0 = (l & 15) * 4;
    const int rbase = w * 16 + q * 4;
    const int rb2 = 2 * rbase;
    const int cb = h * 64;
    const float* hbase = pk + ((size_t)h * 1024 + (size_t)c * CPAIR) * PAIR_F;
    const size_t cb64 = ((size_t)h * NCH + c) * 4096;

    f2_t Sl[4], Sh[4];
#pragma unroll
    for (int r = 0; r < 4; ++r) {
        float4 S4 = *(const float4*)(Scbuf + cb64 + (size_t)(rbase + r) * 64 + j0);
        Sl[r] = (f2_t){S4.x, S4.y};
        Sh[r] = (f2_t){S4.z, S4.w};
    }

    SlotO s0, s1;
    slot_load_o(s0, hbase + 0 * PAIR_F, j0, rb2);
    slot_load_o(s1, hbase + 1 * PAIR_F, j0, rb2);
    __builtin_amdgcn_sched_barrier(0);

    const bool wr = (l & 15) == 0;
    const int pi0 = c * CPAIR;
    float4 o1v, o2v;
#define OUT_STORE(pidx)                                                       \
    if (wr) {                                                                 \
        float* yp = y + (size_t)(2 * (pidx)) * C_DIM + cb + rbase;            \
        *(float4*)yp = o1v;                                                   \
        *(float4*)(yp + C_DIM) = o2v;                                         \
    }
    for (int i = 0; i < CPAIR - 2; i += 2) {
        // 2-slot pinned ring: load for pair i+2 issues right after compute
        // of pair i; sched_barrier stops it sinking into pair i+1's compute.
        pair_out(Sl, Sh, s0, o1v, o2v);
        slot_load_o(s0, hbase + (size_t)(i + 2) * PAIR_F, j0, rb2);
        __builtin_amdgcn_sched_barrier(0);
        OUT_STORE(pi0 + i)
        pair_out(Sl, Sh, s1, o1v, o2v);
        if (i + 3 < CPAIR)
            slot_load_o(s1, hbase + (size_t)(i + 3) * PAIR_F, j0, rb2);
        __builtin_amdgcn_sched_barrier(0);
        OUT_STORE(pi0 + i + 1)
    }
    pair_out(Sl, Sh, s0, o1v, o2v);
    OUT_STORE(pi0 + CPAIR - 2)
    pair_out(Sl, Sh, s1, o1v, o2v);
    OUT_STORE(pi0 + CPAIR - 1)
#undef OUT_STORE
}

// ---------------------------------------------------------------------------
// GroupNorm + bonus + *g ; writes bf16 (xo*g) for the final MFMA GEMM.
// ---------------------------------------------------------------------------
__global__ __launch_bounds__(256) void gn_bonus(
    const float* __restrict__ y, const float* __restrict__ rb,
    const float* __restrict__ kb, const float* __restrict__ vb,
    const float* __restrict__ gb, const float* __restrict__ r_k,
    const float* __restrict__ lnw, const float* __restrict__ lnb,
    unsigned short* __restrict__ yg)
{
    const int t = blockIdx.x, tid = threadIdx.x;
    const int c0 = tid << 2;
    const size_t base = (size_t)t * C_DIM + c0;
    float4 yv = *(const float4*)(y + base);
    float sum = yv.x + yv.y + yv.z + yv.w;
    float ss  = yv.x * yv.x + yv.y * yv.y + yv.z * yv.z + yv.w * yv.w;
    float4 rv = *(const float4*)(rb + base);
    float4 kv = *(const float4*)(kb + base);
    float4 rkv = *(const float4*)(r_k + c0);
    float dot = rv.x * kv.x * rkv.x + rv.y * kv.y * rkv.y +
                rv.z * kv.z * rkv.z + rv.w * kv.w * rkv.w;
#pragma unroll
    for (int m = 1; m <= 8; m <<= 1) {
        sum += __shfl_xor(sum, m);
        ss  += __shfl_xor(ss, m);
        dot += __shfl_xor(dot, m);
    }
    const float mu = sum * 0.015625f;
    const float var = ss * 0.015625f - mu * mu;
    const float rstd = rsqrtf(var + 0.00064f);
    float4 wv = *(const float4*)(lnw + c0);
    float4 bv = *(const float4*)(lnb + c0);
    float4 vv = *(const float4*)(vb + base);
    float4 gv = *(const float4*)(gb + base);
    ushort4 o;
    o.x = f2bf(((yv.x - mu) * rstd * wv.x + bv.x + dot * vv.x) * gv.x);
    o.y = f2bf(((yv.y - mu) * rstd * wv.y + bv.y + dot * vv.y) * gv.y);
    o.z = f2bf(((yv.z - mu) * rstd * wv.z + bv.z + dot * vv.z) * gv.z);
    o.w = f2bf(((yv.w - mu) * rstd * wv.w + bv.w + dot * vv.w) * gv.w);
    *(ushort4*)(yg + base) = o;
}

// ---------------------------------------------------------------------------
extern "C" void kernel_launch(void* const* d_in, const int* in_sizes, int n_in,
                              void* d_out, int out_size, void* d_ws, size_t ws_size,
                              hipStream_t stream)
{
    (void)in_sizes; (void)n_in; (void)out_size; (void)ws_size;
    const float* x       = (const float*)d_in[0];
    const float* v_first = (const float*)d_in[1];
    const float* x_prev  = (const float*)d_in[2];
    const float* init_st = (const float*)d_in[3];
    const float* x_r = (const float*)d_in[4];
    const float* x_w = (const float*)d_in[5];
    const float* x_k = (const float*)d_in[6];
    const float* x_v = (const float*)d_in[7];
    const float* x_a = (const float*)d_in[8];
    const float* x_g = (const float*)d_in[9];
    const float* w0  = (const float*)d_in[10];
    const float* a0  = (const float*)d_in[11];
    const float* v0  = (const float*)d_in[12];
    const float* k_k = (const float*)d_in[13];
    const float* k_a = (const float*)d_in[14];
    const float* w1  = (const float*)d_in[15];
    const float* w2  = (const float*)d_in[16];
    const float* a1  = (const float*)d_in[17];
    const float* a2  = (const float*)d_in[18];
    const float* v1  = (const float*)d_in[19];
    const float* v2  = (const float*)d_in[20];
    const float* g1  = (const float*)d_in[21];
    const float* g2  = (const float*)d_in[22];
    const float* r_k = (const float*)d_in[23];
    const float* Wr  = (const float*)d_in[24];
    const float* Wk  = (const float*)d_in[25];
    const float* Wv  = (const float*)d_in[26];
    const float* Wo  = (const float*)d_in[27];
    const float* ln_w = (const float*)d_in[28];
    const float* ln_b = (const float*)d_in[29];

    float* out = (float*)d_out;
    float* ws  = (float*)d_ws;
    const size_t NE = (size_t)T_LEN * C_DIM;   // 2M
    const size_t WE = (size_t)C_DIM * C_DIM;   // 1M
    float* rB  = ws;
    float* kB  = ws + NE;
    float* vB  = ws + 2 * NE;
    float* gB  = ws + 3 * NE;
    float* hwB = ws + 4 * NE;                  // T*64
    float* haB = hwB + (size_t)T_LEN * 64;
    float* hvB = haB + (size_t)T_LEN * 64;
    float* hgB = hvB + (size_t)T_LEN * 32;     // h region < NE/2
    float* pk  = ws + 4 * NE + NE / 2;         // 6*NE floats (16*1024*768)
    unsigned short* b16 = (unsigned short*)(ws + 10 * NE + NE / 2);
    unsigned short* xr16 = b16;                // NE shorts
    unsigned short* xk16 = b16 + NE;
    unsigned short* xv16 = b16 + 2 * NE;
    unsigned short* Wr16 = b16 + 3 * NE;       // 4*WE shorts
    unsigned short* Wk16 = Wr16 + WE;
    unsigned short* Wv16 = Wr16 + 2 * WE;
    unsigned short* Wo16 = Wr16 + 3 * WE;
    unsigned short* yg16 = b16 + 3 * NE + 4 * WE;  // NE shorts
    unsigned short* lw16 = yg16 + NE;              // 320K shorts (LoRA weights)
    // xw/xa/xg bf16 live in the pk region (pk written later by lora2f)
    unsigned short* xw16 = (unsigned short*)pk;
    unsigned short* xa16 = xw16 + NE;
    unsigned short* xg16 = xw16 + 2 * NE;
    // yB aliases xr16+xk16 (consumed by gemms before the scan writes it)
    float* yB = (float*)xr16;
    // r9 chunk-scan buffers (NCH=32 -> 2M floats each):
    //   Pbuf  <- y region (xr16+xk16): pc_fused writes AFTER gemm3 consumed
    //            xr/xk; combine reads it; out_scan then overwrites with y.
    //   Cbuf  <- xv16+Wr16+Wk16 (2M floats contiguous; all dead after
    //            gemm3/lora1m; stops before live Wo16... spans Wv16? no:
    //            xv16(1M fl)+Wr16(0.5M fl)+Wk16(0.5M fl)=2M fl exactly).
    //            Doubles as Scbuf via in-place combine; must survive out_scan.
    float* Pbuf  = (float*)xr16;   // 16h x 32c x 64 x 64 = 2M floats
    float* CSbuf = (float*)xv16;   // 2M floats (xv16..Wk16)

    wcvtall<<<4384, 256, 0, stream>>>(Wr, Wk, Wv, Wo, w1, a1, v1, g1,
                                      Wr16, lw16);
    xcvt<<<T_LEN, 256, 0, stream>>>(x, x_prev, x_r, x_k, x_v, x_w, x_a, x_g,
                                    xr16, xk16, xv16, xw16, xa16, xg16);

    gemm_bf16_3<<<dim3(16, 16, 3), 256, 0, stream>>>(
        xr16, xk16, xv16, Wr16, Wk16, Wv16, rB, kB, vB);

    lora1m<<<dim3(2, 16, 4), 256, 0, stream>>>(
        xw16, xa16, xv16, xg16, lw16, hwB, haB, hvB, hgB);

    lora2f<<<dim3(4, 256), 256, 0, stream>>>(
        hwB, haB, hvB, hgB, w2, a2, v2, g2, w0, a0, v0,
        k_k, k_a, v_first, rB, kB, vB, gB, pk);

    pc_fused<<<16 * 4 * NCH, 64, 0, stream>>>(pk, Pbuf, CSbuf);
    combine<<<256, 64, 0, stream>>>(Pbuf, CSbuf, init_st);
    out_scan<<<16 * 4 * NCH, 64, 0, stream>>>(pk, CSbuf, yB);

    gn_bonus<<<T_LEN, 256, 0, stream>>>(yB, rB, kB, vB, gB, r_k, ln_w, ln_b, yg16);
    gemm_bf16<<<dim3(16, 16), 256, 0, stream>>>(yg16, Wo16, out);
}

// Round 10
// 378.177 us; speedup vs baseline: 1.3627x; 1.0422x over previous
//
#include <hip/hip_runtime.h>

#define T_LEN 2048
#define C_DIM 1024
#define PAIR_F 768          // floats per (head, step-pair) packet
#define NCH 32              // chunks
#define CPAIR 32            // pairs per chunk (NCH*CPAIR = 1024)

#define AS1 __attribute__((address_space(1)))
#define AS3 __attribute__((address_space(3)))

typedef __attribute__((ext_vector_type(8))) short bf8_t;
typedef __attribute__((ext_vector_type(4))) float f4_t;
typedef __attribute__((ext_vector_type(2))) float f2_t;

static __device__ __forceinline__ float sigf(float x) {
    return 1.f / (1.f + __expf(-x));
}
static __device__ __forceinline__ unsigned short f2bf(float f) {
    unsigned u = __float_as_uint(f);
    u += 0x7fff + ((u >> 16) & 1);
    return (unsigned short)(u >> 16);
}

// ---- cross-lane reduction helpers (defined early; used by lora2f + scans) --
static __device__ __forceinline__ float red16(float x) {
    int xi;
    xi = __builtin_amdgcn_mov_dpp(__float_as_int(x), 0x128, 0xf, 0xf, true);
    x += __int_as_float(xi);
    xi = __builtin_amdgcn_mov_dpp(__float_as_int(x), 0x124, 0xf, 0xf, true);
    x += __int_as_float(xi);
    xi = __builtin_amdgcn_mov_dpp(__float_as_int(x), 0x122, 0xf, 0xf, true);
    x += __int_as_float(xi);
    xi = __builtin_amdgcn_mov_dpp(__float_as_int(x), 0x121, 0xf, 0xf, true);
    x += __int_as_float(xi);
    return x;
}
// full 64-lane sum: DPP within 16 (VALU pipe), then only 2 DS-ops
static __device__ __forceinline__ float red64(float x) {
    x = red16(x);
    x += __shfl_xor(x, 16);
    x += __shfl_xor(x, 32);
    return x;
}

static __device__ __forceinline__ f2_t f2bc(float s) { return (f2_t){s, s}; }
static __device__ __forceinline__ f2_t fma2(f2_t a, f2_t b, f2_t c) {
    return __builtin_elementwise_fma(a, b, c);
}
static __device__ __forceinline__ f2_t lo2(const float4& v) { return (f2_t){v.x, v.y}; }
static __device__ __forceinline__ f2_t hi2(const float4& v) { return (f2_t){v.z, v.w}; }

static __device__ __forceinline__ float dot4pk(f2_t Sl, f2_t Sh, const float4& A) {
    f2_t m = Sl * lo2(A);
    m = fma2(Sh, hi2(A), m);
    return m.x + m.y;
}

// ---------------------------------------------------------------------------
// Convert the four 1024x1024 fp32 weights into one bf16 block (1M strides),
// plus the transposed LoRA stage-1 weights (blocks 4096..4383).
// ---------------------------------------------------------------------------
__global__ __launch_bounds__(256) void wcvtall(
    const float* __restrict__ Wr, const float* __restrict__ Wk,
    const float* __restrict__ Wv, const float* __restrict__ Wo,
    const float* __restrict__ w1, const float* __restrict__ a1,
    const float* __restrict__ v1, const float* __restrict__ g1,
    unsigned short* __restrict__ dst, unsigned short* __restrict__ lw16)
{
    const int b = blockIdx.x;
    if (b < 4096) {
        const size_t idx = ((size_t)b * 256 + threadIdx.x) * 4;
        const int sel = (int)(idx >> 20);
        const float* src = sel == 0 ? Wr : sel == 1 ? Wk : sel == 2 ? Wv : Wo;
        float4 v = *(const float4*)(src + (idx & 0xFFFFF));
        ushort4 o = {f2bf(v.x), f2bf(v.y), f2bf(v.z), f2bf(v.w)};
        *(ushort4*)(dst + idx) = o;
        return;
    }
    const int row = b - 4096;         // 0..287
    const float* src; int Kh, i; unsigned short* dl;
    if (row < 64)       { src = w1; Kh = 64;  i = row;       dl = lw16 + (size_t)row * 1024; }
    else if (row < 128) { src = a1; Kh = 64;  i = row - 64;  dl = lw16 + (size_t)row * 1024; }
    else if (row < 160) { src = v1; Kh = 32;  i = row - 128; dl = lw16 + (size_t)(row - 128 + 128) * 1024; }
    else                { src = g1; Kh = 128; i = row - 160; dl = lw16 + (size_t)(row - 160 + 192) * 1024; }
    const int c0 = threadIdx.x * 4;
#pragma unroll
    for (int u = 0; u < 4; ++u)
        dl[c0 + u] = f2bf(src[(size_t)(c0 + u) * Kh + i]);
}

// ---------------------------------------------------------------------------
// Token-shift mix -> bf16 A-matrices for r/k/v projections and w/a/g LoRA.
// ---------------------------------------------------------------------------
__global__ __launch_bounds__(256) void xcvt(
    const float* __restrict__ x, const float* __restrict__ xprev,
    const float* __restrict__ x_r, const float* __restrict__ x_k,
    const float* __restrict__ x_v, const float* __restrict__ x_w,
    const float* __restrict__ x_a, const float* __restrict__ x_g,
    unsigned short* __restrict__ xr16, unsigned short* __restrict__ xk16,
    unsigned short* __restrict__ xv16, unsigned short* __restrict__ xw16,
    unsigned short* __restrict__ xa16, unsigned short* __restrict__ xg16)
{
    const int t = blockIdx.x;
    const int c0 = threadIdx.x * 4;
    const size_t base = (size_t)t * C_DIM + c0;
    float4 xv = *(const float4*)(x + base);
    float4 pv = (t == 0) ? *(const float4*)(xprev + c0)
                         : *(const float4*)(x + base - C_DIM);
    float4 dx = {pv.x - xv.x, pv.y - xv.y, pv.z - xv.z, pv.w - xv.w};
#define MIXOUT(mixp, dstp)                                                    \
    {                                                                          \
        float4 mv = *(const float4*)(mixp + c0);                               \
        ushort4 o = {f2bf(xv.x + dx.x * mv.x), f2bf(xv.y + dx.y * mv.y),       \
                     f2bf(xv.z + dx.z * mv.z), f2bf(xv.w + dx.w * mv.w)};      \
        *(ushort4*)(dstp + base) = o;                                          \
    }
    MIXOUT(x_r, xr16) MIXOUT(x_k, xk16) MIXOUT(x_v, xv16)
    MIXOUT(x_w, xw16) MIXOUT(x_a, xa16) MIXOUT(x_g, xg16)
#undef MIXOUT
}

// ---------------------------------------------------------------------------
// bf16 MFMA NT GEMM core: out[t,i] = sum_c A[t,c]*W[i,c], fp32 accumulate.
// ---------------------------------------------------------------------------
static __device__ __forceinline__ void gemm_core(
    const unsigned short* __restrict__ A, const unsigned short* __restrict__ W,
    float* __restrict__ out)
{
    __shared__ unsigned short Ab[2][128 * 32];
    __shared__ unsigned short Bb[2][64 * 32];
    const int tid = threadIdx.x;
    const int lane = tid & 63;
    const int w = tid >> 6;
    const int n0 = blockIdx.x * 64;
    const int t0 = blockIdx.y * 128;
    const int wm = (w & 1) * 64;
    const int wn = (w >> 1) * 32;
    const int srow = lane >> 2;
    const int scol = (lane & 3) * 8;

    f4_t acc[4][2];
#pragma unroll
    for (int i = 0; i < 4; ++i)
#pragma unroll
        for (int j = 0; j < 2; ++j)
            acc[i][j] = (f4_t){0.f, 0.f, 0.f, 0.f};

#pragma unroll
    for (int s = 0; s < 2; ++s) {
        const int i = 2 * w + s;
        __builtin_amdgcn_global_load_lds(
            (const AS1 unsigned int*)(A + (size_t)(t0 + i * 16 + srow) * 1024 + scol),
            (AS3 unsigned int*)(&Ab[0][i * 512 + lane * 8]), 16, 0, 0);
    }
    __builtin_amdgcn_global_load_lds(
        (const AS1 unsigned int*)(W + (size_t)(n0 + w * 16 + srow) * 1024 + scol),
        (AS3 unsigned int*)(&Bb[0][w * 512 + lane * 8]), 16, 0, 0);

    const int mrow = lane & 15;
    const int kq = (lane >> 4) * 8;
    for (int k0 = 0; k0 < 1024; k0 += 32) {
        const int cur = (k0 >> 5) & 1, nxt = cur ^ 1;
        __syncthreads();
        if (k0 + 32 < 1024) {
            const int k1 = k0 + 32;
#pragma unroll
            for (int s = 0; s < 2; ++s) {
                const int i = 2 * w + s;
                __builtin_amdgcn_global_load_lds(
                    (const AS1 unsigned int*)(A + (size_t)(t0 + i * 16 + srow) * 1024 + k1 + scol),
                    (AS3 unsigned int*)(&Ab[nxt][i * 512 + lane * 8]), 16, 0, 0);
            }
            __builtin_amdgcn_global_load_lds(
                (const AS1 unsigned int*)(W + (size_t)(n0 + w * 16 + srow) * 1024 + k1 + scol),
                (AS3 unsigned int*)(&Bb[nxt][w * 512 + lane * 8]), 16, 0, 0);
        }
        bf8_t af[4], bfr[2];
#pragma unroll
        for (int i = 0; i < 4; ++i)
            af[i] = *(const bf8_t*)(&Ab[cur][(wm + 16 * i + mrow) * 32 + kq]);
#pragma unroll
        for (int j = 0; j < 2; ++j)
            bfr[j] = *(const bf8_t*)(&Bb[cur][(wn + 16 * j + mrow) * 32 + kq]);
#pragma unroll
        for (int i = 0; i < 4; ++i)
#pragma unroll
            for (int j = 0; j < 2; ++j)
                acc[i][j] = __builtin_amdgcn_mfma_f32_16x16x32_bf16(
                    af[i], bfr[j], acc[i][j], 0, 0, 0);
    }
    const int crow = (lane >> 4) * 4;
    const int ccol = lane & 15;
#pragma unroll
    for (int i = 0; i < 4; ++i)
#pragma unroll
        for (int j = 0; j < 2; ++j)
#pragma unroll
            for (int u = 0; u < 4; ++u)
                out[(size_t)(t0 + wm + 16 * i + crow + u) * 1024
                    + n0 + wn + 16 * j + ccol] = acc[i][j][u];
}

__global__ __launch_bounds__(256) void gemm_bf16_3(
    const unsigned short* __restrict__ xr, const unsigned short* __restrict__ xk,
    const unsigned short* __restrict__ xv,
    const unsigned short* __restrict__ Wr, const unsigned short* __restrict__ Wk,
    const unsigned short* __restrict__ Wv,
    float* __restrict__ rB, float* __restrict__ kB, float* __restrict__ vB)
{
    const int z = blockIdx.z;
    const unsigned short* A = z == 0 ? xr : z == 1 ? xk : xv;
    const unsigned short* W = z == 0 ? Wr : z == 1 ? Wk : Wv;
    float* out = z == 0 ? rB : z == 1 ? kB : vB;
    gemm_core(A, W, out);
}

__global__ __launch_bounds__(256) void gemm_bf16(
    const unsigned short* __restrict__ A, const unsigned short* __restrict__ W,
    float* __restrict__ out)
{
    gemm_core(A, W, out);
}

// ---------------------------------------------------------------------------
// Fused LoRA stage-1 via MFMA: z = 0:w(tanh,N=64) 1:a(N=64) 2:v(N=32) 3:g(sig,N=128)
// ---------------------------------------------------------------------------
__global__ __launch_bounds__(256) void lora1m(
    const unsigned short* __restrict__ xw, const unsigned short* __restrict__ xa,
    const unsigned short* __restrict__ xv, const unsigned short* __restrict__ xg,
    const unsigned short* __restrict__ lw16,
    float* __restrict__ hw, float* __restrict__ ha, float* __restrict__ hv,
    float* __restrict__ hg)
{
    const int z = blockIdx.z;
    const unsigned short* A = z == 0 ? xw : z == 1 ? xa : z == 2 ? xv : xg;
    const unsigned short* W = lw16 + (size_t)(z == 0 ? 0 : z == 1 ? 64 : z == 2 ? 128 : 192) * 1024;
    float* out = z == 0 ? hw : z == 1 ? ha : z == 2 ? hv : hg;
    const int N  = z == 3 ? 128 : z == 2 ? 32 : 64;
    const int Ns = z == 3 ? 128 : 64;
    const int n0 = blockIdx.x * 64;
    if (n0 >= Ns) return;

    __shared__ unsigned short Ab[2][128 * 32];
    __shared__ unsigned short Bb[2][64 * 32];
    const int tid = threadIdx.x;
    const int lane = tid & 63;
    const int w = tid >> 6;
    const int t0 = blockIdx.y * 128;
    const int wm = (w & 1) * 64;
    const int wn = (w >> 1) * 32;
    const int srow = lane >> 2;
    const int scol = (lane & 3) * 8;

    f4_t acc[4][2];
#pragma unroll
    for (int i = 0; i < 4; ++i)
#pragma unroll
        for (int j = 0; j < 2; ++j)
            acc[i][j] = (f4_t){0.f, 0.f, 0.f, 0.f};

#pragma unroll
    for (int s = 0; s < 2; ++s) {
        const int i = 2 * w + s;
        __builtin_amdgcn_global_load_lds(
            (const AS1 unsigned int*)(A + (size_t)(t0 + i * 16 + srow) * 1024 + scol),
            (AS3 unsigned int*)(&Ab[0][i * 512 + lane * 8]), 16, 0, 0);
    }
    __builtin_amdgcn_global_load_lds(
        (const AS1 unsigned int*)(W + (size_t)(n0 + w * 16 + srow) * 1024 + scol),
        (AS3 unsigned int*)(&Bb[0][w * 512 + lane * 8]), 16, 0, 0);

    const int mrow = lane & 15;
    const int kq = (lane >> 4) * 8;
    for (int k0 = 0; k0 < 1024; k0 += 32) {
        const int cur = (k0 >> 5) & 1, nxt = cur ^ 1;
        __syncthreads();
        if (k0 + 32 < 1024) {
            const int k1 = k0 + 32;
#pragma unroll
            for (int s = 0; s < 2; ++s) {
                const int i = 2 * w + s;
                __builtin_amdgcn_global_load_lds(
                    (const AS1 unsigned int*)(A + (size_t)(t0 + i * 16 + srow) * 1024 + k1 + scol),
                    (AS3 unsigned int*)(&Ab[nxt][i * 512 + lane * 8]), 16, 0, 0);
            }
            __builtin_amdgcn_global_load_lds(
                (const AS1 unsigned int*)(W + (size_t)(n0 + w * 16 + srow) * 1024 + k1 + scol),
                (AS3 unsigned int*)(&Bb[nxt][w * 512 + lane * 8]), 16, 0, 0);
        }
        bf8_t af[4], bfr[2];
#pragma unroll
        for (int i = 0; i < 4; ++i)
            af[i] = *(const bf8_t*)(&Ab[cur][(wm + 16 * i + mrow) * 32 + kq]);
#pragma unroll
        for (int j = 0; j < 2; ++j)
            bfr[j] = *(const bf8_t*)(&Bb[cur][(wn + 16 * j + mrow) * 32 + kq]);
#pragma unroll
        for (int i = 0; i < 4; ++i)
#pragma unroll
            for (int j = 0; j < 2; ++j)
                acc[i][j] = __builtin_amdgcn_mfma_f32_16x16x32_bf16(
                    af[i], bfr[j], acc[i][j], 0, 0, 0);
    }
    const int crow = (lane >> 4) * 4;
    const int ccol = lane & 15;
#pragma unroll
    for (int i = 0; i < 4; ++i)
#pragma unroll
        for (int j = 0; j < 2; ++j) {
            const int col = n0 + wn + 16 * j + ccol;
            if (col < N) {
#pragma unroll
                for (int u = 0; u < 4; ++u) {
                    float vv = acc[i][j][u];
                    if (z == 0) vv = tanhf(vv);
                    else if (z == 3) vv = sigf(vv);
                    out[(size_t)(t0 + wm + 16 * i + crow + u) * N + col] = vv;
                }
            }
        }
}

// ---------------------------------------------------------------------------
// Fused LoRA-2 (w/a/v/g) + k post-process + PAIR-COMPOSED packet packing.
// r10: TOK 8->4, grid (4,512) -> 2048 blocks = 8 blocks/CU = 32 waves/CU.
// r9 PMC: 57us at Occupancy 39% (grid gave only 4 blocks/CU), VALUBusy 32%,
// nothing saturated -> latency-exposed s_load->fma chains with too few
// co-resident waves. Same work/traffic, double the waves, half the chain
// length per thread.
// Packet layout (768 floats) unchanged from r4.
// ---------------------------------------------------------------------------
#define TOK 4
__global__ __launch_bounds__(256) void lora2f(
    const float* __restrict__ hwB, const float* __restrict__ haB,
    const float* __restrict__ hvB, const float* __restrict__ hgB,
    const float* __restrict__ w2, const float* __restrict__ a2,
    const float* __restrict__ v2, const float* __restrict__ g2,
    const float* __restrict__ w0, const float* __restrict__ a0,
    const float* __restrict__ v0,
    const float* __restrict__ k_k, const float* __restrict__ k_a,
    const float* __restrict__ v_first, const float* __restrict__ rB,
    float* __restrict__ kB, float* __restrict__ vB, float* __restrict__ gB,
    float* __restrict__ pk)
{
    const int tid = threadIdx.x;
    const int t0 = blockIdx.y * TOK;
    const int i  = blockIdx.x * 256 + tid;
    const int h  = i >> 6;
    const int j  = i & 63;

    float av[TOK], ew[TOK], vf[TOK];
    { // a = sigmoid(a0 + ha@a2)
        float acc[TOK];
        const float b0 = a0[i];
#pragma unroll
        for (int tt = 0; tt < TOK; ++tt) acc[tt] = b0;
        for (int jj = 0; jj < 64; jj += 4) {
            const float q0 = a2[(size_t)(jj + 0) * C_DIM + i];
            const float q1 = a2[(size_t)(jj + 1) * C_DIM + i];
            const float q2 = a2[(size_t)(jj + 2) * C_DIM + i];
            const float q3 = a2[(size_t)(jj + 3) * C_DIM + i];
#pragma unroll
            for (int tt = 0; tt < TOK; ++tt) {
                float4 h4 = *(const float4*)(haB + (size_t)(t0 + tt) * 64 + jj);
                acc[tt] = fmaf(h4.x, q0, acc[tt]);
                acc[tt] = fmaf(h4.y, q1, acc[tt]);
                acc[tt] = fmaf(h4.z, q2, acc[tt]);
                acc[tt] = fmaf(h4.w, q3, acc[tt]);
            }
        }
#pragma unroll
        for (int tt = 0; tt < TOK; ++tt) av[tt] = sigf(acc[tt]);
    }
    { // exp(w)
        float acc[TOK];
        const float b0 = w0[i];
#pragma unroll
        for (int tt = 0; tt < TOK; ++tt) acc[tt] = b0;
        for (int jj = 0; jj < 64; jj += 4) {
            const float q0 = w2[(size_t)(jj + 0) * C_DIM + i];
            const float q1 = w2[(size_t)(jj + 1) * C_DIM + i];
            const float q2 = w2[(size_t)(jj + 2) * C_DIM + i];
            const float q3 = w2[(size_t)(jj + 3) * C_DIM + i];
#pragma unroll
            for (int tt = 0; tt < TOK; ++tt) {
                float4 h4 = *(const float4*)(hwB + (size_t)(t0 + tt) * 64 + jj);
                acc[tt] = fmaf(h4.x, q0, acc[tt]);
                acc[tt] = fmaf(h4.y, q1, acc[tt]);
                acc[tt] = fmaf(h4.z, q2, acc[tt]);
                acc[tt] = fmaf(h4.w, q3, acc[tt]);
            }
        }
#pragma unroll
        for (int tt = 0; tt < TOK; ++tt)
            ew[tt] = __expf(-0.6065306597126334f * sigf(acc[tt]));
    }
    { // v mix
        float acc[TOK];
        const float b0 = v0[i];
#pragma unroll
        for (int tt = 0; tt < TOK; ++tt) acc[tt] = b0;
        for (int jj = 0; jj < 32; jj += 4) {
            const float q0 = v2[(size_t)(jj + 0) * C_DIM + i];
            const float q1 = v2[(size_t)(jj + 1) * C_DIM + i];
            const float q2 = v2[(size_t)(jj + 2) * C_DIM + i];
            const float q3 = v2[(size_t)(jj + 3) * C_DIM + i];
#pragma unroll
            for (int tt = 0; tt < TOK; ++tt) {
                float4 h4 = *(const float4*)(hvB + (size_t)(t0 + tt) * 32 + jj);
                acc[tt] = fmaf(h4.x, q0, acc[tt]);
                acc[tt] = fmaf(h4.y, q1, acc[tt]);
                acc[tt] = fmaf(h4.z, q2, acc[tt]);
                acc[tt] = fmaf(h4.w, q3, acc[tt]);
            }
        }
#pragma unroll
        for (int tt = 0; tt < TOK; ++tt) {
            const size_t gi = (size_t)(t0 + tt) * C_DIM + i;
            const float s = sigf(acc[tt]);
            const float vr = vB[gi];
            vf[tt] = vr + (v_first[gi] - vr) * s;
            vB[gi] = vf[tt];
        }
    }
    { // g
        float acc[TOK];
#pragma unroll
        for (int tt = 0; tt < TOK; ++tt) acc[tt] = 0.f;
        for (int jj = 0; jj < 128; jj += 4) {
            const float q0 = g2[(size_t)(jj + 0) * C_DIM + i];
            const float q1 = g2[(size_t)(jj + 1) * C_DIM + i];
            const float q2 = g2[(size_t)(jj + 2) * C_DIM + i];
            const float q3 = g2[(size_t)(jj + 3) * C_DIM + i];
#pragma unroll
            for (int tt = 0; tt < TOK; ++tt) {
                float4 h4 = *(const float4*)(hgB + (size_t)(t0 + tt) * 128 + jj);
                acc[tt] = fmaf(h4.x, q0, acc[tt]);
                acc[tt] = fmaf(h4.y, q1, acc[tt]);
                acc[tt] = fmaf(h4.z, q2, acc[tt]);
                acc[tt] = fmaf(h4.w, q3, acc[tt]);
            }
        }
#pragma unroll
        for (int tt = 0; tt < TOK; ++tt)
            gB[(size_t)(t0 + tt) * C_DIM + i] = acc[tt];
    }
    // k post-process + pair-composed packing
    const float kkw = k_k[i], kaw = k_a[i];
    const size_t pbase = (size_t)h * 1024 * PAIR_F;
    for (int pt = 0; pt < TOK / 2; ++pt) {
        float r_[2], e_[2], kf_[2], v_[2], aa_[2], bb_[2];
#pragma unroll
        for (int u = 0; u < 2; ++u) {
            const int tt = 2 * pt + u;
            const size_t gi = (size_t)(t0 + tt) * C_DIM + i;
            const float kraw = kB[gi];
            const float kn = kraw * kkw;
            const float ss = red64(kn * kn);
            const float sc = 1.f / fmaxf(sqrtf(ss), 1e-12f);
            const float kk = kn * sc;
            const float a_ = av[tt];
            const float kf = kraw * (1.f + (a_ - 1.f) * kaw);
            kB[gi] = kf;
            r_[u] = rB[gi];
            e_[u] = ew[tt];
            kf_[u] = kf;
            v_[u] = vf[tt];
            aa_[u] = -kk;
            bb_[u] = kk * a_;
        }
        const float E   = e_[0] * e_[1];
        const float A2e = e_[0] * aa_[1];
        const float B1e = bb_[0] * e_[1];
        const float K1e = kf_[0] * e_[1];
        const float R1e = e_[0] * r_[0];
        const float cba = red64(bb_[0] * aa_[1]);
        const float cka = red64(kf_[0] * aa_[1]);
        const float cbr = red64(bb_[0] * r_[0]);
        const float ckr = red64(kf_[0] * r_[0]);
        const float cbr2  = red64(B1e * r_[1]);
        const float ckr2  = red64(K1e * r_[1]);
        const float cb2r2 = red64(bb_[1] * r_[1]);
        const float ck2r2 = red64(kf_[1] * r_[1]);
        float* p = pk + pbase + (size_t)(blockIdx.y * (TOK / 2) + pt) * PAIR_F;
        p[j]        = E;
        p[64 + j]   = aa_[0];
        p[128 + j]  = A2e;
        p[192 + j]  = B1e;
        p[256 + j]  = K1e;
        p[320 + j]  = bb_[1];
        p[384 + j]  = kf_[1];
        p[448 + j]  = R1e;
        p[512 + j]  = E * r_[1];          // R2e = E ⊙ R2
        p[576 + 2 * j]     = v_[0];       // vv interleaved
        p[576 + 2 * j + 1] = v_[1];
        if (j == 0) {
            p[704] = cba;  p[705] = cka;  p[706] = cbr;  p[707] = ckr;
            p[708] = cbr2; p[709] = ckr2; p[710] = cb2r2; p[711] = ck2r2;
        }
    }
}

// ---------------------------------------------------------------------------
// CHUNKED SCAN (r9 structure, unchanged): NCH=32/CPAIR=32, 2048 waves per
// scan phase (2 waves/SIMD); Pbuf aliases y region; CSbuf in-place combine.
// ---------------------------------------------------------------------------
struct SlotPC {
    float4 E, A1, A2e, B1e, K1e, B2, K2;
    float4 vva, vvb;   // {v1,v2} for rows rbase..rbase+3
    float4 sc;         // cba, cka, cbr, ckr (only x,y used here)
};

static __device__ __forceinline__ void slot_load_pc(
    SlotPC& K, const float* __restrict__ p, int j0, int rb2)
{
    K.E   = *(const float4*)(p + j0);
    K.A1  = *(const float4*)(p + 64 + j0);
    K.A2e = *(const float4*)(p + 128 + j0);
    K.B1e = *(const float4*)(p + 192 + j0);
    K.K1e = *(const float4*)(p + 256 + j0);
    K.B2  = *(const float4*)(p + 320 + j0);
    K.K2  = *(const float4*)(p + 384 + j0);
    K.vva = *(const float4*)(p + 576 + rb2);
    K.vvb = *(const float4*)(p + 576 + rb2 + 4);
    K.sc  = *(const float4*)(p + 704);
}

static __device__ __forceinline__ void pair_pc(
    f2_t* PSl, f2_t* PSh, f2_t* CSl, f2_t* CSh, const SlotPC& K)
{
    float pu1[4], pu2[4], cu1[4], cu2[4];
#pragma unroll
    for (int r = 0; r < 4; ++r) {
        pu1[r] = red16(dot4pk(PSl[r], PSh[r], K.A1));
        pu2[r] = red16(dot4pk(PSl[r], PSh[r], K.A2e));
        cu1[r] = red16(dot4pk(CSl[r], CSh[r], K.A1));
        cu2[r] = red16(dot4pk(CSl[r], CSh[r], K.A2e));
    }
#pragma unroll
    for (int r = 0; r < 4; ++r) {
        { // P update: v-terms exactly zero -> dropped (bitwise identical)
            const float sa1 = pu1[r];
            const float sa2 = fmaf(sa1, K.sc.x, pu2[r]);
            const f2_t sa1v = f2bc(sa1), sa2v = f2bc(sa2);
            f2_t nl = PSl[r] * lo2(K.E), nh = PSh[r] * hi2(K.E);
            nl = fma2(sa1v, lo2(K.B1e), nl); nh = fma2(sa1v, hi2(K.B1e), nh);
            nl = fma2(sa2v, lo2(K.B2), nl);  nh = fma2(sa2v, hi2(K.B2), nh);
            PSl[r] = nl; PSh[r] = nh;
        }
        { // C update: full recurrence from zero init
            const float v1 = r == 0 ? K.vva.x : r == 1 ? K.vva.z
                           : r == 2 ? K.vvb.x : K.vvb.z;
            const float v2 = r == 0 ? K.vva.y : r == 1 ? K.vva.w
                           : r == 2 ? K.vvb.y : K.vvb.w;
            const float sa1 = cu1[r];
            const float sa2 = fmaf(v1, K.sc.y, fmaf(sa1, K.sc.x, cu2[r]));
            const f2_t sa1v = f2bc(sa1), sa2v = f2bc(sa2);
            const f2_t v1v = f2bc(v1), v2v = f2bc(v2);
            f2_t nl = CSl[r] * lo2(K.E), nh = CSh[r] * hi2(K.E);
            nl = fma2(sa1v, lo2(K.B1e), nl); nh = fma2(sa1v, hi2(K.B1e), nh);
            nl = fma2(v1v, lo2(K.K1e), nl);  nh = fma2(v1v, hi2(K.K1e), nh);
            nl = fma2(sa2v, lo2(K.B2), nl);  nh = fma2(sa2v, hi2(K.B2), nh);
            nl = fma2(v2v, lo2(K.K2), nl);   nh = fma2(v2v, hi2(K.K2), nh);
            CSl[r] = nl; CSh[r] = nh;
        }
    }
}

// grid: b = h + 16*w + 64*c  (w stride 16 => same (h,c) on same XCD mod 8)
__global__ __launch_bounds__(64, 1) void pc_fused(
    const float* __restrict__ pk, float* __restrict__ Pbuf,
    float* __restrict__ Cbuf)
{
    const int b = blockIdx.x;
    const int h = b & 15;
    const int w = (b >> 4) & 3;
    const int c = b >> 6;
    const int l = threadIdx.x;
    const int q = l >> 4;
    const int j0 = (l & 15) * 4;
    const int rbase = w * 16 + q * 4;
    const int rb2 = 2 * rbase;
    const float* hbase = pk + ((size_t)h * 1024 + (size_t)c * CPAIR) * PAIR_F;

    f2_t PSl[4], PSh[4], CSl[4], CSh[4];
#pragma unroll
    for (int r = 0; r < 4; ++r) {
        const int row = rbase + r;
        PSl[r] = (f2_t){j0 == row ? 1.f : 0.f, j0 + 1 == row ? 1.f : 0.f};
        PSh[r] = (f2_t){j0 + 2 == row ? 1.f : 0.f, j0 + 3 == row ? 1.f : 0.f};
        CSl[r] = (f2_t){0.f, 0.f};
        CSh[r] = (f2_t){0.f, 0.f};
    }

    SlotPC s0, s1, s2, s3;
    slot_load_pc(s0, hbase + 0 * PAIR_F, j0, rb2);
    slot_load_pc(s1, hbase + 1 * PAIR_F, j0, rb2);
    slot_load_pc(s2, hbase + 2 * PAIR_F, j0, rb2);
    slot_load_pc(s3, hbase + 3 * PAIR_F, j0, rb2);
    __builtin_amdgcn_sched_barrier(0);

    for (int i = 0; i < CPAIR - 4; i += 4) {
        const float* pl = hbase + (size_t)(i + 4) * PAIR_F;
        // Pinned ring: loads for pair i+4 issue right after compute of pair i
        // and may NOT sink into later computes.
        pair_pc(PSl, PSh, CSl, CSh, s0); slot_load_pc(s0, pl + 0 * PAIR_F, j0, rb2);
        __builtin_amdgcn_sched_barrier(0);
        pair_pc(PSl, PSh, CSl, CSh, s1); slot_load_pc(s1, pl + 1 * PAIR_F, j0, rb2);
        __builtin_amdgcn_sched_barrier(0);
        pair_pc(PSl, PSh, CSl, CSh, s2); slot_load_pc(s2, pl + 2 * PAIR_F, j0, rb2);
        __builtin_amdgcn_sched_barrier(0);
        pair_pc(PSl, PSh, CSl, CSh, s3); slot_load_pc(s3, pl + 3 * PAIR_F, j0, rb2);
        __builtin_amdgcn_sched_barrier(0);
    }
    pair_pc(PSl, PSh, CSl, CSh, s0);
    pair_pc(PSl, PSh, CSl, CSh, s1);
    pair_pc(PSl, PSh, CSl, CSh, s2);
    pair_pc(PSl, PSh, CSl, CSh, s3);

    const size_t cb64 = ((size_t)h * NCH + c) * 4096;
#pragma unroll
    for (int r = 0; r < 4; ++r) {
        *(float4*)(Pbuf + cb64 + (size_t)(rbase + r) * 64 + j0) =
            (float4){PSl[r].x, PSl[r].y, PSh[r].x, PSh[r].y};
        *(float4*)(Cbuf + cb64 + (size_t)(rbase + r) * 64 + j0) =
            (float4){CSl[r].x, CSl[r].y, CSh[r].x, CSh[r].y};
    }
}

// Phase 2: serial chunk combine S <- S*P_c + C_c. IN-PLACE Scbuf: each
// thread loads its C_c value, then overwrites the slot with the chunk's
// START state (same address, same thread -> no race). 256 blocks x 64 thr.
__global__ __launch_bounds__(64) void combine(
    const float* __restrict__ Pbuf, float* __restrict__ CSbuf,
    const float* __restrict__ init_state)
{
    const int b = blockIdx.x;
    const int h = b & 15;
    const int g = b >> 4;
    const int l = threadIdx.x;
    const int vl = l >> 4;
    const int vidx = g * 4 + vl;
    const int j0 = (l & 15) * 4;
    __shared__ __align__(16) float Pl[64 * 64];
    __shared__ __align__(16) float sl[4 * 64];

    float4 s = *(const float4*)(init_state + h * 4096 + vidx * 64 + j0);
    for (int c = 0; c < NCH; ++c) {
        const size_t cbase = ((size_t)h * NCH + c) * 4096;
        float* cp = CSbuf + cbase + (size_t)vidx * 64 + j0;
        float4 Cv = *(const float4*)cp;   // load C_c FIRST
        *(float4*)cp = s;                 // then store chunk-start state
        const float* Psrc = Pbuf + cbase;
#pragma unroll
        for (int t = 0; t < 16; ++t)
            *(float4*)(&Pl[t * 256 + l * 4]) = *(const float4*)(Psrc + t * 256 + l * 4);
        *(float4*)(&sl[vl * 64 + j0]) = s;
        __syncthreads();
        f2_t al = {Cv.x, Cv.y}, ah = {Cv.z, Cv.w};
        for (int k = 0; k < 64; ++k) {
            const float sk = sl[vl * 64 + k];
            float4 Pr = *(const float4*)(&Pl[k * 64 + j0]);
            al = fma2(f2bc(sk), lo2(Pr), al);
            ah = fma2(f2bc(sk), hi2(Pr), ah);
        }
        s = (float4){al.x, al.y, ah.x, ah.y};
        __syncthreads();
    }
}

// ---- output scan: 4 rows/lane-group, 2-slot pinned ring -------------------
struct SlotO {
    float4 E, A1, A2e, B1e, K1e, B2, K2, R1e, R2e;
    float4 vva, vvb;
    float4 sc, sc2;
};

static __device__ __forceinline__ void slot_load_o(
    SlotO& K, const float* __restrict__ p, int j0, int rb2)
{
    K.E   = *(const float4*)(p + j0);
    K.A1  = *(const float4*)(p + 64 + j0);
    K.A2e = *(const float4*)(p + 128 + j0);
    K.B1e = *(const float4*)(p + 192 + j0);
    K.K1e = *(const float4*)(p + 256 + j0);
    K.B2  = *(const float4*)(p + 320 + j0);
    K.K2  = *(const float4*)(p + 384 + j0);
    K.R1e = *(const float4*)(p + 448 + j0);
    K.R2e = *(const float4*)(p + 512 + j0);
    K.vva = *(const float4*)(p + 576 + rb2);
    K.vvb = *(const float4*)(p + 576 + rb2 + 4);
    K.sc  = *(const float4*)(p + 704);
    K.sc2 = *(const float4*)(p + 708);
}

static __device__ __forceinline__ void pair_out(
    f2_t* Sl, f2_t* Sh, const SlotO& K, float4& o1v, float4& o2v)
{
    float u1[4], u2[4], op[4], oz[4];
#pragma unroll
    for (int r = 0; r < 4; ++r) {
        u1[r] = red16(dot4pk(Sl[r], Sh[r], K.A1));
        u2[r] = red16(dot4pk(Sl[r], Sh[r], K.A2e));
        op[r] = red16(dot4pk(Sl[r], Sh[r], K.R1e));
        oz[r] = red16(dot4pk(Sl[r], Sh[r], K.R2e));
    }
    float o1a[4], o2a[4];
#pragma unroll
    for (int r = 0; r < 4; ++r) {
        const float v1 = r == 0 ? K.vva.x : r == 1 ? K.vva.z
                       : r == 2 ? K.vvb.x : K.vvb.z;
        const float v2 = r == 0 ? K.vva.y : r == 1 ? K.vva.w
                       : r == 2 ? K.vvb.y : K.vvb.w;
        const float sa1 = u1[r];
        const float sa2 = fmaf(v1, K.sc.y, fmaf(sa1, K.sc.x, u2[r]));
        o1a[r] = fmaf(v1, K.sc.w, fmaf(sa1, K.sc.z, op[r]));
        o2a[r] = fmaf(v2, K.sc2.w, fmaf(sa2, K.sc2.z,
                 fmaf(v1, K.sc2.y, fmaf(sa1, K.sc2.x, oz[r]))));
        const f2_t sa1v = f2bc(sa1), sa2v = f2bc(sa2);
        const f2_t v1v = f2bc(v1), v2v = f2bc(v2);
        f2_t nl = Sl[r] * lo2(K.E), nh = Sh[r] * hi2(K.E);
        nl = fma2(sa1v, lo2(K.B1e), nl); nh = fma2(sa1v, hi2(K.B1e), nh);
        nl = fma2(v1v, lo2(K.K1e), nl);  nh = fma2(v1v, hi2(K.K1e), nh);
        nl = fma2(sa2v, lo2(K.B2), nl);  nh = fma2(sa2v, hi2(K.B2), nh);
        nl = fma2(v2v, lo2(K.K2), nl);   nh = fma2(v2v, hi2(K.K2), nh);
        Sl[r] = nl; Sh[r] = nh;
    }
    o1v = (float4){o1a[0], o1a[1], o1a[2], o1a[3]};
    o2v = (float4){o2a[0], o2a[1], o2a[2], o2a[3]};
}

__global__ __launch_bounds__(64, 1) void out_scan(
    const float* __restrict__ pk, const float* __restrict__ Scbuf,
    float* __restrict__ y)
{
    const int b = blockIdx.x;
    const int h = b & 15;
    const int w = (b >> 4) & 3;
    const int c = b >> 6;
    const int l = threadIdx.x;
    const int q = l >> 4;
    const int j0 = (l & 15) * 4;
    const int rbase = w * 16 + q * 4;
    const int rb2 = 2 * rbase;
    const int cb = h * 64;
    const float* hbase = pk + ((size_t)h * 1024 + (size_t)c * CPAIR) * PAIR_F;
    const size_t cb64 = ((size_t)h * NCH + c) * 4096;

    f2_t Sl[4], Sh[4];
#pragma unroll
    for (int r = 0; r < 4; ++r) {
        float4 S4 = *(const float4*)(Scbuf + cb64 + (size_t)(rbase + r) * 64 + j0);
        Sl[r] = (f2_t){S4.x, S4.y};
        Sh[r] = (f2_t){S4.z, S4.w};
    }

    SlotO s0, s1;
    slot_load_o(s0, hbase + 0 * PAIR_F, j0, rb2);
    slot_load_o(s1, hbase + 1 * PAIR_F, j0, rb2);
    __builtin_amdgcn_sched_barrier(0);

    const bool wr = (l & 15) == 0;
    const int pi0 = c * CPAIR;
    float4 o1v, o2v;
#define OUT_STORE(pidx)                                                       \
    if (wr) {                                                                 \
        float* yp = y + (size_t)(2 * (pidx)) * C_DIM + cb + rbase;            \
        *(float4*)yp = o1v;                                                   \
        *(float4*)(yp + C_DIM) = o2v;                                         \
    }
    for (int i = 0; i < CPAIR - 2; i += 2) {
        // 2-slot pinned ring: load for pair i+2 issues right after compute
        // of pair i; sched_barrier stops it sinking into pair i+1's compute.
        pair_out(Sl, Sh, s0, o1v, o2v);
        slot_load_o(s0, hbase + (size_t)(i + 2) * PAIR_F, j0, rb2);
        __builtin_amdgcn_sched_barrier(0);
        OUT_STORE(pi0 + i)
        pair_out(Sl, Sh, s1, o1v, o2v);
        if (i + 3 < CPAIR)
            slot_load_o(s1, hbase + (size_t)(i + 3) * PAIR_F, j0, rb2);
        __builtin_amdgcn_sched_barrier(0);
        OUT_STORE(pi0 + i + 1)
    }
    pair_out(Sl, Sh, s0, o1v, o2v);
    OUT_STORE(pi0 + CPAIR - 2)
    pair_out(Sl, Sh, s1, o1v, o2v);
    OUT_STORE(pi0 + CPAIR - 1)
#undef OUT_STORE
}

// ---------------------------------------------------------------------------
// GroupNorm + bonus + *g ; writes bf16 (xo*g) for the final MFMA GEMM.
// ---------------------------------------------------------------------------
__global__ __launch_bounds__(256) void gn_bonus(
    const float* __restrict__ y, const float* __restrict__ rb,
    const float* __restrict__ kb, const float* __restrict__ vb,
    const float* __restrict__ gb, const float* __restrict__ r_k,
    const float* __restrict__ lnw, const float* __restrict__ lnb,
    unsigned short* __restrict__ yg)
{
    const int t = blockIdx.x, tid = threadIdx.x;
    const int c0 = tid << 2;
    const size_t base = (size_t)t * C_DIM + c0;
    float4 yv = *(const float4*)(y + base);
    float sum = yv.x + yv.y + yv.z + yv.w;
    float ss  = yv.x * yv.x + yv.y * yv.y + yv.z * yv.z + yv.w * yv.w;
    float4 rv = *(const float4*)(rb + base);
    float4 kv = *(const float4*)(kb + base);
    float4 rkv = *(const float4*)(r_k + c0);
    float dot = rv.x * kv.x * rkv.x + rv.y * kv.y * rkv.y +
                rv.z * kv.z * rkv.z + rv.w * kv.w * rkv.w;
#pragma unroll
    for (int m = 1; m <= 8; m <<= 1) {
        sum += __shfl_xor(sum, m);
        ss  += __shfl_xor(ss, m);
        dot += __shfl_xor(dot, m);
    }
    const float mu = sum * 0.015625f;
    const float var = ss * 0.015625f - mu * mu;
    const float rstd = rsqrtf(var + 0.00064f);
    float4 wv = *(const float4*)(lnw + c0);
    float4 bv = *(const float4*)(lnb + c0);
    float4 vv = *(const float4*)(vb + base);
    float4 gv = *(const float4*)(gb + base);
    ushort4 o;
    o.x = f2bf(((yv.x - mu) * rstd * wv.x + bv.x + dot * vv.x) * gv.x);
    o.y = f2bf(((yv.y - mu) * rstd * wv.y + bv.y + dot * vv.y) * gv.y);
    o.z = f2bf(((yv.z - mu) * rstd * wv.z + bv.z + dot * vv.z) * gv.z);
    o.w = f2bf(((yv.w - mu) * rstd * wv.w + bv.w + dot * vv.w) * gv.w);
    *(ushort4*)(yg + base) = o;
}

// ---------------------------------------------------------------------------
extern "C" void kernel_launch(void* const* d_in, const int* in_sizes, int n_in,
                              void* d_out, int out_size, void* d_ws, size_t ws_size,
                              hipStream_t stream)
{
    (void)in_sizes; (void)n_in; (void)out_size; (void)ws_size;
    const float* x       = (const float*)d_in[0];
    const float* v_first = (const float*)d_in[1];
    const float* x_prev  = (const float*)d_in[2];
    const float* init_st = (const float*)d_in[3];
    const float* x_r = (const float*)d_in[4];
    const float* x_w = (const float*)d_in[5];
    const float* x_k = (const float*)d_in[6];
    const float* x_v = (const float*)d_in[7];
    const float* x_a = (const float*)d_in[8];
    const float* x_g = (const float*)d_in[9];
    const float* w0  = (const float*)d_in[10];
    const float* a0  = (const float*)d_in[11];
    const float* v0  = (const float*)d_in[12];
    const float* k_k = (const float*)d_in[13];
    const float* k_a = (const float*)d_in[14];
    const float* w1  = (const float*)d_in[15];
    const float* w2  = (const float*)d_in[16];
    const float* a1  = (const float*)d_in[17];
    const float* a2  = (const float*)d_in[18];
    const float* v1  = (const float*)d_in[19];
    const float* v2  = (const float*)d_in[20];
    const float* g1  = (const float*)d_in[21];
    const float* g2  = (const float*)d_in[22];
    const float* r_k = (const float*)d_in[23];
    const float* Wr  = (const float*)d_in[24];
    const float* Wk  = (const float*)d_in[25];
    const float* Wv  = (const float*)d_in[26];
    const float* Wo  = (const float*)d_in[27];
    const float* ln_w = (const float*)d_in[28];
    const float* ln_b = (const float*)d_in[29];

    float* out = (float*)d_out;
    float* ws  = (float*)d_ws;
    const size_t NE = (size_t)T_LEN * C_DIM;   // 2M
    const size_t WE = (size_t)C_DIM * C_DIM;   // 1M
    float* rB  = ws;
    float* kB  = ws + NE;
    float* vB  = ws + 2 * NE;
    float* gB  = ws + 3 * NE;
    float* hwB = ws + 4 * NE;                  // T*64
    float* haB = hwB + (size_t)T_LEN * 64;
    float* hvB = haB + (size_t)T_LEN * 64;
    float* hgB = hvB + (size_t)T_LEN * 32;     // h region < NE/2
    float* pk  = ws + 4 * NE + NE / 2;         // 6*NE floats (16*1024*768)
    unsigned short* b16 = (unsigned short*)(ws + 10 * NE + NE / 2);
    unsigned short* xr16 = b16;                // NE shorts
    unsigned short* xk16 = b16 + NE;
    unsigned short* xv16 = b16 + 2 * NE;
    unsigned short* Wr16 = b16 + 3 * NE;       // 4*WE shorts
    unsigned short* Wk16 = Wr16 + WE;
    unsigned short* Wv16 = Wr16 + 2 * WE;
    unsigned short* Wo16 = Wr16 + 3 * WE;
    unsigned short* yg16 = b16 + 3 * NE + 4 * WE;  // NE shorts
    unsigned short* lw16 = yg16 + NE;              // 320K shorts (LoRA weights)
    // xw/xa/xg bf16 live in the pk region (pk written later by lora2f)
    unsigned short* xw16 = (unsigned short*)pk;
    unsigned short* xa16 = xw16 + NE;
    unsigned short* xg16 = xw16 + 2 * NE;
    // yB aliases xr16+xk16 (consumed by gemms before the scan writes it)
    float* yB = (float*)xr16;
    // Chunk-scan buffers (NCH=32 -> 2M floats each):
    //   Pbuf  <- y region (xr16+xk16)
    //   CSbuf <- xv16+Wr16+Wk16 (2M floats exactly; dead after gemm3/lora1m)
    float* Pbuf  = (float*)xr16;   // 16h x 32c x 64 x 64 = 2M floats
    float* CSbuf = (float*)xv16;   // 2M floats (xv16..Wk16)

    wcvtall<<<4384, 256, 0, stream>>>(Wr, Wk, Wv, Wo, w1, a1, v1, g1,
                                      Wr16, lw16);
    xcvt<<<T_LEN, 256, 0, stream>>>(x, x_prev, x_r, x_k, x_v, x_w, x_a, x_g,
                                    xr16, xk16, xv16, xw16, xa16, xg16);

    gemm_bf16_3<<<dim3(16, 16, 3), 256, 0, stream>>>(
        xr16, xk16, xv16, Wr16, Wk16, Wv16, rB, kB, vB);

    lora1m<<<dim3(2, 16, 4), 256, 0, stream>>>(
        xw16, xa16, xv16, xg16, lw16, hwB, haB, hvB, hgB);

    lora2f<<<dim3(4, T_LEN / TOK), 256, 0, stream>>>(
        hwB, haB, hvB, hgB, w2, a2, v2, g2, w0, a0, v0,
        k_k, k_a, v_first, rB, kB, vB, gB, pk);

    pc_fused<<<16 * 4 * NCH, 64, 0, stream>>>(pk, Pbuf, CSbuf);
    combine<<<256, 64, 0, stream>>>(Pbuf, CSbuf, init_st);
    out_scan<<<16 * 4 * NCH, 64, 0, stream>>>(pk, CSbuf, yB);

    gn_bonus<<<T_LEN, 256, 0, stream>>>(yB, rB, kB, vB, gB, r_k, ln_w, ln_b, yg16);
    gemm_bf16<<<dim3(16, 16), 256, 0, stream>>>(yg16, Wo16, out);
}